// Round 1
// baseline (1048.887 us; speedup 1.0000x reference)
//
#include <hip/hip_runtime.h>
#include <math.h>

typedef float fx4 __attribute__((ext_vector_type(4)));

#define HDIM 1024
#define SEQ  2048
#define BATCH 2
#define NHEAD 16
#define HD    64
#define MTOT  4096   // BATCH*SEQ
#define LSCALE 8.0f  // lora_alpha / lora_rank

// ---------------------------------------------------------------------------
// K1: XA = X @ [A0|A1|A2]  (each A is [1024,8]); out row-stride 24.
// One wave per row; lane-strided dot + shuffle reduce.
// ---------------------------------------------------------------------------
__global__ __launch_bounds__(64)
void lora_down_kernel(const float* __restrict__ X,
                      const float* __restrict__ A0,
                      const float* __restrict__ A1,
                      const float* __restrict__ A2,
                      float* __restrict__ out, int nmat)
{
    int row  = blockIdx.x;
    int lane = threadIdx.x;
    const float* xr = X + (size_t)row * HDIM;
    float xv[16];
#pragma unroll
    for (int i = 0; i < 16; ++i) xv[i] = xr[lane + 64 * i];
    const float* Amats[3] = {A0, A1, A2};
    for (int m = 0; m < nmat; ++m) {
        const float* A = Amats[m];
        float s[8];
#pragma unroll
        for (int c = 0; c < 8; ++c) s[c] = 0.f;
#pragma unroll
        for (int i = 0; i < 16; ++i) {
            const float* ap = A + (size_t)(lane + 64 * i) * 8;
#pragma unroll
            for (int c = 0; c < 8; ++c) s[c] += xv[i] * ap[c];
        }
#pragma unroll
        for (int c = 0; c < 8; ++c) {
#pragma unroll
            for (int off = 1; off < 64; off <<= 1)
                s[c] += __shfl_xor(s[c], off, 64);
        }
        if (lane == 0) {
#pragma unroll
            for (int c = 0; c < 8; ++c)
                out[(size_t)row * 24 + m * 8 + c] = s[c];
        }
    }
}

// ---------------------------------------------------------------------------
// K2: Out = X @ W + LSCALE * (XA) @ Bm   for up to 3 projections (blockIdx.z).
// 128x128 tile, BK=8, 256 threads, 8x8 per thread, reg-prefetch of next K-slab.
// ---------------------------------------------------------------------------
__global__ __launch_bounds__(256, 2)
void gemm_lora3_kernel(const float* __restrict__ X,
                       const float* __restrict__ W0, const float* __restrict__ W1, const float* __restrict__ W2,
                       const float* __restrict__ XA,
                       const float* __restrict__ B0, const float* __restrict__ B1, const float* __restrict__ B2,
                       float* __restrict__ Out0, float* __restrict__ Out1, float* __restrict__ Out2,
                       int xa_stride)
{
    const int K = HDIM, N = HDIM;
    int pz = blockIdx.z;
    const float* W  = (pz == 0) ? W0 : (pz == 1) ? W1 : W2;
    const float* Bm = (pz == 0) ? B0 : (pz == 1) ? B1 : B2;
    float* Out      = (pz == 0) ? Out0 : (pz == 1) ? Out1 : Out2;
    int xa_off = pz * 8;

    int brow = blockIdx.y * 128;
    int bcol = blockIdx.x * 128;
    int t  = threadIdx.x;
    int tx = t & 15;
    int ty = t >> 4;

    __shared__ __align__(16) float As[8][128];
    __shared__ __align__(16) float Bs[8][128];

    float acc[8][8];
#pragma unroll
    for (int i = 0; i < 8; ++i)
#pragma unroll
        for (int j = 0; j < 8; ++j) acc[i][j] = 0.f;

    int arow = t >> 1;
    int acol = (t & 1) * 4;
    const float* xp = X + (size_t)(brow + arow) * K + acol;
    int bkr = t >> 5;
    int bnc = (t & 31) * 4;
    const float* wp = W + (size_t)bkr * N + bcol + bnc;

    fx4 av = *(const fx4*)xp;
    fx4 bv = *(const fx4*)wp;

    for (int k0 = 0; k0 < K; k0 += 8) {
        __syncthreads();
        As[acol + 0][arow] = av[0];
        As[acol + 1][arow] = av[1];
        As[acol + 2][arow] = av[2];
        As[acol + 3][arow] = av[3];
        *(fx4*)&Bs[bkr][bnc] = bv;
        __syncthreads();
        if (k0 + 8 < K) {
            av = *(const fx4*)(xp + k0 + 8);
            bv = *(const fx4*)(wp + (size_t)(k0 + 8) * N);
        }
#pragma unroll
        for (int k = 0; k < 8; ++k) {
            fx4 a0 = *(const fx4*)&As[k][ty * 8];
            fx4 a1 = *(const fx4*)&As[k][ty * 8 + 4];
            fx4 b0 = *(const fx4*)&Bs[k][tx * 8];
            fx4 b1 = *(const fx4*)&Bs[k][tx * 8 + 4];
#pragma unroll
            for (int i = 0; i < 4; ++i)
#pragma unroll
                for (int j = 0; j < 4; ++j) {
                    acc[i][j]         += a0[i] * b0[j];
                    acc[i][j + 4]     += a0[i] * b1[j];
                    acc[i + 4][j]     += a1[i] * b0[j];
                    acc[i + 4][j + 4] += a1[i] * b1[j];
                }
        }
    }

    // rank-8 LoRA epilogue: acc += LSCALE * XA[row, xa_off..+8] * Bm[., col]
    float lb[8][8];
#pragma unroll
    for (int r = 0; r < 8; ++r) {
        fx4 c0 = *(const fx4*)&Bm[(size_t)r * N + bcol + tx * 8];
        fx4 c1 = *(const fx4*)&Bm[(size_t)r * N + bcol + tx * 8 + 4];
#pragma unroll
        for (int j = 0; j < 4; ++j) { lb[r][j] = c0[j]; lb[r][j + 4] = c1[j]; }
    }
#pragma unroll
    for (int i = 0; i < 8; ++i) {
        int row = brow + ty * 8 + i;
        const float* lap = XA + (size_t)row * xa_stride + xa_off;
        float la[8];
#pragma unroll
        for (int r = 0; r < 8; ++r) la[r] = lap[r] * LSCALE;
        float* op = Out + (size_t)row * N + bcol + tx * 8;
        fx4 o0, o1;
#pragma unroll
        for (int j = 0; j < 8; ++j) {
            float sum = acc[i][j];
#pragma unroll
            for (int r = 0; r < 8; ++r) sum += la[r] * lb[r][j];
            if (j < 4) o0[j] = sum; else o1[j - 4] = sum;
        }
        *(fx4*)op       = o0;
        *(fx4*)(op + 4) = o1;
    }
}

// ---------------------------------------------------------------------------
// K3: flash attention fp32. Block = (b, h, 64 q-rows); K/V tiles of 64 rows.
// Thread (qg=t/16, kg=t%15..): 4x4 score sub-tile, rows 4qg+i, k-cols kg+16c.
// P-tile aliases the K-tile LDS buffer (saves 17KB -> 3 blocks/CU).
// ---------------------------------------------------------------------------
__global__ __launch_bounds__(256, 2)
void attn_kernel(const float* __restrict__ Q, const float* __restrict__ Kb,
                 const float* __restrict__ Vb, const float* __restrict__ mask,
                 float* __restrict__ ctx)
{
    int qt = blockIdx.x, h = blockIdx.y, b = blockIdx.z;
    int t  = threadIdx.x;
    int kg = t & 15;
    int qg = t >> 4;

    __shared__ __align__(16) float Qs[64][68];
    __shared__ __align__(16) float KPs[64][68];   // K tile, then P tile
    __shared__ __align__(16) float Vs[64][68];
    __shared__ float Ms[64];

    const float* qp = Q + ((size_t)(b * SEQ + qt * 64)) * HDIM + h * HD;
#pragma unroll
    for (int i4 = 0; i4 < 4; ++i4) {
        int idx = t + 256 * i4;
        int r = idx >> 4;
        int c = (idx & 15) * 4;
        fx4 qv = *(const fx4*)(qp + (size_t)r * HDIM + c);
        *(fx4*)&Qs[r][c] = qv * 0.125f;   // fold 1/sqrt(HD)
    }

    float m_run[4], l_run[4], acc[4][4];
#pragma unroll
    for (int i = 0; i < 4; ++i) {
        m_run[i] = -1e30f; l_run[i] = 0.f;
#pragma unroll
        for (int j = 0; j < 4; ++j) acc[i][j] = 0.f;
    }

    const float* kp0 = Kb + ((size_t)(b * SEQ)) * HDIM + h * HD;
    const float* vp0 = Vb + ((size_t)(b * SEQ)) * HDIM + h * HD;

    for (int kt = 0; kt < SEQ / 64; ++kt) {
        const float* kp = kp0 + (size_t)kt * 64 * HDIM;
        const float* vp = vp0 + (size_t)kt * 64 * HDIM;
        __syncthreads();   // prev-tile P/V reads done before overwrite
#pragma unroll
        for (int i4 = 0; i4 < 4; ++i4) {
            int idx = t + 256 * i4;
            int r = idx >> 4;
            int c = (idx & 15) * 4;
            *(fx4*)&KPs[r][c] = *(const fx4*)(kp + (size_t)r * HDIM + c);
            *(fx4*)&Vs[r][c]  = *(const fx4*)(vp + (size_t)r * HDIM + c);
        }
        if (t < 64) Ms[t] = (1.0f - mask[b * SEQ + kt * 64 + t]) * -10000.0f;
        __syncthreads();

        // scores: rows 4qg+i, cols kg+16c
        float s[4][4];
#pragma unroll
        for (int i = 0; i < 4; ++i)
#pragma unroll
            for (int c = 0; c < 4; ++c) s[i][c] = Ms[kg + 16 * c];
#pragma unroll
        for (int d4 = 0; d4 < 16; ++d4) {
            fx4 qv[4], kv[4];
#pragma unroll
            for (int i = 0; i < 4; ++i) qv[i] = *(const fx4*)&Qs[4 * qg + i][4 * d4];
#pragma unroll
            for (int c = 0; c < 4; ++c) kv[c] = *(const fx4*)&KPs[kg + 16 * c][4 * d4];
#pragma unroll
            for (int i = 0; i < 4; ++i)
#pragma unroll
                for (int c = 0; c < 4; ++c)
                    s[i][c] += qv[i][0] * kv[c][0] + qv[i][1] * kv[c][1]
                             + qv[i][2] * kv[c][2] + qv[i][3] * kv[c][3];
        }

        // online softmax update (row state per 16-lane group)
        float ps[4][4];
#pragma unroll
        for (int i = 0; i < 4; ++i) {
            float mm = fmaxf(fmaxf(s[i][0], s[i][1]), fmaxf(s[i][2], s[i][3]));
            mm = fmaxf(mm, __shfl_xor(mm, 1, 64));
            mm = fmaxf(mm, __shfl_xor(mm, 2, 64));
            mm = fmaxf(mm, __shfl_xor(mm, 4, 64));
            mm = fmaxf(mm, __shfl_xor(mm, 8, 64));
            float mn   = fmaxf(m_run[i], mm);
            float corr = __expf(m_run[i] - mn);
            m_run[i] = mn;
            float ls = 0.f;
#pragma unroll
            for (int c = 0; c < 4; ++c) { ps[i][c] = __expf(s[i][c] - mn); ls += ps[i][c]; }
            ls += __shfl_xor(ls, 1, 64);
            ls += __shfl_xor(ls, 2, 64);
            ls += __shfl_xor(ls, 4, 64);
            ls += __shfl_xor(ls, 8, 64);
            l_run[i] = l_run[i] * corr + ls;
#pragma unroll
            for (int j = 0; j < 4; ++j) acc[i][j] *= corr;
        }
        __syncthreads();   // all K reads done -> safe to overwrite with P
#pragma unroll
        for (int i = 0; i < 4; ++i)
#pragma unroll
            for (int c = 0; c < 4; ++c) KPs[4 * qg + i][kg + 16 * c] = ps[i][c];
        __syncthreads();   // P visible

        // PV: acc[i][j] += sum_k P[4qg+i][k] * V[k][4kg+j]
#pragma unroll
        for (int kk4 = 0; kk4 < 16; ++kk4) {
            fx4 pv[4];
#pragma unroll
            for (int i = 0; i < 4; ++i) pv[i] = *(const fx4*)&KPs[4 * qg + i][4 * kk4];
#pragma unroll
            for (int kin = 0; kin < 4; ++kin) {
                fx4 vv = *(const fx4*)&Vs[4 * kk4 + kin][4 * kg];
#pragma unroll
                for (int i = 0; i < 4; ++i) {
                    float p = pv[i][kin];
#pragma unroll
                    for (int j = 0; j < 4; ++j) acc[i][j] += p * vv[j];
                }
            }
        }
    }

    float* cp0 = ctx + ((size_t)(b * SEQ + qt * 64)) * HDIM + h * HD;
#pragma unroll
    for (int i = 0; i < 4; ++i) {
        float inv = 1.0f / l_run[i];
        fx4 o;
#pragma unroll
        for (int j = 0; j < 4; ++j) o[j] = acc[i][j] * inv;
        *(fx4*)(cp0 + (size_t)(4 * qg + i) * HDIM + 4 * kg) = o;
    }
}

// ---------------------------------------------------------------------------
extern "C" void kernel_launch(void* const* d_in, const int* in_sizes, int n_in,
                              void* d_out, int out_size, void* d_ws, size_t ws_size,
                              hipStream_t stream)
{
    const float* hs   = (const float*)d_in[0];
    const float* mask = (const float*)d_in[1];
    const float* Wq = (const float*)d_in[2];
    const float* Wk = (const float*)d_in[3];
    const float* Wv = (const float*)d_in[4];
    const float* Wo = (const float*)d_in[5];
    const float* Aq = (const float*)d_in[6];
    const float* Bq = (const float*)d_in[7];
    const float* Ak = (const float*)d_in[8];
    const float* Bk = (const float*)d_in[9];
    const float* Av = (const float*)d_in[10];
    const float* Bv = (const float*)d_in[11];
    const float* Ao = (const float*)d_in[12];
    const float* Bo = (const float*)d_in[13];
    float* out = (float*)d_out;

    float* ws = (float*)d_ws;
    const size_t MH = (size_t)MTOT * HDIM;   // 4M floats
    float* qb   = ws;
    float* kb   = ws + MH;
    float* vb   = ws + 2 * MH;
    float* ctx  = ws + 3 * MH;
    float* hsA  = ws + 4 * MH;               // [4096, 24]
    float* ctxA = hsA + (size_t)MTOT * 24;   // [4096, 24] (8 used)

    lora_down_kernel<<<MTOT, 64, 0, stream>>>(hs, Aq, Ak, Av, hsA, 3);
    gemm_lora3_kernel<<<dim3(8, 32, 3), 256, 0, stream>>>(
        hs, Wq, Wk, Wv, hsA, Bq, Bk, Bv, qb, kb, vb, 24);
    attn_kernel<<<dim3(SEQ / 64, NHEAD, BATCH), 256, 0, stream>>>(
        qb, kb, vb, mask, ctx);
    lora_down_kernel<<<MTOT, 64, 0, stream>>>(ctx, Ao, Ao, Ao, ctxA, 1);
    gemm_lora3_kernel<<<dim3(8, 32, 1), 256, 0, stream>>>(
        ctx, Wo, Wo, Wo, ctxA, Bo, Bo, Bo, out, out, out, 24);
}

// Round 2
// 608.084 us; speedup vs baseline: 1.7249x; 1.7249x over previous
//
#include <hip/hip_runtime.h>
#include <math.h>

typedef float fx4 __attribute__((ext_vector_type(4)));
typedef float f32x4 __attribute__((ext_vector_type(4)));
typedef short bf16x8 __attribute__((ext_vector_type(8)));

#define HDIM 1024
#define SEQ  2048
#define BATCH 2
#define NHEAD 16
#define HD    64
#define MTOT  4096   // BATCH*SEQ
#define LSCALE 8.0f  // lora_alpha / lora_rank

__device__ __forceinline__ unsigned short f2bf(float f) {
    union { float f; unsigned int u; } v; v.f = f;
    unsigned int r = v.u + 0x7FFFu + ((v.u >> 16) & 1u);
    return (unsigned short)(r >> 16);
}

// ---------------------------------------------------------------------------
// K1: XA = X @ [A0|A1|A2]  (each A is [1024,8]); out row-stride 24.
// ---------------------------------------------------------------------------
__global__ __launch_bounds__(64)
void lora_down_kernel(const float* __restrict__ X,
                      const float* __restrict__ A0,
                      const float* __restrict__ A1,
                      const float* __restrict__ A2,
                      float* __restrict__ out, int nmat)
{
    int row  = blockIdx.x;
    int lane = threadIdx.x;
    const float* xr = X + (size_t)row * HDIM;
    float xv[16];
#pragma unroll
    for (int i = 0; i < 16; ++i) xv[i] = xr[lane + 64 * i];
    const float* Amats[3] = {A0, A1, A2};
    for (int m = 0; m < nmat; ++m) {
        const float* A = Amats[m];
        float s[8];
#pragma unroll
        for (int c = 0; c < 8; ++c) s[c] = 0.f;
#pragma unroll
        for (int i = 0; i < 16; ++i) {
            const float* ap = A + (size_t)(lane + 64 * i) * 8;
#pragma unroll
            for (int c = 0; c < 8; ++c) s[c] += xv[i] * ap[c];
        }
#pragma unroll
        for (int c = 0; c < 8; ++c) {
#pragma unroll
            for (int off = 1; off < 64; off <<= 1)
                s[c] += __shfl_xor(s[c], off, 64);
        }
        if (lane == 0) {
#pragma unroll
            for (int c = 0; c < 8; ++c)
                out[(size_t)row * 24 + m * 8 + c] = s[c];
        }
    }
}

// ---------------------------------------------------------------------------
// K2: Out = X @ W + LSCALE * (XA) @ Bm   for up to 3 projections (blockIdx.z).
// ---------------------------------------------------------------------------
__global__ __launch_bounds__(256, 2)
void gemm_lora3_kernel(const float* __restrict__ X,
                       const float* __restrict__ W0, const float* __restrict__ W1, const float* __restrict__ W2,
                       const float* __restrict__ XA,
                       const float* __restrict__ B0, const float* __restrict__ B1, const float* __restrict__ B2,
                       float* __restrict__ Out0, float* __restrict__ Out1, float* __restrict__ Out2,
                       int xa_stride)
{
    const int K = HDIM, N = HDIM;
    int pz = blockIdx.z;
    const float* W  = (pz == 0) ? W0 : (pz == 1) ? W1 : W2;
    const float* Bm = (pz == 0) ? B0 : (pz == 1) ? B1 : B2;
    float* Out      = (pz == 0) ? Out0 : (pz == 1) ? Out1 : Out2;
    int xa_off = pz * 8;

    int brow = blockIdx.y * 128;
    int bcol = blockIdx.x * 128;
    int t  = threadIdx.x;
    int tx = t & 15;
    int ty = t >> 4;

    __shared__ __align__(16) float As[8][128];
    __shared__ __align__(16) float Bs[8][128];

    float acc[8][8];
#pragma unroll
    for (int i = 0; i < 8; ++i)
#pragma unroll
        for (int j = 0; j < 8; ++j) acc[i][j] = 0.f;

    int arow = t >> 1;
    int acol = (t & 1) * 4;
    const float* xp = X + (size_t)(brow + arow) * K + acol;
    int bkr = t >> 5;
    int bnc = (t & 31) * 4;
    const float* wp = W + (size_t)bkr * N + bcol + bnc;

    fx4 av = *(const fx4*)xp;
    fx4 bv = *(const fx4*)wp;

    for (int k0 = 0; k0 < K; k0 += 8) {
        __syncthreads();
        As[acol + 0][arow] = av[0];
        As[acol + 1][arow] = av[1];
        As[acol + 2][arow] = av[2];
        As[acol + 3][arow] = av[3];
        *(fx4*)&Bs[bkr][bnc] = bv;
        __syncthreads();
        if (k0 + 8 < K) {
            av = *(const fx4*)(xp + k0 + 8);
            bv = *(const fx4*)(wp + (size_t)(k0 + 8) * N);
        }
#pragma unroll
        for (int k = 0; k < 8; ++k) {
            fx4 a0 = *(const fx4*)&As[k][ty * 8];
            fx4 a1 = *(const fx4*)&As[k][ty * 8 + 4];
            fx4 b0 = *(const fx4*)&Bs[k][tx * 8];
            fx4 b1 = *(const fx4*)&Bs[k][tx * 8 + 4];
#pragma unroll
            for (int i = 0; i < 4; ++i)
#pragma unroll
                for (int j = 0; j < 4; ++j) {
                    acc[i][j]         += a0[i] * b0[j];
                    acc[i][j + 4]     += a0[i] * b1[j];
                    acc[i + 4][j]     += a1[i] * b0[j];
                    acc[i + 4][j + 4] += a1[i] * b1[j];
                }
        }
    }

    float lb[8][8];
#pragma unroll
    for (int r = 0; r < 8; ++r) {
        fx4 c0 = *(const fx4*)&Bm[(size_t)r * N + bcol + tx * 8];
        fx4 c1 = *(const fx4*)&Bm[(size_t)r * N + bcol + tx * 8 + 4];
#pragma unroll
        for (int j = 0; j < 4; ++j) { lb[r][j] = c0[j]; lb[r][j + 4] = c1[j]; }
    }
#pragma unroll
    for (int i = 0; i < 8; ++i) {
        int row = brow + ty * 8 + i;
        const float* lap = XA + (size_t)row * xa_stride + xa_off;
        float la[8];
#pragma unroll
        for (int r = 0; r < 8; ++r) la[r] = lap[r] * LSCALE;
        float* op = Out + (size_t)row * N + bcol + tx * 8;
        fx4 o0, o1;
#pragma unroll
        for (int j = 0; j < 8; ++j) {
            float sum = acc[i][j];
#pragma unroll
            for (int r = 0; r < 8; ++r) sum += la[r] * lb[r][j];
            if (j < 4) o0[j] = sum; else o1[j - 4] = sum;
        }
        *(fx4*)op       = o0;
        *(fx4*)(op + 4) = o1;
    }
}

// ---------------------------------------------------------------------------
// K3: flash attention, bf16 MFMA (16x16x32), fp32 softmax/accum.
// Block = 4 waves, owns (b, h, 128 q-rows); wave owns 32 q-rows.
// KV tile = 64 rows. K row-major bf16 LDS; V transposed bf16 LDS (Vt[d][k]);
// stride 72 keeps ds_read_b128 16B-aligned and rotates banks by 4/row.
// P goes through wave-private LDS tile (D-layout -> A-layout).
// MFMA layouts (gfx950 16x16x32): A row=lane&15, k=8*(lane>>4)+j;
// B col=lane&15, k=8*(lane>>4)+j; D col=lane&15, row=4*(lane>>4)+reg.
// ---------------------------------------------------------------------------
#define QBLK 128
#define WQ   32
#define KVB  64

__global__ __launch_bounds__(256, 2)
void attn_mfma_kernel(const float* __restrict__ Qg, const float* __restrict__ Kg,
                      const float* __restrict__ Vg, const float* __restrict__ mask,
                      float* __restrict__ ctx)
{
    int qt = blockIdx.x, h = blockIdx.y, b = blockIdx.z;
    int t    = threadIdx.x;
    int wid  = t >> 6;
    int lane = t & 63;
    int l15  = lane & 15;
    int g    = lane >> 4;

    __shared__ __align__(16) unsigned short Ks[64][72];
    __shared__ __align__(16) unsigned short Vt[64][72];
    __shared__ __align__(16) unsigned short Ps[4][32][72];
    __shared__ float Ms[64];

    // Q fragments in registers (A layout), fold 1/sqrt(64)=0.125
    bf16x8 qa[2][2];
    const float* qp = Qg + ((size_t)(b * SEQ + qt * QBLK + wid * WQ)) * HDIM + h * HD;
#pragma unroll
    for (int m = 0; m < 2; ++m)
#pragma unroll
        for (int kc = 0; kc < 2; ++kc) {
            const float* p = qp + (size_t)(16 * m + l15) * HDIM + 32 * kc + 8 * g;
            fx4 f0 = *(const fx4*)p;
            fx4 f1 = *(const fx4*)(p + 4);
            bf16x8 a;
#pragma unroll
            for (int j = 0; j < 4; ++j) {
                a[j]     = (short)f2bf(f0[j] * 0.125f);
                a[4 + j] = (short)f2bf(f1[j] * 0.125f);
            }
            qa[m][kc] = a;
        }

    float m_run[2][4], l_run[2][4];
    f32x4 acc[2][4];
#pragma unroll
    for (int m = 0; m < 2; ++m)
#pragma unroll
        for (int r = 0; r < 4; ++r) { m_run[m][r] = -1e30f; l_run[m][r] = 0.f; }
#pragma unroll
    for (int m = 0; m < 2; ++m)
#pragma unroll
        for (int n = 0; n < 4; ++n) acc[m][n] = (f32x4){0.f, 0.f, 0.f, 0.f};

    const float* kp0 = Kg + ((size_t)(b * SEQ)) * HDIM + h * HD;
    const float* vp0 = Vg + ((size_t)(b * SEQ)) * HDIM + h * HD;

    for (int kt = 0; kt < SEQ / KVB; ++kt) {
        const float* kp = kp0 + (size_t)kt * KVB * HDIM;
        const float* vp = vp0 + (size_t)kt * KVB * HDIM;
        __syncthreads();   // all waves done reading prev K/V tiles
#pragma unroll
        for (int i = 0; i < 4; ++i) {
            int idx = t + 256 * i;
            int r = idx >> 4;
            int c = (idx & 15) * 4;
            fx4 kv = *(const fx4*)(kp + (size_t)r * HDIM + c);
            fx4 vv = *(const fx4*)(vp + (size_t)r * HDIM + c);
            unsigned int p0 = (unsigned int)f2bf(kv[0]) | ((unsigned int)f2bf(kv[1]) << 16);
            unsigned int p1 = (unsigned int)f2bf(kv[2]) | ((unsigned int)f2bf(kv[3]) << 16);
            *(unsigned int*)&Ks[r][c]     = p0;
            *(unsigned int*)&Ks[r][c + 2] = p1;
            Vt[c + 0][r] = f2bf(vv[0]);
            Vt[c + 1][r] = f2bf(vv[1]);
            Vt[c + 2][r] = f2bf(vv[2]);
            Vt[c + 3][r] = f2bf(vv[3]);
        }
        if (t < 64) Ms[t] = (1.0f - mask[b * SEQ + kt * KVB + t]) * -10000.0f;
        __syncthreads();

        // ---- QK^T ----
        bf16x8 kb[4][2];
#pragma unroll
        for (int n = 0; n < 4; ++n)
#pragma unroll
            for (int kc = 0; kc < 2; ++kc)
                kb[n][kc] = *(const bf16x8*)&Ks[16 * n + l15][32 * kc + 8 * g];

        f32x4 s[2][4];
#pragma unroll
        for (int m = 0; m < 2; ++m)
#pragma unroll
            for (int n = 0; n < 4; ++n) {
                f32x4 a = (f32x4){0.f, 0.f, 0.f, 0.f};
#pragma unroll
                for (int kc = 0; kc < 2; ++kc)
                    a = __builtin_amdgcn_mfma_f32_16x16x32_bf16(qa[m][kc], kb[n][kc], a, 0, 0, 0);
                s[m][n] = a;
            }

        float msk[4];
#pragma unroll
        for (int n = 0; n < 4; ++n) msk[n] = Ms[16 * n + l15];

        // ---- online softmax (rows 16m + 4g + r) ----
#pragma unroll
        for (int m = 0; m < 2; ++m) {
#pragma unroll
            for (int n = 0; n < 4; ++n)
#pragma unroll
                for (int r = 0; r < 4; ++r) s[m][n][r] += msk[n];
            float mx[4];
#pragma unroll
            for (int r = 0; r < 4; ++r)
                mx[r] = fmaxf(fmaxf(s[m][0][r], s[m][1][r]), fmaxf(s[m][2][r], s[m][3][r]));
#pragma unroll
            for (int off = 1; off < 16; off <<= 1)
#pragma unroll
                for (int r = 0; r < 4; ++r) mx[r] = fmaxf(mx[r], __shfl_xor(mx[r], off, 64));
            float corr[4];
#pragma unroll
            for (int r = 0; r < 4; ++r) {
                float mn = fmaxf(m_run[m][r], mx[r]);
                corr[r] = __expf(m_run[m][r] - mn);
                m_run[m][r] = mn;
            }
            float ls[4] = {0.f, 0.f, 0.f, 0.f};
#pragma unroll
            for (int n = 0; n < 4; ++n)
#pragma unroll
                for (int r = 0; r < 4; ++r) {
                    float p = __expf(s[m][n][r] - m_run[m][r]);
                    s[m][n][r] = p;
                    ls[r] += p;
                }
#pragma unroll
            for (int off = 1; off < 16; off <<= 1)
#pragma unroll
                for (int r = 0; r < 4; ++r) ls[r] += __shfl_xor(ls[r], off, 64);
#pragma unroll
            for (int r = 0; r < 4; ++r) l_run[m][r] = l_run[m][r] * corr[r] + ls[r];
#pragma unroll
            for (int n = 0; n < 4; ++n)
#pragma unroll
                for (int r = 0; r < 4; ++r) acc[m][n][r] *= corr[r];
            // P: D-layout (row 16m+4g+r, col 16n+l15) -> wave-private LDS
#pragma unroll
            for (int n = 0; n < 4; ++n)
#pragma unroll
                for (int r = 0; r < 4; ++r)
                    Ps[wid][16 * m + 4 * g + r][16 * n + l15] = f2bf(s[m][n][r]);
        }

        // ---- PV ----
        bf16x8 vb[4][2];
#pragma unroll
        for (int n = 0; n < 4; ++n)
#pragma unroll
            for (int kc = 0; kc < 2; ++kc)
                vb[n][kc] = *(const bf16x8*)&Vt[16 * n + l15][32 * kc + 8 * g];
        bf16x8 pa[2][2];
#pragma unroll
        for (int m = 0; m < 2; ++m)
#pragma unroll
            for (int kc = 0; kc < 2; ++kc)
                pa[m][kc] = *(const bf16x8*)&Ps[wid][16 * m + l15][32 * kc + 8 * g];
#pragma unroll
        for (int m = 0; m < 2; ++m)
#pragma unroll
            for (int n = 0; n < 4; ++n)
#pragma unroll
                for (int kc = 0; kc < 2; ++kc)
                    acc[m][n] = __builtin_amdgcn_mfma_f32_16x16x32_bf16(pa[m][kc], vb[n][kc], acc[m][n], 0, 0, 0);
    }

    float* cp = ctx + ((size_t)(b * SEQ + qt * QBLK + wid * WQ)) * HDIM + h * HD;
#pragma unroll
    for (int m = 0; m < 2; ++m)
#pragma unroll
        for (int r = 0; r < 4; ++r) {
            float inv = 1.0f / l_run[m][r];
#pragma unroll
            for (int n = 0; n < 4; ++n)
                cp[(size_t)(16 * m + 4 * g + r) * HDIM + 16 * n + l15] = acc[m][n][r] * inv;
        }
}

// ---------------------------------------------------------------------------
extern "C" void kernel_launch(void* const* d_in, const int* in_sizes, int n_in,
                              void* d_out, int out_size, void* d_ws, size_t ws_size,
                              hipStream_t stream)
{
    const float* hs   = (const float*)d_in[0];
    const float* mask = (const float*)d_in[1];
    const float* Wq = (const float*)d_in[2];
    const float* Wk = (const float*)d_in[3];
    const float* Wv = (const float*)d_in[4];
    const float* Wo = (const float*)d_in[5];
    const float* Aq = (const float*)d_in[6];
    const float* Bq = (const float*)d_in[7];
    const float* Ak = (const float*)d_in[8];
    const float* Bk = (const float*)d_in[9];
    const float* Av = (const float*)d_in[10];
    const float* Bv = (const float*)d_in[11];
    const float* Ao = (const float*)d_in[12];
    const float* Bo = (const float*)d_in[13];
    float* out = (float*)d_out;

    float* ws = (float*)d_ws;
    const size_t MH = (size_t)MTOT * HDIM;
    float* qb   = ws;
    float* kb   = ws + MH;
    float* vb   = ws + 2 * MH;
    float* ctx  = ws + 3 * MH;
    float* hsA  = ws + 4 * MH;               // [4096, 24]
    float* ctxA = hsA + (size_t)MTOT * 24;   // [4096, 24] (8 used)

    lora_down_kernel<<<MTOT, 64, 0, stream>>>(hs, Aq, Ak, Av, hsA, 3);
    gemm_lora3_kernel<<<dim3(8, 32, 3), 256, 0, stream>>>(
        hs, Wq, Wk, Wv, hsA, Bq, Bk, Bv, qb, kb, vb, 24);
    attn_mfma_kernel<<<dim3(SEQ / QBLK, NHEAD, BATCH), 256, 0, stream>>>(
        qb, kb, vb, mask, ctx);
    lora_down_kernel<<<MTOT, 64, 0, stream>>>(ctx, Ao, Ao, Ao, ctxA, 1);
    gemm_lora3_kernel<<<dim3(8, 32, 1), 256, 0, stream>>>(
        ctx, Wo, Wo, Wo, ctxA, Bo, Bo, Bo, out, out, out, 24);
}

// Round 4
// 286.765 us; speedup vs baseline: 3.6576x; 2.1205x over previous
//
#include <hip/hip_runtime.h>
#include <math.h>

typedef float fx4 __attribute__((ext_vector_type(4)));
typedef float f32x4 __attribute__((ext_vector_type(4)));
typedef short bf16x8 __attribute__((ext_vector_type(8)));
typedef unsigned short us4 __attribute__((ext_vector_type(4)));
typedef unsigned short us8 __attribute__((ext_vector_type(8)));

#define HDIM 1024
#define SEQ  2048
#define BATCH 2
#define NHEAD 16
#define HD    64
#define MTOT  4096
#define LSCALE 8.0f

__device__ __forceinline__ unsigned short f2bf(float f) {
    union { float f; unsigned int u; } v; v.f = f;
    unsigned int r = v.u + 0x7FFFu + ((v.u >> 16) & 1u);
    return (unsigned short)(r >> 16);
}
__device__ __forceinline__ float bf2f(unsigned short h) {
    union { unsigned int u; float f; } v; v.u = ((unsigned int)h) << 16;
    return v.f;
}

// ---------------------------------------------------------------------------
// split X (fp32) -> hi/lo bf16 planes
// ---------------------------------------------------------------------------
__global__ __launch_bounds__(256)
void split_x_kernel(const float* __restrict__ X, unsigned short* __restrict__ Xh,
                    unsigned short* __restrict__ Xl, int n4)
{
    int i = blockIdx.x * 256 + threadIdx.x;
    int stride = gridDim.x * 256;
    for (; i < n4; i += stride) {
        fx4 v = *((const fx4*)X + i);
        us4 h, l;
#pragma unroll
        for (int j = 0; j < 4; ++j) {
            h[j] = f2bf(v[j]);
            l[j] = f2bf(v[j] - bf2f(h[j]));
        }
        *((us4*)Xh + i) = h;
        *((us4*)Xl + i) = l;
    }
}

// ---------------------------------------------------------------------------
// transpose + split W [k][n] fp32 -> WT hi/lo bf16 [n][k]; z selects matrix.
// ---------------------------------------------------------------------------
__global__ __launch_bounds__(256)
void tsplit_w_kernel(const float* __restrict__ W0, const float* __restrict__ W1,
                     const float* __restrict__ W2, const float* __restrict__ W3,
                     unsigned short* __restrict__ WTbase)
{
    int z = blockIdx.z;
    const float* W = (z == 0) ? W0 : (z == 1) ? W1 : (z == 2) ? W2 : W3;
    unsigned short* WTh = WTbase + (size_t)z * 2097152;
    unsigned short* WTl = WTh + 1048576;
    int n0 = blockIdx.x * 64, k0 = blockIdx.y * 64;
    __shared__ unsigned int T[64][65];
    int t = threadIdx.x;
#pragma unroll
    for (int i = 0; i < 4; ++i) {
        int idx = t + 256 * i;
        int r = idx >> 4, c4 = (idx & 15) * 4;
        fx4 w = *(const fx4*)&W[(size_t)(k0 + r) * HDIM + n0 + c4];
#pragma unroll
        for (int j = 0; j < 4; ++j) {
            unsigned short hi = f2bf(w[j]);
            unsigned short lo = f2bf(w[j] - bf2f(hi));
            T[r][c4 + j] = (unsigned int)hi | ((unsigned int)lo << 16);
        }
    }
    __syncthreads();
#pragma unroll
    for (int i = 0; i < 4; ++i) {
        int idx = t + 256 * i;
        int n = idx >> 4, kg = (idx & 15) * 4;
        us4 hv, lv;
#pragma unroll
        for (int j = 0; j < 4; ++j) {
            unsigned int p = T[kg + j][n];
            hv[j] = (unsigned short)(p & 0xffffu);
            lv[j] = (unsigned short)(p >> 16);
        }
        *(us4*)&WTh[(size_t)(n0 + n) * HDIM + k0 + kg] = hv;
        *(us4*)&WTl[(size_t)(n0 + n) * HDIM + k0 + kg] = lv;
    }
}

// ---------------------------------------------------------------------------
// transpose V: vb [4096][1024] bf16 -> vt [(b*16+h)*64+d][2048] bf16
// ---------------------------------------------------------------------------
__global__ __launch_bounds__(256)
void transpose_v_kernel(const unsigned short* __restrict__ vb,
                        unsigned short* __restrict__ vt)
{
    int s0 = blockIdx.x * 64;
    int bh = blockIdx.y;               // b*16+h
    int b = bh >> 4, h = bh & 15;
    __shared__ unsigned short T[64][80];
    int t = threadIdx.x;
#pragma unroll
    for (int i = 0; i < 2; ++i) {
        int u = t + 256 * i;
        int r = u >> 3, cg = u & 7;
        us8 v = *(const us8*)&vb[(size_t)(b * SEQ + s0 + r) * HDIM + h * HD + 8 * cg];
        *(us8*)&T[r][8 * cg] = v;
    }
    __syncthreads();
#pragma unroll
    for (int i = 0; i < 2; ++i) {
        int u = t + 256 * i;
        int d = u & 63, sg = u >> 6;
        us8 v;
#pragma unroll
        for (int j = 0; j < 8; ++j) v[j] = T[8 * sg + j][d];
        *(us8*)&vt[(size_t)(bh * HD + d) * SEQ + s0 + 8 * sg] = v;
    }
}

// ---------------------------------------------------------------------------
// lora down: fp32 X; XA = X @ [A0|A1|A2]; out row stride 24
// ---------------------------------------------------------------------------
__global__ __launch_bounds__(64)
void lora_down_kernel(const float* __restrict__ X,
                      const float* __restrict__ A0,
                      const float* __restrict__ A1,
                      const float* __restrict__ A2,
                      float* __restrict__ out, int nmat)
{
    int row  = blockIdx.x;
    int lane = threadIdx.x;
    const float* xr = X + (size_t)row * HDIM;
    float xv[16];
#pragma unroll
    for (int i = 0; i < 16; ++i) xv[i] = xr[lane + 64 * i];
    const float* Amats[3] = {A0, A1, A2};
    for (int m = 0; m < nmat; ++m) {
        const float* A = Amats[m];
        float s[8];
#pragma unroll
        for (int c = 0; c < 8; ++c) s[c] = 0.f;
#pragma unroll
        for (int i = 0; i < 16; ++i) {
            const float* ap = A + (size_t)(lane + 64 * i) * 8;
#pragma unroll
            for (int c = 0; c < 8; ++c) s[c] += xv[i] * ap[c];
        }
#pragma unroll
        for (int c = 0; c < 8; ++c) {
#pragma unroll
            for (int off = 1; off < 64; off <<= 1)
                s[c] += __shfl_xor(s[c], off, 64);
        }
        if (lane == 0) {
#pragma unroll
            for (int c = 0; c < 8; ++c)
                out[(size_t)row * 24 + m * 8 + c] = s[c];
        }
    }
}

// lora down from hi/lo bf16 planes (ctx); out stride 8
__global__ __launch_bounds__(64)
void lora_down_bf_kernel(const unsigned short* __restrict__ Xh,
                         const unsigned short* __restrict__ Xl,
                         const float* __restrict__ A,
                         float* __restrict__ out)
{
    int row  = blockIdx.x;
    int lane = threadIdx.x;
    const unsigned short* xh = Xh + (size_t)row * HDIM;
    const unsigned short* xl = Xl + (size_t)row * HDIM;
    float xv[16];
#pragma unroll
    for (int i = 0; i < 16; ++i)
        xv[i] = bf2f(xh[lane + 64 * i]) + bf2f(xl[lane + 64 * i]);
    float s[8];
#pragma unroll
    for (int c = 0; c < 8; ++c) s[c] = 0.f;
#pragma unroll
    for (int i = 0; i < 16; ++i) {
        const float* ap = A + (size_t)(lane + 64 * i) * 8;
#pragma unroll
        for (int c = 0; c < 8; ++c) s[c] += xv[i] * ap[c];
    }
#pragma unroll
    for (int c = 0; c < 8; ++c) {
#pragma unroll
        for (int off = 1; off < 64; off <<= 1)
            s[c] += __shfl_xor(s[c], off, 64);
    }
    if (lane == 0) {
#pragma unroll
        for (int c = 0; c < 8; ++c) out[(size_t)row * 8 + c] = s[c];
    }
}

// ---------------------------------------------------------------------------
// split-bf16 MFMA GEMM: Out = X@W + LSCALE*(XA)@Bu
// X from hi/lo planes [M][1024]; W from WT hi/lo planes [n][k].
// 128x128 tile, BK=32, 4 waves (2x2), 3 MFMA per fragment (hh, hl, lh).
// ---------------------------------------------------------------------------
template<bool OUTF32>
__global__ __launch_bounds__(256, 2)
void gemm_mfma_kernel(const unsigned short* __restrict__ Xh, const unsigned short* __restrict__ Xl,
                      const unsigned short* __restrict__ WTbase, int wsel0,
                      const float* __restrict__ XA, int xa_stride, int xa_off0,
                      const float* __restrict__ Bu0, const float* __restrict__ Bu1, const float* __restrict__ Bu2,
                      void* __restrict__ O0, void* __restrict__ O1, void* __restrict__ O2)
{
    int pz = blockIdx.z;
    const unsigned short* WTh = WTbase + (size_t)(wsel0 + pz) * 2097152;
    const unsigned short* WTl = WTh + 1048576;
    const float* Bu = (pz == 0) ? Bu0 : (pz == 1) ? Bu1 : Bu2;
    void* Ovp       = (pz == 0) ? O0 : (pz == 1) ? O1 : O2;
    int xa_off = xa_off0 + pz * 8;

    int brow = blockIdx.y * 128, bcol = blockIdx.x * 128;
    int t = threadIdx.x, wid = t >> 6, lane = t & 63, l15 = lane & 15, g = lane >> 4;
    int wm = (wid >> 1) * 64, wn = (wid & 1) * 64;

    __shared__ unsigned short Ah[128][40];
    __shared__ unsigned short Al[128][40];
    __shared__ unsigned short Bh[128][40];
    __shared__ unsigned short Bl[128][40];

    f32x4 acc[4][4];
#pragma unroll
    for (int i = 0; i < 4; ++i)
#pragma unroll
        for (int j = 0; j < 4; ++j) acc[i][j] = (f32x4){0.f, 0.f, 0.f, 0.f};

    int sm = t >> 2, skg = t & 3;
    const unsigned short* aH0 = Xh  + (size_t)(brow + sm) * HDIM + 8 * skg;
    const unsigned short* aL0 = Xl  + (size_t)(brow + sm) * HDIM + 8 * skg;
    const unsigned short* bH0 = WTh + (size_t)(bcol + sm) * HDIM + 8 * skg;
    const unsigned short* bL0 = WTl + (size_t)(bcol + sm) * HDIM + 8 * skg;
    const size_t R64 = (size_t)64 * HDIM;

    us8 rAH0 = *(const us8*)(aH0);
    us8 rAH1 = *(const us8*)(aH0 + R64);
    us8 rAL0 = *(const us8*)(aL0);
    us8 rAL1 = *(const us8*)(aL0 + R64);
    us8 rBH0 = *(const us8*)(bH0);
    us8 rBH1 = *(const us8*)(bH0 + R64);
    us8 rBL0 = *(const us8*)(bL0);
    us8 rBL1 = *(const us8*)(bL0 + R64);

    for (int k0 = 0; k0 < HDIM; k0 += 32) {
        __syncthreads();
        *(us8*)&Ah[sm][8 * skg]      = rAH0;
        *(us8*)&Ah[sm + 64][8 * skg] = rAH1;
        *(us8*)&Al[sm][8 * skg]      = rAL0;
        *(us8*)&Al[sm + 64][8 * skg] = rAL1;
        *(us8*)&Bh[sm][8 * skg]      = rBH0;
        *(us8*)&Bh[sm + 64][8 * skg] = rBH1;
        *(us8*)&Bl[sm][8 * skg]      = rBL0;
        *(us8*)&Bl[sm + 64][8 * skg] = rBL1;
        __syncthreads();
        if (k0 + 32 < HDIM) {
            int ko = k0 + 32;
            rAH0 = *(const us8*)(aH0 + ko);
            rAH1 = *(const us8*)(aH0 + R64 + ko);
            rAL0 = *(const us8*)(aL0 + ko);
            rAL1 = *(const us8*)(aL0 + R64 + ko);
            rBH0 = *(const us8*)(bH0 + ko);
            rBH1 = *(const us8*)(bH0 + R64 + ko);
            rBL0 = *(const us8*)(bL0 + ko);
            rBL1 = *(const us8*)(bL0 + R64 + ko);
        }
        bf16x8 fah[4], fal[4], fbh[4], fbl[4];
#pragma unroll
        for (int f = 0; f < 4; ++f) {
            fah[f] = *(const bf16x8*)&Ah[wm + 16 * f + l15][8 * g];
            fal[f] = *(const bf16x8*)&Al[wm + 16 * f + l15][8 * g];
            fbh[f] = *(const bf16x8*)&Bh[wn + 16 * f + l15][8 * g];
            fbl[f] = *(const bf16x8*)&Bl[wn + 16 * f + l15][8 * g];
        }
#pragma unroll
        for (int fm = 0; fm < 4; ++fm)
#pragma unroll
            for (int fn = 0; fn < 4; ++fn) {
                f32x4 a = acc[fm][fn];
                a = __builtin_amdgcn_mfma_f32_16x16x32_bf16(fah[fm], fbh[fn], a, 0, 0, 0);
                a = __builtin_amdgcn_mfma_f32_16x16x32_bf16(fah[fm], fbl[fn], a, 0, 0, 0);
                a = __builtin_amdgcn_mfma_f32_16x16x32_bf16(fal[fm], fbh[fn], a, 0, 0, 0);
                acc[fm][fn] = a;
            }
    }

    // LoRA epilogue + store
    float lb[8][4];
#pragma unroll
    for (int rr = 0; rr < 8; ++rr)
#pragma unroll
        for (int fn = 0; fn < 4; ++fn)
            lb[rr][fn] = Bu[(size_t)rr * HDIM + bcol + wn + 16 * fn + l15] * LSCALE;

#pragma unroll
    for (int fm = 0; fm < 4; ++fm) {
        float la[4][8];
#pragma unroll
        for (int r = 0; r < 4; ++r) {
            int row = brow + wm + 16 * fm + 4 * g + r;
            const float* lap = XA + (size_t)row * xa_stride + xa_off;
            fx4 q0 = *(const fx4*)lap;
            fx4 q1 = *(const fx4*)(lap + 4);
#pragma unroll
            for (int j = 0; j < 4; ++j) { la[r][j] = q0[j]; la[r][4 + j] = q1[j]; }
        }
#pragma unroll
        for (int fn = 0; fn < 4; ++fn)
#pragma unroll
            for (int r = 0; r < 4; ++r) {
                float sum = acc[fm][fn][r];
#pragma unroll
                for (int rr = 0; rr < 8; ++rr) sum += la[r][rr] * lb[rr][fn];
                size_t row = (size_t)(brow + wm + 16 * fm + 4 * g + r);
                int col = bcol + wn + 16 * fn + l15;
                if (OUTF32) ((float*)Ovp)[row * HDIM + col] = sum;
                else ((unsigned short*)Ovp)[row * HDIM + col] = f2bf(sum);
            }
    }
}

// ---------------------------------------------------------------------------
// flash attention, bf16 in (Q,K row-major; V pre-transposed), hi/lo bf16 out
// ---------------------------------------------------------------------------
#define QBLK 128
#define KVB  64

__global__ __launch_bounds__(256, 2)
void attn_mfma_kernel(const unsigned short* __restrict__ Qg, const unsigned short* __restrict__ Kg,
                      const unsigned short* __restrict__ Vt, const float* __restrict__ mask,
                      unsigned short* __restrict__ Ch, unsigned short* __restrict__ Cl)
{
    int qt = blockIdx.x, h = blockIdx.y, b = blockIdx.z;
    int t    = threadIdx.x;
    int wid  = t >> 6;
    int lane = t & 63;
    int l15  = lane & 15;
    int g    = lane >> 4;

    __shared__ __align__(16) unsigned short Ks[64][72];
    __shared__ __align__(16) unsigned short Vs[64][72];   // Vs[d][s]
    __shared__ __align__(16) unsigned short Ps[4][32][72];
    __shared__ float Ms[64];

    bf16x8 qa[2][2];
    const unsigned short* qp = Qg + (size_t)(b * SEQ + qt * QBLK + wid * 32) * HDIM + h * HD;
#pragma unroll
    for (int m = 0; m < 2; ++m)
#pragma unroll
        for (int kc = 0; kc < 2; ++kc)
            qa[m][kc] = *(const bf16x8*)(qp + (size_t)(16 * m + l15) * HDIM + 32 * kc + 8 * g);

    float m_run[2][4], l_run[2][4];
    f32x4 acc[2][4];
#pragma unroll
    for (int m = 0; m < 2; ++m)
#pragma unroll
        for (int r = 0; r < 4; ++r) { m_run[m][r] = -1e30f; l_run[m][r] = 0.f; }
#pragma unroll
    for (int m = 0; m < 2; ++m)
#pragma unroll
        for (int n = 0; n < 4; ++n) acc[m][n] = (f32x4){0.f, 0.f, 0.f, 0.f};

    const unsigned short* kp0 = Kg + (size_t)(b * SEQ) * HDIM + h * HD;
    const unsigned short* vt0 = Vt + (size_t)((b * NHEAD + h) * HD) * SEQ;

    for (int kt = 0; kt < SEQ / KVB; ++kt) {
        __syncthreads();
#pragma unroll
        for (int i = 0; i < 2; ++i) {
            int u = t + 256 * i;
            int r = u >> 3, cg = u & 7;
            us8 kv = *(const us8*)(kp0 + (size_t)(kt * KVB + r) * HDIM + 8 * cg);
            us8 vv = *(const us8*)(vt0 + (size_t)r * SEQ + kt * KVB + 8 * cg);
            *(us8*)&Ks[r][8 * cg] = kv;
            *(us8*)&Vs[r][8 * cg] = vv;
        }
        if (t < 64) Ms[t] = (1.0f - mask[b * SEQ + kt * KVB + t]) * -10000.0f;
        __syncthreads();

        bf16x8 kb[4][2];
#pragma unroll
        for (int n = 0; n < 4; ++n)
#pragma unroll
            for (int kc = 0; kc < 2; ++kc)
                kb[n][kc] = *(const bf16x8*)&Ks[16 * n + l15][32 * kc + 8 * g];

        f32x4 s[2][4];
#pragma unroll
        for (int m = 0; m < 2; ++m)
#pragma unroll
            for (int n = 0; n < 4; ++n) {
                f32x4 a = (f32x4){0.f, 0.f, 0.f, 0.f};
#pragma unroll
                for (int kc = 0; kc < 2; ++kc)
                    a = __builtin_amdgcn_mfma_f32_16x16x32_bf16(qa[m][kc], kb[n][kc], a, 0, 0, 0);
                s[m][n] = a;
            }

        float msk[4];
#pragma unroll
        for (int n = 0; n < 4; ++n) msk[n] = Ms[16 * n + l15];

#pragma unroll
        for (int m = 0; m < 2; ++m) {
#pragma unroll
            for (int n = 0; n < 4; ++n)
#pragma unroll
                for (int r = 0; r < 4; ++r) s[m][n][r] = fmaf(s[m][n][r], 0.125f, msk[n]);
            float mx[4];
#pragma unroll
            for (int r = 0; r < 4; ++r)
                mx[r] = fmaxf(fmaxf(s[m][0][r], s[m][1][r]), fmaxf(s[m][2][r], s[m][3][r]));
#pragma unroll
            for (int off = 1; off < 16; off <<= 1)
#pragma unroll
                for (int r = 0; r < 4; ++r) mx[r] = fmaxf(mx[r], __shfl_xor(mx[r], off, 64));
            float corr[4];
#pragma unroll
            for (int r = 0; r < 4; ++r) {
                float mn = fmaxf(m_run[m][r], mx[r]);
                corr[r] = __expf(m_run[m][r] - mn);
                m_run[m][r] = mn;
            }
            float ls[4] = {0.f, 0.f, 0.f, 0.f};
#pragma unroll
            for (int n = 0; n < 4; ++n)
#pragma unroll
                for (int r = 0; r < 4; ++r) {
                    float p = __expf(s[m][n][r] - m_run[m][r]);
                    s[m][n][r] = p;
                    ls[r] += p;
                }
#pragma unroll
            for (int off = 1; off < 16; off <<= 1)
#pragma unroll
                for (int r = 0; r < 4; ++r) ls[r] += __shfl_xor(ls[r], off, 64);
#pragma unroll
            for (int r = 0; r < 4; ++r) l_run[m][r] = l_run[m][r] * corr[r] + ls[r];
#pragma unroll
            for (int n = 0; n < 4; ++n)
#pragma unroll
                for (int r = 0; r < 4; ++r) acc[m][n][r] *= corr[r];
#pragma unroll
            for (int n = 0; n < 4; ++n)
#pragma unroll
                for (int r = 0; r < 4; ++r)
                    Ps[wid][16 * m + 4 * g + r][16 * n + l15] = f2bf(s[m][n][r]);
        }

        bf16x8 vbf[4][2];
#pragma unroll
        for (int n = 0; n < 4; ++n)
#pragma unroll
            for (int kc = 0; kc < 2; ++kc)
                vbf[n][kc] = *(const bf16x8*)&Vs[16 * n + l15][32 * kc + 8 * g];
        bf16x8 pa[2][2];
#pragma unroll
        for (int m = 0; m < 2; ++m)
#pragma unroll
            for (int kc = 0; kc < 2; ++kc)
                pa[m][kc] = *(const bf16x8*)&Ps[wid][16 * m + l15][32 * kc + 8 * g];
#pragma unroll
        for (int m = 0; m < 2; ++m)
#pragma unroll
            for (int n = 0; n < 4; ++n)
#pragma unroll
                for (int kc = 0; kc < 2; ++kc)
                    acc[m][n] = __builtin_amdgcn_mfma_f32_16x16x32_bf16(pa[m][kc], vbf[n][kc], acc[m][n], 0, 0, 0);
    }

    size_t rbase = (size_t)(b * SEQ + qt * QBLK + wid * 32);
#pragma unroll
    for (int m = 0; m < 2; ++m)
#pragma unroll
        for (int r = 0; r < 4; ++r) {
            float inv = 1.0f / l_run[m][r];
            size_t row = rbase + 16 * m + 4 * g + r;
#pragma unroll
            for (int n = 0; n < 4; ++n) {
                float o = acc[m][n][r] * inv;
                unsigned short hi = f2bf(o);
                unsigned short lo = f2bf(o - bf2f(hi));
                size_t idx = row * HDIM + h * HD + 16 * n + l15;
                Ch[idx] = hi;
                Cl[idx] = lo;
            }
        }
}

// ---------------------------------------------------------------------------
extern "C" void kernel_launch(void* const* d_in, const int* in_sizes, int n_in,
                              void* d_out, int out_size, void* d_ws, size_t ws_size,
                              hipStream_t stream)
{
    const float* hs   = (const float*)d_in[0];
    const float* mask = (const float*)d_in[1];
    const float* Wq = (const float*)d_in[2];
    const float* Wk = (const float*)d_in[3];
    const float* Wv = (const float*)d_in[4];
    const float* Wo = (const float*)d_in[5];
    const float* Aq = (const float*)d_in[6];
    const float* Bq = (const float*)d_in[7];
    const float* Ak = (const float*)d_in[8];
    const float* Bk = (const float*)d_in[9];
    const float* Av = (const float*)d_in[10];
    const float* Bv = (const float*)d_in[11];
    const float* Ao = (const float*)d_in[12];
    const float* Bo = (const float*)d_in[13];
    float* out = (float*)d_out;

    char* w = (char*)d_ws;
    unsigned short* Xh = (unsigned short*)(w);                       // 8 MB (later Ch)
    unsigned short* Xl = (unsigned short*)(w + ((size_t)8 << 20));   // 8 MB (later Cl)
    unsigned short* WT = (unsigned short*)(w + ((size_t)16 << 20));  // 16 MB (8 planes)
    unsigned short* qb = (unsigned short*)(w + ((size_t)32 << 20));  // 8 MB
    unsigned short* kb = (unsigned short*)(w + ((size_t)40 << 20));  // 8 MB
    unsigned short* vb = (unsigned short*)(w + ((size_t)48 << 20));  // 8 MB
    unsigned short* vt = (unsigned short*)(w + ((size_t)56 << 20));  // 8 MB
    float* hsA  = (float*)(w + ((size_t)64 << 20));                  // 4096*24*4
    float* ctxA = (float*)(w + ((size_t)64 << 20) + 400 * 1024);     // 4096*8*4

    split_x_kernel<<<2048, 256, 0, stream>>>(hs, Xh, Xl, MTOT * HDIM / 4);
    tsplit_w_kernel<<<dim3(16, 16, 4), 256, 0, stream>>>(Wq, Wk, Wv, Wo, WT);
    lora_down_kernel<<<MTOT, 64, 0, stream>>>(hs, Aq, Ak, Av, hsA, 3);
    gemm_mfma_kernel<false><<<dim3(8, 32, 3), 256, 0, stream>>>(
        Xh, Xl, WT, 0, hsA, 24, 0, Bq, Bk, Bv, qb, kb, vb);
    transpose_v_kernel<<<dim3(SEQ / 64, BATCH * NHEAD), 256, 0, stream>>>(vb, vt);
    attn_mfma_kernel<<<dim3(SEQ / QBLK, NHEAD, BATCH), 256, 0, stream>>>(
        qb, kb, vt, mask, Xh /*Ch*/, Xl /*Cl*/);
    lora_down_bf_kernel<<<MTOT, 64, 0, stream>>>(Xh, Xl, Ao, ctxA);
    gemm_mfma_kernel<true><<<dim3(8, 32, 1), 256, 0, stream>>>(
        Xh, Xl, WT, 3, ctxA, 8, 0, Bo, Bo, Bo, out, out, out);
}

// Round 6
// 285.008 us; speedup vs baseline: 3.6802x; 1.0062x over previous
//
#include <hip/hip_runtime.h>
#include <math.h>

typedef float fx4 __attribute__((ext_vector_type(4)));
typedef float f32x4 __attribute__((ext_vector_type(4)));
typedef short bf16x8 __attribute__((ext_vector_type(8)));
typedef unsigned short us4 __attribute__((ext_vector_type(4)));
typedef unsigned short us8 __attribute__((ext_vector_type(8)));

#define HDIM 1024
#define SEQ  2048
#define BATCH 2
#define NHEAD 16
#define HD    64
#define MTOT  4096
#define LSCALE 8.0f

__device__ __forceinline__ unsigned short f2bf(float f) {
    union { float f; unsigned int u; } v; v.f = f;
    unsigned int r = v.u + 0x7FFFu + ((v.u >> 16) & 1u);
    return (unsigned short)(r >> 16);
}
__device__ __forceinline__ float bf2f(unsigned short h) {
    union { unsigned int u; float f; } v; v.u = ((unsigned int)h) << 16;
    return v.f;
}

// ---------------------------------------------------------------------------
// split X (fp32) -> hi/lo bf16 planes
// ---------------------------------------------------------------------------
__global__ __launch_bounds__(256)
void split_x_kernel(const float* __restrict__ X, unsigned short* __restrict__ Xh,
                    unsigned short* __restrict__ Xl, int n4)
{
    int i = blockIdx.x * 256 + threadIdx.x;
    int stride = gridDim.x * 256;
    for (; i < n4; i += stride) {
        fx4 v = *((const fx4*)X + i);
        us4 h, l;
#pragma unroll
        for (int j = 0; j < 4; ++j) {
            h[j] = f2bf(v[j]);
            l[j] = f2bf(v[j] - bf2f(h[j]));
        }
        *((us4*)Xh + i) = h;
        *((us4*)Xl + i) = l;
    }
}

// ---------------------------------------------------------------------------
// transpose + split W [k][n] fp32 -> WT hi/lo bf16 [n][k]; z selects matrix.
// ---------------------------------------------------------------------------
__global__ __launch_bounds__(256)
void tsplit_w_kernel(const float* __restrict__ W0, const float* __restrict__ W1,
                     const float* __restrict__ W2, const float* __restrict__ W3,
                     unsigned short* __restrict__ WTbase)
{
    int z = blockIdx.z;
    const float* W = (z == 0) ? W0 : (z == 1) ? W1 : (z == 2) ? W2 : W3;
    unsigned short* WTh = WTbase + (size_t)z * 2097152;
    unsigned short* WTl = WTh + 1048576;
    int n0 = blockIdx.x * 64, k0 = blockIdx.y * 64;
    __shared__ unsigned int T[64][65];
    int t = threadIdx.x;
#pragma unroll
    for (int i = 0; i < 4; ++i) {
        int idx = t + 256 * i;
        int r = idx >> 4, c4 = (idx & 15) * 4;
        fx4 w = *(const fx4*)&W[(size_t)(k0 + r) * HDIM + n0 + c4];
#pragma unroll
        for (int j = 0; j < 4; ++j) {
            unsigned short hi = f2bf(w[j]);
            unsigned short lo = f2bf(w[j] - bf2f(hi));
            T[r][c4 + j] = (unsigned int)hi | ((unsigned int)lo << 16);
        }
    }
    __syncthreads();
#pragma unroll
    for (int i = 0; i < 4; ++i) {
        int idx = t + 256 * i;
        int n = idx >> 4, kg = (idx & 15) * 4;
        us4 hv, lv;
#pragma unroll
        for (int j = 0; j < 4; ++j) {
            unsigned int p = T[kg + j][n];
            hv[j] = (unsigned short)(p & 0xffffu);
            lv[j] = (unsigned short)(p >> 16);
        }
        *(us4*)&WTh[(size_t)(n0 + n) * HDIM + k0 + kg] = hv;
        *(us4*)&WTl[(size_t)(n0 + n) * HDIM + k0 + kg] = lv;
    }
}

// ---------------------------------------------------------------------------
// transpose V: vb [4096][1024] bf16 -> vt [(b*16+h)*64+d][2048] bf16
// ---------------------------------------------------------------------------
__global__ __launch_bounds__(256)
void transpose_v_kernel(const unsigned short* __restrict__ vb,
                        unsigned short* __restrict__ vt)
{
    int s0 = blockIdx.x * 64;
    int bh = blockIdx.y;               // b*16+h
    int b = bh >> 4, h = bh & 15;
    __shared__ unsigned short T[64][80];
    int t = threadIdx.x;
#pragma unroll
    for (int i = 0; i < 2; ++i) {
        int u = t + 256 * i;
        int r = u >> 3, cg = u & 7;
        us8 v = *(const us8*)&vb[(size_t)(b * SEQ + s0 + r) * HDIM + h * HD + 8 * cg];
        *(us8*)&T[r][8 * cg] = v;
    }
    __syncthreads();
#pragma unroll
    for (int i = 0; i < 2; ++i) {
        int u = t + 256 * i;
        int d = u & 63, sg = u >> 6;
        us8 v;
#pragma unroll
        for (int j = 0; j < 8; ++j) v[j] = T[8 * sg + j][d];
        *(us8*)&vt[(size_t)(bh * HD + d) * SEQ + s0 + 8 * sg] = v;
    }
}

// ---------------------------------------------------------------------------
// lora down: fp32 X; XA = X @ [A0|A1|A2]; out row stride 24
// ---------------------------------------------------------------------------
__global__ __launch_bounds__(64)
void lora_down_kernel(const float* __restrict__ X,
                      const float* __restrict__ A0,
                      const float* __restrict__ A1,
                      const float* __restrict__ A2,
                      float* __restrict__ out, int nmat)
{
    int row  = blockIdx.x;
    int lane = threadIdx.x;
    const float* xr = X + (size_t)row * HDIM;
    float xv[16];
#pragma unroll
    for (int i = 0; i < 16; ++i) xv[i] = xr[lane + 64 * i];
    const float* Amats[3] = {A0, A1, A2};
    for (int m = 0; m < nmat; ++m) {
        const float* A = Amats[m];
        float s[8];
#pragma unroll
        for (int c = 0; c < 8; ++c) s[c] = 0.f;
#pragma unroll
        for (int i = 0; i < 16; ++i) {
            const float* ap = A + (size_t)(lane + 64 * i) * 8;
#pragma unroll
            for (int c = 0; c < 8; ++c) s[c] += xv[i] * ap[c];
        }
#pragma unroll
        for (int c = 0; c < 8; ++c) {
#pragma unroll
            for (int off = 1; off < 64; off <<= 1)
                s[c] += __shfl_xor(s[c], off, 64);
        }
        if (lane == 0) {
#pragma unroll
            for (int c = 0; c < 8; ++c)
                out[(size_t)row * 24 + m * 8 + c] = s[c];
        }
    }
}

// lora down from hi/lo bf16 planes (ctx); out stride 8
__global__ __launch_bounds__(64)
void lora_down_bf_kernel(const unsigned short* __restrict__ Xh,
                         const unsigned short* __restrict__ Xl,
                         const float* __restrict__ A,
                         float* __restrict__ out)
{
    int row  = blockIdx.x;
    int lane = threadIdx.x;
    const unsigned short* xh = Xh + (size_t)row * HDIM;
    const unsigned short* xl = Xl + (size_t)row * HDIM;
    float xv[16];
#pragma unroll
    for (int i = 0; i < 16; ++i)
        xv[i] = bf2f(xh[lane + 64 * i]) + bf2f(xl[lane + 64 * i]);
    float s[8];
#pragma unroll
    for (int c = 0; c < 8; ++c) s[c] = 0.f;
#pragma unroll
    for (int i = 0; i < 16; ++i) {
        const float* ap = A + (size_t)(lane + 64 * i) * 8;
#pragma unroll
        for (int c = 0; c < 8; ++c) s[c] += xv[i] * ap[c];
    }
#pragma unroll
    for (int c = 0; c < 8; ++c) {
#pragma unroll
        for (int off = 1; off < 64; off <<= 1)
            s[c] += __shfl_xor(s[c], off, 64);
    }
    if (lane == 0) {
#pragma unroll
        for (int c = 0; c < 8; ++c) out[(size_t)row * 8 + c] = s[c];
    }
}

// ---------------------------------------------------------------------------
// split-bf16 MFMA GEMM: Out = X@W + LSCALE*(XA)@Bu
// ---------------------------------------------------------------------------
template<bool OUTF32>
__global__ __launch_bounds__(256, 2)
void gemm_mfma_kernel(const unsigned short* __restrict__ Xh, const unsigned short* __restrict__ Xl,
                      const unsigned short* __restrict__ WTbase, int wsel0,
                      const float* __restrict__ XA, int xa_stride, int xa_off0,
                      const float* __restrict__ Bu0, const float* __restrict__ Bu1, const float* __restrict__ Bu2,
                      void* __restrict__ O0, void* __restrict__ O1, void* __restrict__ O2)
{
    int pz = blockIdx.z;
    const unsigned short* WTh = WTbase + (size_t)(wsel0 + pz) * 2097152;
    const unsigned short* WTl = WTh + 1048576;
    const float* Bu = (pz == 0) ? Bu0 : (pz == 1) ? Bu1 : Bu2;
    void* Ovp       = (pz == 0) ? O0 : (pz == 1) ? O1 : O2;
    int xa_off = xa_off0 + pz * 8;

    int brow = blockIdx.y * 128, bcol = blockIdx.x * 128;
    int t = threadIdx.x, wid = t >> 6, lane = t & 63, l15 = lane & 15, g = lane >> 4;
    int wm = (wid >> 1) * 64, wn = (wid & 1) * 64;

    __shared__ unsigned short Ah[128][40];
    __shared__ unsigned short Al[128][40];
    __shared__ unsigned short Bh[128][40];
    __shared__ unsigned short Bl[128][40];

    f32x4 acc[4][4];
#pragma unroll
    for (int i = 0; i < 4; ++i)
#pragma unroll
        for (int j = 0; j < 4; ++j) acc[i][j] = (f32x4){0.f, 0.f, 0.f, 0.f};

    int sm = t >> 2, skg = t & 3;
    const unsigned short* aH0 = Xh  + (size_t)(brow + sm) * HDIM + 8 * skg;
    const unsigned short* aL0 = Xl  + (size_t)(brow + sm) * HDIM + 8 * skg;
    const unsigned short* bH0 = WTh + (size_t)(bcol + sm) * HDIM + 8 * skg;
    const unsigned short* bL0 = WTl + (size_t)(bcol + sm) * HDIM + 8 * skg;
    const size_t R64 = (size_t)64 * HDIM;

    us8 rAH0 = *(const us8*)(aH0);
    us8 rAH1 = *(const us8*)(aH0 + R64);
    us8 rAL0 = *(const us8*)(aL0);
    us8 rAL1 = *(const us8*)(aL0 + R64);
    us8 rBH0 = *(const us8*)(bH0);
    us8 rBH1 = *(const us8*)(bH0 + R64);
    us8 rBL0 = *(const us8*)(bL0);
    us8 rBL1 = *(const us8*)(bL0 + R64);

    for (int k0 = 0; k0 < HDIM; k0 += 32) {
        __syncthreads();
        *(us8*)&Ah[sm][8 * skg]      = rAH0;
        *(us8*)&Ah[sm + 64][8 * skg] = rAH1;
        *(us8*)&Al[sm][8 * skg]      = rAL0;
        *(us8*)&Al[sm + 64][8 * skg] = rAL1;
        *(us8*)&Bh[sm][8 * skg]      = rBH0;
        *(us8*)&Bh[sm + 64][8 * skg] = rBH1;
        *(us8*)&Bl[sm][8 * skg]      = rBL0;
        *(us8*)&Bl[sm + 64][8 * skg] = rBL1;
        __syncthreads();
        if (k0 + 32 < HDIM) {
            int ko = k0 + 32;
            rAH0 = *(const us8*)(aH0 + ko);
            rAH1 = *(const us8*)(aH0 + R64 + ko);
            rAL0 = *(const us8*)(aL0 + ko);
            rAL1 = *(const us8*)(aL0 + R64 + ko);
            rBH0 = *(const us8*)(bH0 + ko);
            rBH1 = *(const us8*)(bH0 + R64 + ko);
            rBL0 = *(const us8*)(bL0 + ko);
            rBL1 = *(const us8*)(bL0 + R64 + ko);
        }
        bf16x8 fah[4], fal[4], fbh[4], fbl[4];
#pragma unroll
        for (int f = 0; f < 4; ++f) {
            fah[f] = *(const bf16x8*)&Ah[wm + 16 * f + l15][8 * g];
            fal[f] = *(const bf16x8*)&Al[wm + 16 * f + l15][8 * g];
            fbh[f] = *(const bf16x8*)&Bh[wn + 16 * f + l15][8 * g];
            fbl[f] = *(const bf16x8*)&Bl[wn + 16 * f + l15][8 * g];
        }
#pragma unroll
        for (int fm = 0; fm < 4; ++fm)
#pragma unroll
            for (int fn = 0; fn < 4; ++fn) {
                f32x4 a = acc[fm][fn];
                a = __builtin_amdgcn_mfma_f32_16x16x32_bf16(fah[fm], fbh[fn], a, 0, 0, 0);
                a = __builtin_amdgcn_mfma_f32_16x16x32_bf16(fah[fm], fbl[fn], a, 0, 0, 0);
                a = __builtin_amdgcn_mfma_f32_16x16x32_bf16(fal[fm], fbh[fn], a, 0, 0, 0);
                acc[fm][fn] = a;
            }
    }

    // LoRA epilogue + store
    float lb[8][4];
#pragma unroll
    for (int rr = 0; rr < 8; ++rr)
#pragma unroll
        for (int fn = 0; fn < 4; ++fn)
            lb[rr][fn] = Bu[(size_t)rr * HDIM + bcol + wn + 16 * fn + l15] * LSCALE;

#pragma unroll
    for (int fm = 0; fm < 4; ++fm) {
        float la[4][8];
#pragma unroll
        for (int r = 0; r < 4; ++r) {
            int row = brow + wm + 16 * fm + 4 * g + r;
            const float* lap = XA + (size_t)row * xa_stride + xa_off;
            fx4 q0 = *(const fx4*)lap;
            fx4 q1 = *(const fx4*)(lap + 4);
#pragma unroll
            for (int j = 0; j < 4; ++j) { la[r][j] = q0[j]; la[r][4 + j] = q1[j]; }
        }
#pragma unroll
        for (int fn = 0; fn < 4; ++fn)
#pragma unroll
            for (int r = 0; r < 4; ++r) {
                float sum = acc[fm][fn][r];
#pragma unroll
                for (int rr = 0; rr < 8; ++rr) sum += la[r][rr] * lb[rr][fn];
                size_t row = (size_t)(brow + wm + 16 * fm + 4 * g + r);
                int col = bcol + wn + 16 * fn + l15;
                if (OUTF32) ((float*)Ovp)[row * HDIM + col] = sum;
                else ((unsigned short*)Ovp)[row * HDIM + col] = f2bf(sum);
            }
    }
}

// ---------------------------------------------------------------------------
// flash attention, bf16 MFMA. QBLK=64, 4 waves, wave owns 16 q-rows.
// Grid = 32x16x2 = 1024 blocks -> 4 blocks/CU (16 waves/CU) for latency hiding.
// ---------------------------------------------------------------------------
#define QBLK 64
#define KVB  64

__global__ __launch_bounds__(256, 4)
void attn_mfma_kernel(const unsigned short* __restrict__ Qg, const unsigned short* __restrict__ Kg,
                      const unsigned short* __restrict__ Vt, const float* __restrict__ mask,
                      unsigned short* __restrict__ Ch, unsigned short* __restrict__ Cl)
{
    int qt = blockIdx.x, h = blockIdx.y, b = blockIdx.z;
    int t    = threadIdx.x;
    int wid  = t >> 6;
    int lane = t & 63;
    int l15  = lane & 15;
    int g    = lane >> 4;

    __shared__ __align__(16) unsigned short Ks[64][72];
    __shared__ __align__(16) unsigned short Vs[64][72];   // Vs[d][s]
    __shared__ __align__(16) unsigned short Ps[4][16][72];
    __shared__ float Ms[64];

    // wave's 16 q rows: A-fragments (row=l15, k=32kc+8g+j), scale folded later
    bf16x8 qa[2];
    const unsigned short* qp = Qg + (size_t)(b * SEQ + qt * QBLK + wid * 16) * HDIM + h * HD;
#pragma unroll
    for (int kc = 0; kc < 2; ++kc)
        qa[kc] = *(const bf16x8*)(qp + (size_t)l15 * HDIM + 32 * kc + 8 * g);

    float m_run[4], l_run[4];
    f32x4 acc[4];
#pragma unroll
    for (int r = 0; r < 4; ++r) { m_run[r] = -1e30f; l_run[r] = 0.f; }
#pragma unroll
    for (int n = 0; n < 4; ++n) acc[n] = (f32x4){0.f, 0.f, 0.f, 0.f};

    const unsigned short* kp0 = Kg + (size_t)(b * SEQ) * HDIM + h * HD;
    const unsigned short* vt0 = Vt + (size_t)((b * NHEAD + h) * HD) * SEQ;

    for (int kt = 0; kt < SEQ / KVB; ++kt) {
        __syncthreads();
#pragma unroll
        for (int i = 0; i < 2; ++i) {
            int u = t + 256 * i;
            int r = u >> 3, cg = u & 7;
            us8 kv = *(const us8*)(kp0 + (size_t)(kt * KVB + r) * HDIM + 8 * cg);
            us8 vv = *(const us8*)(vt0 + (size_t)r * SEQ + kt * KVB + 8 * cg);
            *(us8*)&Ks[r][8 * cg] = kv;
            *(us8*)&Vs[r][8 * cg] = vv;
        }
        if (t < 64) Ms[t] = (1.0f - mask[b * SEQ + kt * KVB + t]) * -10000.0f;
        __syncthreads();

        // ---- QK^T: s[n] covers kv-cols 16n+l15, rows 4g+r ----
        bf16x8 kb[4][2];
#pragma unroll
        for (int n = 0; n < 4; ++n)
#pragma unroll
            for (int kc = 0; kc < 2; ++kc)
                kb[n][kc] = *(const bf16x8*)&Ks[16 * n + l15][32 * kc + 8 * g];

        f32x4 s[4];
#pragma unroll
        for (int n = 0; n < 4; ++n) {
            f32x4 a = (f32x4){0.f, 0.f, 0.f, 0.f};
#pragma unroll
            for (int kc = 0; kc < 2; ++kc)
                a = __builtin_amdgcn_mfma_f32_16x16x32_bf16(qa[kc], kb[n][kc], a, 0, 0, 0);
            s[n] = a;
        }

        float msk[4];
#pragma unroll
        for (int n = 0; n < 4; ++n) msk[n] = Ms[16 * n + l15];

        // ---- online softmax (rows 4g+r, reduce over 16 lanes) ----
#pragma unroll
        for (int n = 0; n < 4; ++n)
#pragma unroll
            for (int r = 0; r < 4; ++r) s[n][r] = fmaf(s[n][r], 0.125f, msk[n]);
        float mx[4];
#pragma unroll
        for (int r = 0; r < 4; ++r)
            mx[r] = fmaxf(fmaxf(s[0][r], s[1][r]), fmaxf(s[2][r], s[3][r]));
#pragma unroll
        for (int off = 1; off < 16; off <<= 1)
#pragma unroll
            for (int r = 0; r < 4; ++r) mx[r] = fmaxf(mx[r], __shfl_xor(mx[r], off, 64));
        float corr[4];
#pragma unroll
        for (int r = 0; r < 4; ++r) {
            float mn = fmaxf(m_run[r], mx[r]);
            corr[r] = __expf(m_run[r] - mn);
            m_run[r] = mn;
        }
        float ls[4] = {0.f, 0.f, 0.f, 0.f};
#pragma unroll
        for (int n = 0; n < 4; ++n)
#pragma unroll
            for (int r = 0; r < 4; ++r) {
                float p = __expf(s[n][r] - m_run[r]);
                s[n][r] = p;
                ls[r] += p;
            }
#pragma unroll
        for (int off = 1; off < 16; off <<= 1)
#pragma unroll
            for (int r = 0; r < 4; ++r) ls[r] += __shfl_xor(ls[r], off, 64);
#pragma unroll
        for (int r = 0; r < 4; ++r) l_run[r] = l_run[r] * corr[r] + ls[r];
#pragma unroll
        for (int n = 0; n < 4; ++n)
#pragma unroll
            for (int r = 0; r < 4; ++r) acc[n][r] *= corr[r];
        // P (D-layout row 4g+r, col 16n+l15) -> wave-private LDS
#pragma unroll
        for (int n = 0; n < 4; ++n)
#pragma unroll
            for (int r = 0; r < 4; ++r)
                Ps[wid][4 * g + r][16 * n + l15] = f2bf(s[n][r]);

        // ---- PV ----
        bf16x8 vbf[4][2];
#pragma unroll
        for (int n = 0; n < 4; ++n)
#pragma unroll
            for (int kc = 0; kc < 2; ++kc)
                vbf[n][kc] = *(const bf16x8*)&Vs[16 * n + l15][32 * kc + 8 * g];
        bf16x8 pa[2];
#pragma unroll
        for (int kc = 0; kc < 2; ++kc)
            pa[kc] = *(const bf16x8*)&Ps[wid][l15][32 * kc + 8 * g];
#pragma unroll
        for (int n = 0; n < 4; ++n)
#pragma unroll
            for (int kc = 0; kc < 2; ++kc)
                acc[n] = __builtin_amdgcn_mfma_f32_16x16x32_bf16(pa[kc], vbf[n][kc], acc[n], 0, 0, 0);
    }

    size_t rbase = (size_t)(b * SEQ + qt * QBLK + wid * 16);
#pragma unroll
    for (int r = 0; r < 4; ++r) {
        float inv = 1.0f / l_run[r];
        size_t row = rbase + 4 * g + r;
#pragma unroll
        for (int n = 0; n < 4; ++n) {
            float o = acc[n][r] * inv;
            unsigned short hi = f2bf(o);
            unsigned short lo = f2bf(o - bf2f(hi));
            size_t idx = row * HDIM + h * HD + 16 * n + l15;
            Ch[idx] = hi;
            Cl[idx] = lo;
        }
    }
}

// ---------------------------------------------------------------------------
extern "C" void kernel_launch(void* const* d_in, const int* in_sizes, int n_in,
                              void* d_out, int out_size, void* d_ws, size_t ws_size,
                              hipStream_t stream)
{
    const float* hs   = (const float*)d_in[0];
    const float* mask = (const float*)d_in[1];
    const float* Wq = (const float*)d_in[2];
    const float* Wk = (const float*)d_in[3];
    const float* Wv = (const float*)d_in[4];
    const float* Wo = (const float*)d_in[5];
    const float* Aq = (const float*)d_in[6];
    const float* Bq = (const float*)d_in[7];
    const float* Ak = (const float*)d_in[8];
    const float* Bk = (const float*)d_in[9];
    const float* Av = (const float*)d_in[10];
    const float* Bv = (const float*)d_in[11];
    const float* Ao = (const float*)d_in[12];
    const float* Bo = (const float*)d_in[13];
    float* out = (float*)d_out;

    char* w = (char*)d_ws;
    unsigned short* Xh = (unsigned short*)(w);                       // 8 MB (later Ch)
    unsigned short* Xl = (unsigned short*)(w + ((size_t)8 << 20));   // 8 MB (later Cl)
    unsigned short* WT = (unsigned short*)(w + ((size_t)16 << 20));  // 16 MB (8 planes)
    unsigned short* qb = (unsigned short*)(w + ((size_t)32 << 20));  // 8 MB
    unsigned short* kb = (unsigned short*)(w + ((size_t)40 << 20));  // 8 MB
    unsigned short* vb = (unsigned short*)(w + ((size_t)48 << 20));  // 8 MB
    unsigned short* vt = (unsigned short*)(w + ((size_t)56 << 20));  // 8 MB
    float* hsA  = (float*)(w + ((size_t)64 << 20));                  // 4096*24*4
    float* ctxA = (float*)(w + ((size_t)64 << 20) + 400 * 1024);     // 4096*8*4

    split_x_kernel<<<2048, 256, 0, stream>>>(hs, Xh, Xl, MTOT * HDIM / 4);
    tsplit_w_kernel<<<dim3(16, 16, 4), 256, 0, stream>>>(Wq, Wk, Wv, Wo, WT);
    lora_down_kernel<<<MTOT, 64, 0, stream>>>(hs, Aq, Ak, Av, hsA, 3);
    gemm_mfma_kernel<false><<<dim3(8, 32, 3), 256, 0, stream>>>(
        Xh, Xl, WT, 0, hsA, 24, 0, Bq, Bk, Bv, qb, kb, vb);
    transpose_v_kernel<<<dim3(SEQ / 64, BATCH * NHEAD), 256, 0, stream>>>(vb, vt);
    attn_mfma_kernel<<<dim3(SEQ / QBLK, NHEAD, BATCH), 256, 0, stream>>>(
        qb, kb, vt, mask, Xh /*Ch*/, Xl /*Cl*/);
    lora_down_bf_kernel<<<MTOT, 64, 0, stream>>>(Xh, Xl, Ao, ctxA);
    gemm_mfma_kernel<true><<<dim3(8, 32, 1), 256, 0, stream>>>(
        Xh, Xl, WT, 3, ctxA, 8, 0, Bo, Bo, Bo, out, out, out);
}

// Round 7
// 259.416 us; speedup vs baseline: 4.0433x; 1.0986x over previous
//
#include <hip/hip_runtime.h>
#include <math.h>

typedef float fx4 __attribute__((ext_vector_type(4)));
typedef float f32x4 __attribute__((ext_vector_type(4)));
typedef short bf16x8 __attribute__((ext_vector_type(8)));
typedef unsigned short us4 __attribute__((ext_vector_type(4)));
typedef unsigned short us8 __attribute__((ext_vector_type(8)));
typedef unsigned int u32x4 __attribute__((ext_vector_type(4)));

#define HDIM 1024
#define SEQ  2048
#define BATCH 2
#define NHEAD 16
#define HD    64
#define MTOT  4096
#define LSCALE 8.0f

__device__ __forceinline__ unsigned short f2bf(float f) {
    union { float f; unsigned int u; } v; v.f = f;
    unsigned int r = v.u + 0x7FFFu + ((v.u >> 16) & 1u);
    return (unsigned short)(r >> 16);
}
__device__ __forceinline__ float bf2f(unsigned short h) {
    union { unsigned int u; float f; } v; v.u = ((unsigned int)h) << 16;
    return v.f;
}

// ---------------------------------------------------------------------------
// split X (fp32) -> hi/lo bf16 planes
// ---------------------------------------------------------------------------
__global__ __launch_bounds__(256)
void split_x_kernel(const float* __restrict__ X, unsigned short* __restrict__ Xh,
                    unsigned short* __restrict__ Xl, int n4)
{
    int i = blockIdx.x * 256 + threadIdx.x;
    int stride = gridDim.x * 256;
    for (; i < n4; i += stride) {
        fx4 v = *((const fx4*)X + i);
        us4 h, l;
#pragma unroll
        for (int j = 0; j < 4; ++j) {
            h[j] = f2bf(v[j]);
            l[j] = f2bf(v[j] - bf2f(h[j]));
        }
        *((us4*)Xh + i) = h;
        *((us4*)Xl + i) = l;
    }
}

// ---------------------------------------------------------------------------
// transpose + split W [k][n] fp32 -> WT hi/lo bf16 [n][k]; z selects matrix.
// ---------------------------------------------------------------------------
__global__ __launch_bounds__(256)
void tsplit_w_kernel(const float* __restrict__ W0, const float* __restrict__ W1,
                     const float* __restrict__ W2, const float* __restrict__ W3,
                     unsigned short* __restrict__ WTbase)
{
    int z = blockIdx.z;
    const float* W = (z == 0) ? W0 : (z == 1) ? W1 : (z == 2) ? W2 : W3;
    unsigned short* WTh = WTbase + (size_t)z * 2097152;
    unsigned short* WTl = WTh + 1048576;
    int n0 = blockIdx.x * 64, k0 = blockIdx.y * 64;
    __shared__ unsigned int T[64][65];
    int t = threadIdx.x;
#pragma unroll
    for (int i = 0; i < 4; ++i) {
        int idx = t + 256 * i;
        int r = idx >> 4, c4 = (idx & 15) * 4;
        fx4 w = *(const fx4*)&W[(size_t)(k0 + r) * HDIM + n0 + c4];
#pragma unroll
        for (int j = 0; j < 4; ++j) {
            unsigned short hi = f2bf(w[j]);
            unsigned short lo = f2bf(w[j] - bf2f(hi));
            T[r][c4 + j] = (unsigned int)hi | ((unsigned int)lo << 16);
        }
    }
    __syncthreads();
#pragma unroll
    for (int i = 0; i < 4; ++i) {
        int idx = t + 256 * i;
        int n = idx >> 4, kg = (idx & 15) * 4;
        us4 hv, lv;
#pragma unroll
        for (int j = 0; j < 4; ++j) {
            unsigned int p = T[kg + j][n];
            hv[j] = (unsigned short)(p & 0xffffu);
            lv[j] = (unsigned short)(p >> 16);
        }
        *(us4*)&WTh[(size_t)(n0 + n) * HDIM + k0 + kg] = hv;
        *(us4*)&WTl[(size_t)(n0 + n) * HDIM + k0 + kg] = lv;
    }
}

// ---------------------------------------------------------------------------
// transpose V: vb [4096][1024] bf16 -> vt [(b*16+h)*64+d][2048] bf16
// ---------------------------------------------------------------------------
__global__ __launch_bounds__(256)
void transpose_v_kernel(const unsigned short* __restrict__ vb,
                        unsigned short* __restrict__ vt)
{
    int s0 = blockIdx.x * 64;
    int bh = blockIdx.y;               // b*16+h
    int b = bh >> 4, h = bh & 15;
    __shared__ unsigned short T[64][80];
    int t = threadIdx.x;
#pragma unroll
    for (int i = 0; i < 2; ++i) {
        int u = t + 256 * i;
        int r = u >> 3, cg = u & 7;
        us8 v = *(const us8*)&vb[(size_t)(b * SEQ + s0 + r) * HDIM + h * HD + 8 * cg];
        *(us8*)&T[r][8 * cg] = v;
    }
    __syncthreads();
#pragma unroll
    for (int i = 0; i < 2; ++i) {
        int u = t + 256 * i;
        int d = u & 63, sg = u >> 6;
        us8 v;
#pragma unroll
        for (int j = 0; j < 8; ++j) v[j] = T[8 * sg + j][d];
        *(us8*)&vt[(size_t)(bh * HD + d) * SEQ + s0 + 8 * sg] = v;
    }
}

// ---------------------------------------------------------------------------
// lora down: fp32 X; XA = X @ [A0|A1|A2]; out row stride 24
// ---------------------------------------------------------------------------
__global__ __launch_bounds__(64)
void lora_down_kernel(const float* __restrict__ X,
                      const float* __restrict__ A0,
                      const float* __restrict__ A1,
                      const float* __restrict__ A2,
                      float* __restrict__ out, int nmat)
{
    int row  = blockIdx.x;
    int lane = threadIdx.x;
    const float* xr = X + (size_t)row * HDIM;
    float xv[16];
#pragma unroll
    for (int i = 0; i < 16; ++i) xv[i] = xr[lane + 64 * i];
    const float* Amats[3] = {A0, A1, A2};
    for (int m = 0; m < nmat; ++m) {
        const float* A = Amats[m];
        float s[8];
#pragma unroll
        for (int c = 0; c < 8; ++c) s[c] = 0.f;
#pragma unroll
        for (int i = 0; i < 16; ++i) {
            const float* ap = A + (size_t)(lane + 64 * i) * 8;
#pragma unroll
            for (int c = 0; c < 8; ++c) s[c] += xv[i] * ap[c];
        }
#pragma unroll
        for (int c = 0; c < 8; ++c) {
#pragma unroll
            for (int off = 1; off < 64; off <<= 1)
                s[c] += __shfl_xor(s[c], off, 64);
        }
        if (lane == 0) {
#pragma unroll
            for (int c = 0; c < 8; ++c)
                out[(size_t)row * 24 + m * 8 + c] = s[c];
        }
    }
}

// lora down from hi/lo bf16 planes (ctx); out stride 8
__global__ __launch_bounds__(64)
void lora_down_bf_kernel(const unsigned short* __restrict__ Xh,
                         const unsigned short* __restrict__ Xl,
                         const float* __restrict__ A,
                         float* __restrict__ out)
{
    int row  = blockIdx.x;
    int lane = threadIdx.x;
    const unsigned short* xh = Xh + (size_t)row * HDIM;
    const unsigned short* xl = Xl + (size_t)row * HDIM;
    float xv[16];
#pragma unroll
    for (int i = 0; i < 16; ++i)
        xv[i] = bf2f(xh[lane + 64 * i]) + bf2f(xl[lane + 64 * i]);
    float s[8];
#pragma unroll
    for (int c = 0; c < 8; ++c) s[c] = 0.f;
#pragma unroll
    for (int i = 0; i < 16; ++i) {
        const float* ap = A + (size_t)(lane + 64 * i) * 8;
#pragma unroll
        for (int c = 0; c < 8; ++c) s[c] += xv[i] * ap[c];
    }
#pragma unroll
    for (int c = 0; c < 8; ++c) {
#pragma unroll
        for (int off = 1; off < 64; off <<= 1)
            s[c] += __shfl_xor(s[c], off, 64);
    }
    if (lane == 0) {
#pragma unroll
        for (int c = 0; c < 8; ++c) out[(size_t)row * 8 + c] = s[c];
    }
}

// ---------------------------------------------------------------------------
// split-bf16 MFMA GEMM: Out = X@W + LSCALE*(XA)@Bu
// ---------------------------------------------------------------------------
template<bool OUTF32>
__global__ __launch_bounds__(256, 2)
void gemm_mfma_kernel(const unsigned short* __restrict__ Xh, const unsigned short* __restrict__ Xl,
                      const unsigned short* __restrict__ WTbase, int wsel0,
                      const float* __restrict__ XA, int xa_stride, int xa_off0,
                      const float* __restrict__ Bu0, const float* __restrict__ Bu1, const float* __restrict__ Bu2,
                      void* __restrict__ O0, void* __restrict__ O1, void* __restrict__ O2)
{
    int pz = blockIdx.z;
    const unsigned short* WTh = WTbase + (size_t)(wsel0 + pz) * 2097152;
    const unsigned short* WTl = WTh + 1048576;
    const float* Bu = (pz == 0) ? Bu0 : (pz == 1) ? Bu1 : Bu2;
    void* Ovp       = (pz == 0) ? O0 : (pz == 1) ? O1 : O2;
    int xa_off = xa_off0 + pz * 8;

    int brow = blockIdx.y * 128, bcol = blockIdx.x * 128;
    int t = threadIdx.x, wid = t >> 6, lane = t & 63, l15 = lane & 15, g = lane >> 4;
    int wm = (wid >> 1) * 64, wn = (wid & 1) * 64;

    __shared__ unsigned short Ah[128][40];
    __shared__ unsigned short Al[128][40];
    __shared__ unsigned short Bh[128][40];
    __shared__ unsigned short Bl[128][40];

    f32x4 acc[4][4];
#pragma unroll
    for (int i = 0; i < 4; ++i)
#pragma unroll
        for (int j = 0; j < 4; ++j) acc[i][j] = (f32x4){0.f, 0.f, 0.f, 0.f};

    int sm = t >> 2, skg = t & 3;
    const unsigned short* aH0 = Xh  + (size_t)(brow + sm) * HDIM + 8 * skg;
    const unsigned short* aL0 = Xl  + (size_t)(brow + sm) * HDIM + 8 * skg;
    const unsigned short* bH0 = WTh + (size_t)(bcol + sm) * HDIM + 8 * skg;
    const unsigned short* bL0 = WTl + (size_t)(bcol + sm) * HDIM + 8 * skg;
    const size_t R64 = (size_t)64 * HDIM;

    us8 rAH0 = *(const us8*)(aH0);
    us8 rAH1 = *(const us8*)(aH0 + R64);
    us8 rAL0 = *(const us8*)(aL0);
    us8 rAL1 = *(const us8*)(aL0 + R64);
    us8 rBH0 = *(const us8*)(bH0);
    us8 rBH1 = *(const us8*)(bH0 + R64);
    us8 rBL0 = *(const us8*)(bL0);
    us8 rBL1 = *(const us8*)(bL0 + R64);

    for (int k0 = 0; k0 < HDIM; k0 += 32) {
        __syncthreads();
        *(us8*)&Ah[sm][8 * skg]      = rAH0;
        *(us8*)&Ah[sm + 64][8 * skg] = rAH1;
        *(us8*)&Al[sm][8 * skg]      = rAL0;
        *(us8*)&Al[sm + 64][8 * skg] = rAL1;
        *(us8*)&Bh[sm][8 * skg]      = rBH0;
        *(us8*)&Bh[sm + 64][8 * skg] = rBH1;
        *(us8*)&Bl[sm][8 * skg]      = rBL0;
        *(us8*)&Bl[sm + 64][8 * skg] = rBL1;
        __syncthreads();
        if (k0 + 32 < HDIM) {
            int ko = k0 + 32;
            rAH0 = *(const us8*)(aH0 + ko);
            rAH1 = *(const us8*)(aH0 + R64 + ko);
            rAL0 = *(const us8*)(aL0 + ko);
            rAL1 = *(const us8*)(aL0 + R64 + ko);
            rBH0 = *(const us8*)(bH0 + ko);
            rBH1 = *(const us8*)(bH0 + R64 + ko);
            rBL0 = *(const us8*)(bL0 + ko);
            rBL1 = *(const us8*)(bL0 + R64 + ko);
        }
        bf16x8 fah[4], fal[4], fbh[4], fbl[4];
#pragma unroll
        for (int f = 0; f < 4; ++f) {
            fah[f] = *(const bf16x8*)&Ah[wm + 16 * f + l15][8 * g];
            fal[f] = *(const bf16x8*)&Al[wm + 16 * f + l15][8 * g];
            fbh[f] = *(const bf16x8*)&Bh[wn + 16 * f + l15][8 * g];
            fbl[f] = *(const bf16x8*)&Bl[wn + 16 * f + l15][8 * g];
        }
#pragma unroll
        for (int fm = 0; fm < 4; ++fm)
#pragma unroll
            for (int fn = 0; fn < 4; ++fn) {
                f32x4 a = acc[fm][fn];
                a = __builtin_amdgcn_mfma_f32_16x16x32_bf16(fah[fm], fbh[fn], a, 0, 0, 0);
                a = __builtin_amdgcn_mfma_f32_16x16x32_bf16(fah[fm], fbl[fn], a, 0, 0, 0);
                a = __builtin_amdgcn_mfma_f32_16x16x32_bf16(fal[fm], fbh[fn], a, 0, 0, 0);
                acc[fm][fn] = a;
            }
    }

    // LoRA epilogue + store
    float lb[8][4];
#pragma unroll
    for (int rr = 0; rr < 8; ++rr)
#pragma unroll
        for (int fn = 0; fn < 4; ++fn)
            lb[rr][fn] = Bu[(size_t)rr * HDIM + bcol + wn + 16 * fn + l15] * LSCALE;

#pragma unroll
    for (int fm = 0; fm < 4; ++fm) {
        float la[4][8];
#pragma unroll
        for (int r = 0; r < 4; ++r) {
            int row = brow + wm + 16 * fm + 4 * g + r;
            const float* lap = XA + (size_t)row * xa_stride + xa_off;
            fx4 q0 = *(const fx4*)lap;
            fx4 q1 = *(const fx4*)(lap + 4);
#pragma unroll
            for (int j = 0; j < 4; ++j) { la[r][j] = q0[j]; la[r][4 + j] = q1[j]; }
        }
#pragma unroll
        for (int fn = 0; fn < 4; ++fn)
#pragma unroll
            for (int r = 0; r < 4; ++r) {
                float sum = acc[fm][fn][r];
#pragma unroll
                for (int rr = 0; rr < 8; ++rr) sum += la[r][rr] * lb[rr][fn];
                size_t row = (size_t)(brow + wm + 16 * fm + 4 * g + r);
                int col = bcol + wn + 16 * fn + l15;
                if (OUTF32) ((float*)Ovp)[row * HDIM + col] = sum;
                else ((unsigned short*)Ovp)[row * HDIM + col] = f2bf(sum);
            }
    }
}

// ---------------------------------------------------------------------------
// flash attention, swapped-operand MFMA, in-register softmax.
// QBLK=64, 4 waves, wave owns 16 q-rows (q = lane&15).
// QK^T = mfma(K,Q): lane l15 holds q-row l15, c=16n+4g+r -> softmax needs
// only 2 shfl_xor per reduction. P kept in registers, redistributed to
// B-fragments with 16 bpermutes. PV = mfma(V,P): acc q=l15 (corr lane-local).
// K/V/mask double-buffered; global loads issued before compute, LDS writes
// after; one barrier per tile.
// ---------------------------------------------------------------------------
#define QBLK 64
#define KVB  64
#define NT   (SEQ / KVB)

__global__ __launch_bounds__(256, 4)
void attn_mfma_kernel(const unsigned short* __restrict__ Qg, const unsigned short* __restrict__ Kg,
                      const unsigned short* __restrict__ Vt, const float* __restrict__ mask,
                      unsigned short* __restrict__ Ch, unsigned short* __restrict__ Cl)
{
    int qt = blockIdx.x, h = blockIdx.y, b = blockIdx.z;
    int t    = threadIdx.x;
    int wid  = t >> 6;
    int lane = t & 63;
    int l15  = lane & 15;
    int g    = lane >> 4;

    __shared__ __align__(16) unsigned short Ks[2][64][72];
    __shared__ __align__(16) unsigned short Vs[2][64][72];   // Vs[d][s]
    __shared__ __align__(16) float Msd[2][64];

    // Q as B-fragment: col=q=l15, k=32kc+8g+j
    bf16x8 qa[2];
    const unsigned short* qp = Qg + (size_t)(b * SEQ + qt * QBLK + wid * 16) * HDIM + h * HD;
#pragma unroll
    for (int kc = 0; kc < 2; ++kc)
        qa[kc] = *(const bf16x8*)(qp + (size_t)l15 * HDIM + 32 * kc + 8 * g);

    float m_run = -1e30f, l_run = 0.f;
    f32x4 acc[4];
#pragma unroll
    for (int n = 0; n < 4; ++n) acc[n] = (f32x4){0.f, 0.f, 0.f, 0.f};

    const unsigned short* kp0 = Kg + (size_t)(b * SEQ) * HDIM + h * HD;
    const unsigned short* vt0 = Vt + (size_t)((b * NHEAD + h) * HD) * SEQ;

    // staging map: u in {t, t+256}: row r=u>>3 (0..63), col group cg=(u&7)*8
    int r0 = t >> 3,           c0 = (t & 7) * 8;
    int r1 = (t + 256) >> 3,   c1 = c0;   // (t+256)&7 == t&7

    // prologue: stage tile 0 into buffer 0
    *(us8*)&Ks[0][r0][c0] = *(const us8*)(kp0 + (size_t)r0 * HDIM + c0);
    *(us8*)&Ks[0][r1][c1] = *(const us8*)(kp0 + (size_t)r1 * HDIM + c1);
    *(us8*)&Vs[0][r0][c0] = *(const us8*)(vt0 + (size_t)r0 * SEQ + c0);
    *(us8*)&Vs[0][r1][c1] = *(const us8*)(vt0 + (size_t)r1 * SEQ + c1);
    if (t < 64) Msd[0][t] = (1.0f - mask[b * SEQ + t]) * -10000.0f;
    __syncthreads();

    int cur = 0;
    for (int kt = 0; kt < NT; ++kt) {
        // ---- issue next tile's global loads (hidden under compute) ----
        us8 knr0, knr1, vnr0, vnr1;
        float mreg = 1.0f;
        bool more = (kt + 1 < NT);
        if (more) {
            const unsigned short* kp = kp0 + (size_t)(kt + 1) * KVB * HDIM;
            const unsigned short* vp = vt0 + (kt + 1) * KVB;
            knr0 = *(const us8*)(kp + (size_t)r0 * HDIM + c0);
            knr1 = *(const us8*)(kp + (size_t)r1 * HDIM + c1);
            vnr0 = *(const us8*)(vp + (size_t)r0 * SEQ + c0);
            vnr1 = *(const us8*)(vp + (size_t)r1 * SEQ + c1);
            if (t < 64) mreg = mask[b * SEQ + (kt + 1) * KVB + t];
        }

        // ---- QK^T swapped: sT[n][r] = S[q=l15][c=16n+4g+r] ----
        f32x4 sT[4];
#pragma unroll
        for (int n = 0; n < 4; ++n) {
            f32x4 a = (f32x4){0.f, 0.f, 0.f, 0.f};
#pragma unroll
            for (int kc = 0; kc < 2; ++kc) {
                bf16x8 kb = *(const bf16x8*)&Ks[cur][16 * n + l15][32 * kc + 8 * g];
                a = __builtin_amdgcn_mfma_f32_16x16x32_bf16(kb, qa[kc], a, 0, 0, 0);
            }
            sT[n] = a;
        }

        // ---- scale + mask ----
#pragma unroll
        for (int n = 0; n < 4; ++n) {
            fx4 msk = *(const fx4*)&Msd[cur][16 * n + 4 * g];
#pragma unroll
            for (int r = 0; r < 4; ++r) sT[n][r] = fmaf(sT[n][r], 0.125f, msk[r]);
        }

        // ---- in-register online softmax (row q=l15; reduce across g only) ----
        float mx = sT[0][0];
#pragma unroll
        for (int n = 0; n < 4; ++n)
#pragma unroll
            for (int r = 0; r < 4; ++r) mx = fmaxf(mx, sT[n][r]);
        mx = fmaxf(mx, __shfl_xor(mx, 16, 64));
        mx = fmaxf(mx, __shfl_xor(mx, 32, 64));
        float mn = fmaxf(m_run, mx);
        float corr = __expf(m_run - mn);
        m_run = mn;
        float ls = 0.f;
#pragma unroll
        for (int n = 0; n < 4; ++n)
#pragma unroll
            for (int r = 0; r < 4; ++r) {
                float p = __expf(sT[n][r] - mn);
                sT[n][r] = p;
                ls += p;
            }
        ls += __shfl_xor(ls, 16, 64);
        ls += __shfl_xor(ls, 32, 64);
        l_run = l_run * corr + ls;
#pragma unroll
        for (int n = 0; n < 4; ++n)
#pragma unroll
            for (int r = 0; r < 4; ++r) acc[n][r] *= corr;

        // ---- pack P to bf16 dwords: pk[n] = {r0|r1<<16, r2|r3<<16} ----
        unsigned int pkx[4], pky[4];
#pragma unroll
        for (int n = 0; n < 4; ++n) {
            pkx[n] = (unsigned int)f2bf(sT[n][0]) | ((unsigned int)f2bf(sT[n][1]) << 16);
            pky[n] = (unsigned int)f2bf(sT[n][2]) | ((unsigned int)f2bf(sT[n][3]) << 16);
        }

        // ---- redistribute to B-fragment pb[kc]: P[q=l15][c=32kc+8g+j] ----
        // src lane for j<4: lA = l15 + 32*(g&1); j>=4: lB = lA + 16.
        // n* = 2kc + (g>>1) -> select between shfl(pk[2kc]) and shfl(pk[2kc+1]).
        int lA = l15 + 32 * (g & 1);
        int lB = lA + 16;
        bool selhi = (g & 2) != 0;
        bf16x8 pb[2];
#pragma unroll
        for (int kc = 0; kc < 2; ++kc) {
            unsigned int xA0 = __shfl((int)pkx[2 * kc], lA, 64);
            unsigned int yA0 = __shfl((int)pky[2 * kc], lA, 64);
            unsigned int xA1 = __shfl((int)pkx[2 * kc + 1], lA, 64);
            unsigned int yA1 = __shfl((int)pky[2 * kc + 1], lA, 64);
            unsigned int xB0 = __shfl((int)pkx[2 * kc], lB, 64);
            unsigned int yB0 = __shfl((int)pky[2 * kc], lB, 64);
            unsigned int xB1 = __shfl((int)pkx[2 * kc + 1], lB, 64);
            unsigned int yB1 = __shfl((int)pky[2 * kc + 1], lB, 64);
            u32x4 d;
            d[0] = selhi ? xA1 : xA0;
            d[1] = selhi ? yA1 : yA0;
            d[2] = selhi ? xB1 : xB0;
            d[3] = selhi ? yB1 : yB0;
            pb[kc] = *(bf16x8*)&d;
        }

        // ---- PV swapped: acc[n][r] = O[q=l15][dout=16n+4g+r] ----
#pragma unroll
        for (int n = 0; n < 4; ++n)
#pragma unroll
            for (int kc = 0; kc < 2; ++kc) {
                bf16x8 vb = *(const bf16x8*)&Vs[cur][16 * n + l15][32 * kc + 8 * g];
                acc[n] = __builtin_amdgcn_mfma_f32_16x16x32_bf16(vb, pb[kc], acc[n], 0, 0, 0);
            }

        // ---- write staged tile to other buffer, publish ----
        if (more) {
            *(us8*)&Ks[cur ^ 1][r0][c0] = knr0;
            *(us8*)&Ks[cur ^ 1][r1][c1] = knr1;
            *(us8*)&Vs[cur ^ 1][r0][c0] = vnr0;
            *(us8*)&Vs[cur ^ 1][r1][c1] = vnr1;
            if (t < 64) Msd[cur ^ 1][t] = (1.0f - mreg) * -10000.0f;
        }
        __syncthreads();
        cur ^= 1;
    }

    // ---- epilogue: q = l15, dout = 16n+4g+r ----
    float inv = 1.0f / l_run;
    size_t row = (size_t)(b * SEQ + qt * QBLK + wid * 16 + l15);
#pragma unroll
    for (int n = 0; n < 4; ++n) {
        us4 hv, lv;
#pragma unroll
        for (int r = 0; r < 4; ++r) {
            float o = acc[n][r] * inv;
            unsigned short hi = f2bf(o);
            hv[r] = hi;
            lv[r] = f2bf(o - bf2f(hi));
        }
        size_t idx = row * HDIM + h * HD + 16 * n + 4 * g;
        *(us4*)&Ch[idx] = hv;
        *(us4*)&Cl[idx] = lv;
    }
}

// ---------------------------------------------------------------------------
extern "C" void kernel_launch(void* const* d_in, const int* in_sizes, int n_in,
                              void* d_out, int out_size, void* d_ws, size_t ws_size,
                              hipStream_t stream)
{
    const float* hs   = (const float*)d_in[0];
    const float* mask = (const float*)d_in[1];
    const float* Wq = (const float*)d_in[2];
    const float* Wk = (const float*)d_in[3];
    const float* Wv = (const float*)d_in[4];
    const float* Wo = (const float*)d_in[5];
    const float* Aq = (const float*)d_in[6];
    const float* Bq = (const float*)d_in[7];
    const float* Ak = (const float*)d_in[8];
    const float* Bk = (const float*)d_in[9];
    const float* Av = (const float*)d_in[10];
    const float* Bv = (const float*)d_in[11];
    const float* Ao = (const float*)d_in[12];
    const float* Bo = (const float*)d_in[13];
    float* out = (float*)d_out;

    char* w = (char*)d_ws;
    unsigned short* Xh = (unsigned short*)(w);                       // 8 MB (later Ch)
    unsigned short* Xl = (unsigned short*)(w + ((size_t)8 << 20));   // 8 MB (later Cl)
    unsigned short* WT = (unsigned short*)(w + ((size_t)16 << 20));  // 16 MB (8 planes)
    unsigned short* qb = (unsigned short*)(w + ((size_t)32 << 20));  // 8 MB
    unsigned short* kb = (unsigned short*)(w + ((size_t)40 << 20));  // 8 MB
    unsigned short* vb = (unsigned short*)(w + ((size_t)48 << 20));  // 8 MB
    unsigned short* vt = (unsigned short*)(w + ((size_t)56 << 20));  // 8 MB
    float* hsA  = (float*)(w + ((size_t)64 << 20));                  // 4096*24*4
    float* ctxA = (float*)(w + ((size_t)64 << 20) + 400 * 1024);     // 4096*8*4

    split_x_kernel<<<2048, 256, 0, stream>>>(hs, Xh, Xl, MTOT * HDIM / 4);
    tsplit_w_kernel<<<dim3(16, 16, 4), 256, 0, stream>>>(Wq, Wk, Wv, Wo, WT);
    lora_down_kernel<<<MTOT, 64, 0, stream>>>(hs, Aq, Ak, Av, hsA, 3);
    gemm_mfma_kernel<false><<<dim3(8, 32, 3), 256, 0, stream>>>(
        Xh, Xl, WT, 0, hsA, 24, 0, Bq, Bk, Bv, qb, kb, vb);
    transpose_v_kernel<<<dim3(SEQ / 64, BATCH * NHEAD), 256, 0, stream>>>(vb, vt);
    attn_mfma_kernel<<<dim3(SEQ / QBLK, NHEAD, BATCH), 256, 0, stream>>>(
        qb, kb, vt, mask, Xh /*Ch*/, Xl /*Cl*/);
    lora_down_bf_kernel<<<MTOT, 64, 0, stream>>>(Xh, Xl, Ao, ctxA);
    gemm_mfma_kernel<true><<<dim3(8, 32, 1), 256, 0, stream>>>(
        Xh, Xl, WT, 3, ctxA, 8, 0, Bo, Bo, Bo, out, out, out);
}

// Round 8
// 254.793 us; speedup vs baseline: 4.1166x; 1.0181x over previous
//
#include <hip/hip_runtime.h>
#include <math.h>

typedef float fx4 __attribute__((ext_vector_type(4)));
typedef float f32x4 __attribute__((ext_vector_type(4)));
typedef short bf16x8 __attribute__((ext_vector_type(8)));
typedef unsigned short us4 __attribute__((ext_vector_type(4)));
typedef unsigned short us8 __attribute__((ext_vector_type(8)));
typedef unsigned int u32x4 __attribute__((ext_vector_type(4)));

#define HDIM 1024
#define SEQ  2048
#define BATCH 2
#define NHEAD 16
#define HD    64
#define MTOT  4096
#define LSCALE 8.0f
#define LOG2E 1.44269504088896340736f

__device__ __forceinline__ unsigned short f2bf(float f) {
    union { float f; unsigned int u; } v; v.f = f;
    unsigned int r = v.u + 0x7FFFu + ((v.u >> 16) & 1u);
    return (unsigned short)(r >> 16);
}
__device__ __forceinline__ float bf2f(unsigned short h) {
    union { unsigned int u; float f; } v; v.u = ((unsigned int)h) << 16;
    return v.f;
}
// packed bf16 convert: low16 = bf16(a), high16 = bf16(b), RNE
__device__ __forceinline__ unsigned int cvt_pk_bf16(float a, float b) {
    unsigned int r;
    asm("v_cvt_pk_bf16_f32 %0, %1, %2" : "=v"(r) : "v"(a), "v"(b));
    return r;
}

// ---------------------------------------------------------------------------
// split X (fp32) -> hi/lo bf16 planes
// ---------------------------------------------------------------------------
__global__ __launch_bounds__(256)
void split_x_kernel(const float* __restrict__ X, unsigned short* __restrict__ Xh,
                    unsigned short* __restrict__ Xl, int n4)
{
    int i = blockIdx.x * 256 + threadIdx.x;
    int stride = gridDim.x * 256;
    for (; i < n4; i += stride) {
        fx4 v = *((const fx4*)X + i);
        us4 h, l;
#pragma unroll
        for (int j = 0; j < 4; ++j) {
            h[j] = f2bf(v[j]);
            l[j] = f2bf(v[j] - bf2f(h[j]));
        }
        *((us4*)Xh + i) = h;
        *((us4*)Xl + i) = l;
    }
}

// ---------------------------------------------------------------------------
// transpose + split W [k][n] fp32 -> WT hi/lo bf16 [n][k]; z selects matrix.
// ---------------------------------------------------------------------------
__global__ __launch_bounds__(256)
void tsplit_w_kernel(const float* __restrict__ W0, const float* __restrict__ W1,
                     const float* __restrict__ W2, const float* __restrict__ W3,
                     unsigned short* __restrict__ WTbase)
{
    int z = blockIdx.z;
    const float* W = (z == 0) ? W0 : (z == 1) ? W1 : (z == 2) ? W2 : W3;
    unsigned short* WTh = WTbase + (size_t)z * 2097152;
    unsigned short* WTl = WTh + 1048576;
    int n0 = blockIdx.x * 64, k0 = blockIdx.y * 64;
    __shared__ unsigned int T[64][65];
    int t = threadIdx.x;
#pragma unroll
    for (int i = 0; i < 4; ++i) {
        int idx = t + 256 * i;
        int r = idx >> 4, c4 = (idx & 15) * 4;
        fx4 w = *(const fx4*)&W[(size_t)(k0 + r) * HDIM + n0 + c4];
#pragma unroll
        for (int j = 0; j < 4; ++j) {
            unsigned short hi = f2bf(w[j]);
            unsigned short lo = f2bf(w[j] - bf2f(hi));
            T[r][c4 + j] = (unsigned int)hi | ((unsigned int)lo << 16);
        }
    }
    __syncthreads();
#pragma unroll
    for (int i = 0; i < 4; ++i) {
        int idx = t + 256 * i;
        int n = idx >> 4, kg = (idx & 15) * 4;
        us4 hv, lv;
#pragma unroll
        for (int j = 0; j < 4; ++j) {
            unsigned int p = T[kg + j][n];
            hv[j] = (unsigned short)(p & 0xffffu);
            lv[j] = (unsigned short)(p >> 16);
        }
        *(us4*)&WTh[(size_t)(n0 + n) * HDIM + k0 + kg] = hv;
        *(us4*)&WTl[(size_t)(n0 + n) * HDIM + k0 + kg] = lv;
    }
}

// ---------------------------------------------------------------------------
// transpose V: vb [4096][1024] bf16 -> vt [(b*16+h)*64+d][2048] bf16
// ---------------------------------------------------------------------------
__global__ __launch_bounds__(256)
void transpose_v_kernel(const unsigned short* __restrict__ vb,
                        unsigned short* __restrict__ vt)
{
    int s0 = blockIdx.x * 64;
    int bh = blockIdx.y;               // b*16+h
    int b = bh >> 4, h = bh & 15;
    __shared__ unsigned short T[64][80];
    int t = threadIdx.x;
#pragma unroll
    for (int i = 0; i < 2; ++i) {
        int u = t + 256 * i;
        int r = u >> 3, cg = u & 7;
        us8 v = *(const us8*)&vb[(size_t)(b * SEQ + s0 + r) * HDIM + h * HD + 8 * cg];
        *(us8*)&T[r][8 * cg] = v;
    }
    __syncthreads();
#pragma unroll
    for (int i = 0; i < 2; ++i) {
        int u = t + 256 * i;
        int d = u & 63, sg = u >> 6;
        us8 v;
#pragma unroll
        for (int j = 0; j < 8; ++j) v[j] = T[8 * sg + j][d];
        *(us8*)&vt[(size_t)(bh * HD + d) * SEQ + s0 + 8 * sg] = v;
    }
}

// ---------------------------------------------------------------------------
// lora down: fp32 X; XA = X @ [A0|A1|A2]; out row stride 24
// ---------------------------------------------------------------------------
__global__ __launch_bounds__(64)
void lora_down_kernel(const float* __restrict__ X,
                      const float* __restrict__ A0,
                      const float* __restrict__ A1,
                      const float* __restrict__ A2,
                      float* __restrict__ out, int nmat)
{
    int row  = blockIdx.x;
    int lane = threadIdx.x;
    const float* xr = X + (size_t)row * HDIM;
    float xv[16];
#pragma unroll
    for (int i = 0; i < 16; ++i) xv[i] = xr[lane + 64 * i];
    const float* Amats[3] = {A0, A1, A2};
    for (int m = 0; m < nmat; ++m) {
        const float* A = Amats[m];
        float s[8];
#pragma unroll
        for (int c = 0; c < 8; ++c) s[c] = 0.f;
#pragma unroll
        for (int i = 0; i < 16; ++i) {
            const float* ap = A + (size_t)(lane + 64 * i) * 8;
#pragma unroll
            for (int c = 0; c < 8; ++c) s[c] += xv[i] * ap[c];
        }
#pragma unroll
        for (int c = 0; c < 8; ++c) {
#pragma unroll
            for (int off = 1; off < 64; off <<= 1)
                s[c] += __shfl_xor(s[c], off, 64);
        }
        if (lane == 0) {
#pragma unroll
            for (int c = 0; c < 8; ++c)
                out[(size_t)row * 24 + m * 8 + c] = s[c];
        }
    }
}

// lora down from hi/lo bf16 planes (ctx); out stride 8
__global__ __launch_bounds__(64)
void lora_down_bf_kernel(const unsigned short* __restrict__ Xh,
                         const unsigned short* __restrict__ Xl,
                         const float* __restrict__ A,
                         float* __restrict__ out)
{
    int row  = blockIdx.x;
    int lane = threadIdx.x;
    const unsigned short* xh = Xh + (size_t)row * HDIM;
    const unsigned short* xl = Xl + (size_t)row * HDIM;
    float xv[16];
#pragma unroll
    for (int i = 0; i < 16; ++i)
        xv[i] = bf2f(xh[lane + 64 * i]) + bf2f(xl[lane + 64 * i]);
    float s[8];
#pragma unroll
    for (int c = 0; c < 8; ++c) s[c] = 0.f;
#pragma unroll
    for (int i = 0; i < 16; ++i) {
        const float* ap = A + (size_t)(lane + 64 * i) * 8;
#pragma unroll
        for (int c = 0; c < 8; ++c) s[c] += xv[i] * ap[c];
    }
#pragma unroll
    for (int c = 0; c < 8; ++c) {
#pragma unroll
        for (int off = 1; off < 64; off <<= 1)
            s[c] += __shfl_xor(s[c], off, 64);
    }
    if (lane == 0) {
#pragma unroll
        for (int c = 0; c < 8; ++c) out[(size_t)row * 8 + c] = s[c];
    }
}

// ---------------------------------------------------------------------------
// split-bf16 MFMA GEMM: Out = X@W + LSCALE*(XA)@Bu
// BM=128: 4 waves 2x2 of 64x64 (FN=4).  BM=64: 4 waves 1x4 of 64x32 (FN=2).
// ---------------------------------------------------------------------------
template<bool OUTF32, int BM>
__global__ __launch_bounds__(256, BM == 128 ? 2 : 3)
void gemm_mfma_kernel(const unsigned short* __restrict__ Xh, const unsigned short* __restrict__ Xl,
                      const unsigned short* __restrict__ WTbase, int wsel0,
                      const float* __restrict__ XA, int xa_stride, int xa_off0,
                      const float* __restrict__ Bu0, const float* __restrict__ Bu1, const float* __restrict__ Bu2,
                      void* __restrict__ O0, void* __restrict__ O1, void* __restrict__ O2)
{
    constexpr int FN = (BM == 128) ? 4 : 2;
    int pz = blockIdx.z;
    const unsigned short* WTh = WTbase + (size_t)(wsel0 + pz) * 2097152;
    const unsigned short* WTl = WTh + 1048576;
    const float* Bu = (pz == 0) ? Bu0 : (pz == 1) ? Bu1 : Bu2;
    void* Ovp       = (pz == 0) ? O0 : (pz == 1) ? O1 : O2;
    int xa_off = xa_off0 + pz * 8;

    int brow = blockIdx.y * BM, bcol = blockIdx.x * 128;
    int t = threadIdx.x, wid = t >> 6, lane = t & 63, l15 = lane & 15, g = lane >> 4;
    int wm = (BM == 128) ? (wid >> 1) * 64 : 0;
    int wn = (BM == 128) ? (wid & 1) * 64 : wid * 32;

    __shared__ unsigned short Ah[BM][40];
    __shared__ unsigned short Al[BM][40];
    __shared__ unsigned short Bh[128][40];
    __shared__ unsigned short Bl[128][40];

    f32x4 acc[4][FN];
#pragma unroll
    for (int i = 0; i < 4; ++i)
#pragma unroll
        for (int j = 0; j < FN; ++j) acc[i][j] = (f32x4){0.f, 0.f, 0.f, 0.f};

    int sm = t >> 2, skg = t & 3;
    const unsigned short* aH0 = Xh  + (size_t)(brow + sm) * HDIM + 8 * skg;
    const unsigned short* aL0 = Xl  + (size_t)(brow + sm) * HDIM + 8 * skg;
    const unsigned short* bH0 = WTh + (size_t)(bcol + sm) * HDIM + 8 * skg;
    const unsigned short* bL0 = WTl + (size_t)(bcol + sm) * HDIM + 8 * skg;
    const size_t R64 = (size_t)64 * HDIM;

    us8 rAH0, rAH1, rAL0, rAL1, rBH0, rBH1, rBL0, rBL1;
    rAH0 = *(const us8*)(aH0);
    rAL0 = *(const us8*)(aL0);
    if (BM == 128) {
        rAH1 = *(const us8*)(aH0 + R64);
        rAL1 = *(const us8*)(aL0 + R64);
    }
    rBH0 = *(const us8*)(bH0);
    rBH1 = *(const us8*)(bH0 + R64);
    rBL0 = *(const us8*)(bL0);
    rBL1 = *(const us8*)(bL0 + R64);

    for (int k0 = 0; k0 < HDIM; k0 += 32) {
        __syncthreads();
        *(us8*)&Ah[sm][8 * skg] = rAH0;
        *(us8*)&Al[sm][8 * skg] = rAL0;
        if (BM == 128) {
            *(us8*)&Ah[(sm + 64) & (BM - 1)][8 * skg] = rAH1;
            *(us8*)&Al[(sm + 64) & (BM - 1)][8 * skg] = rAL1;
        }
        *(us8*)&Bh[sm][8 * skg]      = rBH0;
        *(us8*)&Bh[sm + 64][8 * skg] = rBH1;
        *(us8*)&Bl[sm][8 * skg]      = rBL0;
        *(us8*)&Bl[sm + 64][8 * skg] = rBL1;
        __syncthreads();
        if (k0 + 32 < HDIM) {
            int ko = k0 + 32;
            rAH0 = *(const us8*)(aH0 + ko);
            rAL0 = *(const us8*)(aL0 + ko);
            if (BM == 128) {
                rAH1 = *(const us8*)(aH0 + R64 + ko);
                rAL1 = *(const us8*)(aL0 + R64 + ko);
            }
            rBH0 = *(const us8*)(bH0 + ko);
            rBH1 = *(const us8*)(bH0 + R64 + ko);
            rBL0 = *(const us8*)(bL0 + ko);
            rBL1 = *(const us8*)(bL0 + R64 + ko);
        }
        bf16x8 fah[4], fal[4], fbh[FN], fbl[FN];
#pragma unroll
        for (int f = 0; f < 4; ++f) {
            fah[f] = *(const bf16x8*)&Ah[wm + 16 * f + l15][8 * g];
            fal[f] = *(const bf16x8*)&Al[wm + 16 * f + l15][8 * g];
        }
#pragma unroll
        for (int f = 0; f < FN; ++f) {
            fbh[f] = *(const bf16x8*)&Bh[wn + 16 * f + l15][8 * g];
            fbl[f] = *(const bf16x8*)&Bl[wn + 16 * f + l15][8 * g];
        }
#pragma unroll
        for (int fm = 0; fm < 4; ++fm)
#pragma unroll
            for (int fn = 0; fn < FN; ++fn) {
                f32x4 a = acc[fm][fn];
                a = __builtin_amdgcn_mfma_f32_16x16x32_bf16(fah[fm], fbh[fn], a, 0, 0, 0);
                a = __builtin_amdgcn_mfma_f32_16x16x32_bf16(fah[fm], fbl[fn], a, 0, 0, 0);
                a = __builtin_amdgcn_mfma_f32_16x16x32_bf16(fal[fm], fbh[fn], a, 0, 0, 0);
                acc[fm][fn] = a;
            }
    }

    // LoRA epilogue + store
    float lb[8][FN];
#pragma unroll
    for (int rr = 0; rr < 8; ++rr)
#pragma unroll
        for (int fn = 0; fn < FN; ++fn)
            lb[rr][fn] = Bu[(size_t)rr * HDIM + bcol + wn + 16 * fn + l15] * LSCALE;

#pragma unroll
    for (int fm = 0; fm < 4; ++fm) {
        float la[4][8];
#pragma unroll
        for (int r = 0; r < 4; ++r) {
            int row = brow + wm + 16 * fm + 4 * g + r;
            const float* lap = XA + (size_t)row * xa_stride + xa_off;
            fx4 q0 = *(const fx4*)lap;
            fx4 q1 = *(const fx4*)(lap + 4);
#pragma unroll
            for (int j = 0; j < 4; ++j) { la[r][j] = q0[j]; la[r][4 + j] = q1[j]; }
        }
#pragma unroll
        for (int fn = 0; fn < FN; ++fn)
#pragma unroll
            for (int r = 0; r < 4; ++r) {
                float sum = acc[fm][fn][r];
#pragma unroll
                for (int rr = 0; rr < 8; ++rr) sum += la[r][rr] * lb[rr][fn];
                size_t row = (size_t)(brow + wm + 16 * fm + 4 * g + r);
                int col = bcol + wn + 16 * fn + l15;
                if (OUTF32) ((float*)Ovp)[row * HDIM + col] = sum;
                else ((unsigned short*)Ovp)[row * HDIM + col] = f2bf(sum);
            }
    }
}

// ---------------------------------------------------------------------------
// flash attention, swapped-operand MFMA, in-register softmax (exp2 domain),
// cvt_pk_bf16 P-pack. QBLK=64, 4 waves, wave owns 16 q-rows (q = lane&15).
// ---------------------------------------------------------------------------
#define QBLK 64
#define KVB  64
#define NT   (SEQ / KVB)

__global__ __launch_bounds__(256, 4)
void attn_mfma_kernel(const unsigned short* __restrict__ Qg, const unsigned short* __restrict__ Kg,
                      const unsigned short* __restrict__ Vt, const float* __restrict__ mask,
                      unsigned short* __restrict__ Ch, unsigned short* __restrict__ Cl)
{
    int qt = blockIdx.x, h = blockIdx.y, b = blockIdx.z;
    int t    = threadIdx.x;
    int wid  = t >> 6;
    int lane = t & 63;
    int l15  = lane & 15;
    int g    = lane >> 4;

    __shared__ __align__(16) unsigned short Ks[2][64][72];
    __shared__ __align__(16) unsigned short Vs[2][64][72];   // Vs[d][s]
    __shared__ __align__(16) float Msd[2][64];

    // Q as B-fragment: col=q=l15, k=32kc+8g+j
    bf16x8 qa[2];
    const unsigned short* qp = Qg + (size_t)(b * SEQ + qt * QBLK + wid * 16) * HDIM + h * HD;
#pragma unroll
    for (int kc = 0; kc < 2; ++kc)
        qa[kc] = *(const bf16x8*)(qp + (size_t)l15 * HDIM + 32 * kc + 8 * g);

    float m_run = -1e30f, l_run = 0.f;   // m_run in log2 domain
    f32x4 acc[4];
#pragma unroll
    for (int n = 0; n < 4; ++n) acc[n] = (f32x4){0.f, 0.f, 0.f, 0.f};

    const unsigned short* kp0 = Kg + (size_t)(b * SEQ) * HDIM + h * HD;
    const unsigned short* vt0 = Vt + (size_t)((b * NHEAD + h) * HD) * SEQ;

    const float QSCL = 0.125f * LOG2E;
    const float MSCL = -10000.0f * LOG2E;

    int r0 = t >> 3,           c0 = (t & 7) * 8;
    int r1 = (t + 256) >> 3,   c1 = c0;

    // prologue: stage tile 0 into buffer 0
    *(us8*)&Ks[0][r0][c0] = *(const us8*)(kp0 + (size_t)r0 * HDIM + c0);
    *(us8*)&Ks[0][r1][c1] = *(const us8*)(kp0 + (size_t)r1 * HDIM + c1);
    *(us8*)&Vs[0][r0][c0] = *(const us8*)(vt0 + (size_t)r0 * SEQ + c0);
    *(us8*)&Vs[0][r1][c1] = *(const us8*)(vt0 + (size_t)r1 * SEQ + c1);
    if (t < 64) Msd[0][t] = (1.0f - mask[b * SEQ + t]) * MSCL;
    __syncthreads();

    int cur = 0;
    for (int kt = 0; kt < NT; ++kt) {
        us8 knr0, knr1, vnr0, vnr1;
        float mreg = 1.0f;
        bool more = (kt + 1 < NT);
        if (more) {
            const unsigned short* kp = kp0 + (size_t)(kt + 1) * KVB * HDIM;
            const unsigned short* vp = vt0 + (kt + 1) * KVB;
            knr0 = *(const us8*)(kp + (size_t)r0 * HDIM + c0);
            knr1 = *(const us8*)(kp + (size_t)r1 * HDIM + c1);
            vnr0 = *(const us8*)(vp + (size_t)r0 * SEQ + c0);
            vnr1 = *(const us8*)(vp + (size_t)r1 * SEQ + c1);
            if (t < 64) mreg = mask[b * SEQ + (kt + 1) * KVB + t];
        }

        // ---- QK^T swapped: sT[n][r] = S[q=l15][c=16n+4g+r] (log2 units) ----
        f32x4 sT[4];
#pragma unroll
        for (int n = 0; n < 4; ++n) {
            f32x4 a = (f32x4){0.f, 0.f, 0.f, 0.f};
#pragma unroll
            for (int kc = 0; kc < 2; ++kc) {
                bf16x8 kb = *(const bf16x8*)&Ks[cur][16 * n + l15][32 * kc + 8 * g];
                a = __builtin_amdgcn_mfma_f32_16x16x32_bf16(kb, qa[kc], a, 0, 0, 0);
            }
            sT[n] = a;
        }

#pragma unroll
        for (int n = 0; n < 4; ++n) {
            fx4 msk = *(const fx4*)&Msd[cur][16 * n + 4 * g];
#pragma unroll
            for (int r = 0; r < 4; ++r) sT[n][r] = fmaf(sT[n][r], QSCL, msk[r]);
        }

        // ---- in-register online softmax (row q=l15; reduce across g) ----
        float mx = sT[0][0];
#pragma unroll
        for (int n = 0; n < 4; ++n)
#pragma unroll
            for (int r = 0; r < 4; ++r) mx = fmaxf(mx, sT[n][r]);
        mx = fmaxf(mx, __shfl_xor(mx, 16, 64));
        mx = fmaxf(mx, __shfl_xor(mx, 32, 64));
        float mn = fmaxf(m_run, mx);
        float corr = exp2f(m_run - mn);
        m_run = mn;
        float ls = 0.f;
#pragma unroll
        for (int n = 0; n < 4; ++n)
#pragma unroll
            for (int r = 0; r < 4; ++r) {
                float p = exp2f(sT[n][r] - mn);
                sT[n][r] = p;
                ls += p;
            }
        ls += __shfl_xor(ls, 16, 64);
        ls += __shfl_xor(ls, 32, 64);
        l_run = l_run * corr + ls;
#pragma unroll
        for (int n = 0; n < 4; ++n)
#pragma unroll
            for (int r = 0; r < 4; ++r) acc[n][r] *= corr;

        // ---- pack P to bf16 dwords via v_cvt_pk_bf16_f32 ----
        unsigned int pkx[4], pky[4];
#pragma unroll
        for (int n = 0; n < 4; ++n) {
            pkx[n] = cvt_pk_bf16(sT[n][0], sT[n][1]);
            pky[n] = cvt_pk_bf16(sT[n][2], sT[n][3]);
        }

        // ---- redistribute to B-fragment pb[kc]: P[q=l15][c=32kc+8g+j] ----
        int lA = l15 + 32 * (g & 1);
        int lB = lA + 16;
        bool selhi = (g & 2) != 0;
        bf16x8 pb[2];
#pragma unroll
        for (int kc = 0; kc < 2; ++kc) {
            unsigned int xA0 = __shfl((int)pkx[2 * kc], lA, 64);
            unsigned int yA0 = __shfl((int)pky[2 * kc], lA, 64);
            unsigned int xA1 = __shfl((int)pkx[2 * kc + 1], lA, 64);
            unsigned int yA1 = __shfl((int)pky[2 * kc + 1], lA, 64);
            unsigned int xB0 = __shfl((int)pkx[2 * kc], lB, 64);
            unsigned int yB0 = __shfl((int)pky[2 * kc], lB, 64);
            unsigned int xB1 = __shfl((int)pkx[2 * kc + 1], lB, 64);
            unsigned int yB1 = __shfl((int)pky[2 * kc + 1], lB, 64);
            u32x4 d;
            d[0] = selhi ? xA1 : xA0;
            d[1] = selhi ? yA1 : yA0;
            d[2] = selhi ? xB1 : xB0;
            d[3] = selhi ? yB1 : yB0;
            pb[kc] = *(bf16x8*)&d;
        }

        // ---- PV swapped: acc[n][r] = O[q=l15][dout=16n+4g+r] ----
#pragma unroll
        for (int n = 0; n < 4; ++n)
#pragma unroll
            for (int kc = 0; kc < 2; ++kc) {
                bf16x8 vb = *(const bf16x8*)&Vs[cur][16 * n + l15][32 * kc + 8 * g];
                acc[n] = __builtin_amdgcn_mfma_f32_16x16x32_bf16(vb, pb[kc], acc[n], 0, 0, 0);
            }

        if (more) {
            *(us8*)&Ks[cur ^ 1][r0][c0] = knr0;
            *(us8*)&Ks[cur ^ 1][r1][c1] = knr1;
            *(us8*)&Vs[cur ^ 1][r0][c0] = vnr0;
            *(us8*)&Vs[cur ^ 1][r1][c1] = vnr1;
            if (t < 64) Msd[cur ^ 1][t] = (1.0f - mreg) * MSCL;
        }
        __syncthreads();
        cur ^= 1;
    }

    // ---- epilogue ----
    float inv = 1.0f / l_run;
    size_t row = (size_t)(b * SEQ + qt * QBLK + wid * 16 + l15);
#pragma unroll
    for (int n = 0; n < 4; ++n) {
        us4 hv, lv;
#pragma unroll
        for (int r = 0; r < 4; ++r) {
            float o = acc[n][r] * inv;
            unsigned short hi = f2bf(o);
            hv[r] = hi;
            lv[r] = f2bf(o - bf2f(hi));
        }
        size_t idx = row * HDIM + h * HD + 16 * n + 4 * g;
        *(us4*)&Ch[idx] = hv;
        *(us4*)&Cl[idx] = lv;
    }
}

// ---------------------------------------------------------------------------
extern "C" void kernel_launch(void* const* d_in, const int* in_sizes, int n_in,
                              void* d_out, int out_size, void* d_ws, size_t ws_size,
                              hipStream_t stream)
{
    const float* hs   = (const float*)d_in[0];
    const float* mask = (const float*)d_in[1];
    const float* Wq = (const float*)d_in[2];
    const float* Wk = (const float*)d_in[3];
    const float* Wv = (const float*)d_in[4];
    const float* Wo = (const float*)d_in[5];
    const float* Aq = (const float*)d_in[6];
    const float* Bq = (const float*)d_in[7];
    const float* Ak = (const float*)d_in[8];
    const float* Bk = (const float*)d_in[9];
    const float* Av = (const float*)d_in[10];
    const float* Bv = (const float*)d_in[11];
    const float* Ao = (const float*)d_in[12];
    const float* Bo = (const float*)d_in[13];
    float* out = (float*)d_out;

    char* w = (char*)d_ws;
    unsigned short* Xh = (unsigned short*)(w);                       // 8 MB (later Ch)
    unsigned short* Xl = (unsigned short*)(w + ((size_t)8 << 20));   // 8 MB (later Cl)
    unsigned short* WT = (unsigned short*)(w + ((size_t)16 << 20));  // 16 MB (8 planes)
    unsigned short* qb = (unsigned short*)(w + ((size_t)32 << 20));  // 8 MB
    unsigned short* kb = (unsigned short*)(w + ((size_t)40 << 20));  // 8 MB
    unsigned short* vb = (unsigned short*)(w + ((size_t)48 << 20));  // 8 MB
    unsigned short* vt = (unsigned short*)(w + ((size_t)56 << 20));  // 8 MB
    float* hsA  = (float*)(w + ((size_t)64 << 20));                  // 4096*24*4
    float* ctxA = (float*)(w + ((size_t)64 << 20) + 400 * 1024);     // 4096*8*4

    split_x_kernel<<<2048, 256, 0, stream>>>(hs, Xh, Xl, MTOT * HDIM / 4);
    tsplit_w_kernel<<<dim3(16, 16, 4), 256, 0, stream>>>(Wq, Wk, Wv, Wo, WT);
    lora_down_kernel<<<MTOT, 64, 0, stream>>>(hs, Aq, Ak, Av, hsA, 3);
    gemm_mfma_kernel<false, 128><<<dim3(8, 32, 3), 256, 0, stream>>>(
        Xh, Xl, WT, 0, hsA, 24, 0, Bq, Bk, Bv, qb, kb, vb);
    transpose_v_kernel<<<dim3(SEQ / 64, BATCH * NHEAD), 256, 0, stream>>>(vb, vt);
    attn_mfma_kernel<<<dim3(SEQ / QBLK, NHEAD, BATCH), 256, 0, stream>>>(
        qb, kb, vt, mask, Xh /*Ch*/, Xl /*Cl*/);
    lora_down_bf_kernel<<<MTOT, 64, 0, stream>>>(Xh, Xl, Ao, ctxA);
    gemm_mfma_kernel<true, 64><<<dim3(8, 64, 1), 256, 0, stream>>>(
        Xh, Xl, WT, 3, ctxA, 8, 0, Bo, Bo, Bo, out, out, out);
}

// Round 9
// 245.432 us; speedup vs baseline: 4.2736x; 1.0381x over previous
//
#include <hip/hip_runtime.h>
#include <math.h>

typedef float fx4 __attribute__((ext_vector_type(4)));
typedef float f32x4 __attribute__((ext_vector_type(4)));
typedef short bf16x8 __attribute__((ext_vector_type(8)));
typedef unsigned short us4 __attribute__((ext_vector_type(4)));
typedef unsigned short us8 __attribute__((ext_vector_type(8)));
typedef unsigned int u32x4 __attribute__((ext_vector_type(4)));

#define HDIM 1024
#define SEQ  2048
#define BATCH 2
#define NHEAD 16
#define HD    64
#define MTOT  4096
#define LSCALE 8.0f
#define LOG2E 1.44269504088896340736f

__device__ __forceinline__ unsigned short f2bf(float f) {
    union { float f; unsigned int u; } v; v.f = f;
    unsigned int r = v.u + 0x7FFFu + ((v.u >> 16) & 1u);
    return (unsigned short)(r >> 16);
}
__device__ __forceinline__ float bf2f(unsigned short h) {
    union { unsigned int u; float f; } v; v.u = ((unsigned int)h) << 16;
    return v.f;
}
// packed bf16 convert: low16 = bf16(a), high16 = bf16(b), RNE
__device__ __forceinline__ unsigned int cvt_pk_bf16(float a, float b) {
    unsigned int r;
    asm("v_cvt_pk_bf16_f32 %0, %1, %2" : "=v"(r) : "v"(a), "v"(b));
    return r;
}

// ---------------------------------------------------------------------------
// split X (fp32) -> hi/lo bf16 planes
// ---------------------------------------------------------------------------
__global__ __launch_bounds__(256)
void split_x_kernel(const float* __restrict__ X, unsigned short* __restrict__ Xh,
                    unsigned short* __restrict__ Xl, int n4)
{
    int i = blockIdx.x * 256 + threadIdx.x;
    int stride = gridDim.x * 256;
    for (; i < n4; i += stride) {
        fx4 v = *((const fx4*)X + i);
        us4 h, l;
#pragma unroll
        for (int j = 0; j < 4; ++j) {
            h[j] = f2bf(v[j]);
            l[j] = f2bf(v[j] - bf2f(h[j]));
        }
        *((us4*)Xh + i) = h;
        *((us4*)Xl + i) = l;
    }
}

// ---------------------------------------------------------------------------
// transpose + split W [k][n] fp32 -> WT hi/lo bf16 [n][k]; z selects matrix.
// ---------------------------------------------------------------------------
__global__ __launch_bounds__(256)
void tsplit_w_kernel(const float* __restrict__ W0, const float* __restrict__ W1,
                     const float* __restrict__ W2, const float* __restrict__ W3,
                     unsigned short* __restrict__ WTbase)
{
    int z = blockIdx.z;
    const float* W = (z == 0) ? W0 : (z == 1) ? W1 : (z == 2) ? W2 : W3;
    unsigned short* WTh = WTbase + (size_t)z * 2097152;
    unsigned short* WTl = WTh + 1048576;
    int n0 = blockIdx.x * 64, k0 = blockIdx.y * 64;
    __shared__ unsigned int T[64][65];
    int t = threadIdx.x;
#pragma unroll
    for (int i = 0; i < 4; ++i) {
        int idx = t + 256 * i;
        int r = idx >> 4, c4 = (idx & 15) * 4;
        fx4 w = *(const fx4*)&W[(size_t)(k0 + r) * HDIM + n0 + c4];
#pragma unroll
        for (int j = 0; j < 4; ++j) {
            unsigned short hi = f2bf(w[j]);
            unsigned short lo = f2bf(w[j] - bf2f(hi));
            T[r][c4 + j] = (unsigned int)hi | ((unsigned int)lo << 16);
        }
    }
    __syncthreads();
#pragma unroll
    for (int i = 0; i < 4; ++i) {
        int idx = t + 256 * i;
        int n = idx >> 4, kg = (idx & 15) * 4;
        us4 hv, lv;
#pragma unroll
        for (int j = 0; j < 4; ++j) {
            unsigned int p = T[kg + j][n];
            hv[j] = (unsigned short)(p & 0xffffu);
            lv[j] = (unsigned short)(p >> 16);
        }
        *(us4*)&WTh[(size_t)(n0 + n) * HDIM + k0 + kg] = hv;
        *(us4*)&WTl[(size_t)(n0 + n) * HDIM + k0 + kg] = lv;
    }
}

// ---------------------------------------------------------------------------
// transpose V: vb [4096][1024] bf16 -> vt [(b*16+h)*64+d][2048] bf16
// ---------------------------------------------------------------------------
__global__ __launch_bounds__(256)
void transpose_v_kernel(const unsigned short* __restrict__ vb,
                        unsigned short* __restrict__ vt)
{
    int s0 = blockIdx.x * 64;
    int bh = blockIdx.y;               // b*16+h
    int b = bh >> 4, h = bh & 15;
    __shared__ unsigned short T[64][80];
    int t = threadIdx.x;
#pragma unroll
    for (int i = 0; i < 2; ++i) {
        int u = t + 256 * i;
        int r = u >> 3, cg = u & 7;
        us8 v = *(const us8*)&vb[(size_t)(b * SEQ + s0 + r) * HDIM + h * HD + 8 * cg];
        *(us8*)&T[r][8 * cg] = v;
    }
    __syncthreads();
#pragma unroll
    for (int i = 0; i < 2; ++i) {
        int u = t + 256 * i;
        int d = u & 63, sg = u >> 6;
        us8 v;
#pragma unroll
        for (int j = 0; j < 8; ++j) v[j] = T[8 * sg + j][d];
        *(us8*)&vt[(size_t)(bh * HD + d) * SEQ + s0 + 8 * sg] = v;
    }
}

// ---------------------------------------------------------------------------
// lora down: fp32 X; XA = X @ [A0|A1|A2]; out row stride 24
// ---------------------------------------------------------------------------
__global__ __launch_bounds__(64)
void lora_down_kernel(const float* __restrict__ X,
                      const float* __restrict__ A0,
                      const float* __restrict__ A1,
                      const float* __restrict__ A2,
                      float* __restrict__ out, int nmat)
{
    int row  = blockIdx.x;
    int lane = threadIdx.x;
    const float* xr = X + (size_t)row * HDIM;
    float xv[16];
#pragma unroll
    for (int i = 0; i < 16; ++i) xv[i] = xr[lane + 64 * i];
    const float* Amats[3] = {A0, A1, A2};
    for (int m = 0; m < nmat; ++m) {
        const float* A = Amats[m];
        float s[8];
#pragma unroll
        for (int c = 0; c < 8; ++c) s[c] = 0.f;
#pragma unroll
        for (int i = 0; i < 16; ++i) {
            const float* ap = A + (size_t)(lane + 64 * i) * 8;
#pragma unroll
            for (int c = 0; c < 8; ++c) s[c] += xv[i] * ap[c];
        }
#pragma unroll
        for (int c = 0; c < 8; ++c) {
#pragma unroll
            for (int off = 1; off < 64; off <<= 1)
                s[c] += __shfl_xor(s[c], off, 64);
        }
        if (lane == 0) {
#pragma unroll
            for (int c = 0; c < 8; ++c)
                out[(size_t)row * 24 + m * 8 + c] = s[c];
        }
    }
}

// lora down from hi/lo bf16 planes (ctx); out stride 8
__global__ __launch_bounds__(64)
void lora_down_bf_kernel(const unsigned short* __restrict__ Xh,
                         const unsigned short* __restrict__ Xl,
                         const float* __restrict__ A,
                         float* __restrict__ out)
{
    int row  = blockIdx.x;
    int lane = threadIdx.x;
    const unsigned short* xh = Xh + (size_t)row * HDIM;
    const unsigned short* xl = Xl + (size_t)row * HDIM;
    float xv[16];
#pragma unroll
    for (int i = 0; i < 16; ++i)
        xv[i] = bf2f(xh[lane + 64 * i]) + bf2f(xl[lane + 64 * i]);
    float s[8];
#pragma unroll
    for (int c = 0; c < 8; ++c) s[c] = 0.f;
#pragma unroll
    for (int i = 0; i < 16; ++i) {
        const float* ap = A + (size_t)(lane + 64 * i) * 8;
#pragma unroll
        for (int c = 0; c < 8; ++c) s[c] += xv[i] * ap[c];
    }
#pragma unroll
    for (int c = 0; c < 8; ++c) {
#pragma unroll
        for (int off = 1; off < 64; off <<= 1)
            s[c] += __shfl_xor(s[c], off, 64);
    }
    if (lane == 0) {
#pragma unroll
        for (int c = 0; c < 8; ++c) out[(size_t)row * 8 + c] = s[c];
    }
}

// ---------------------------------------------------------------------------
// split-bf16 MFMA GEMM: Out = X@W + LSCALE*(XA)@Bu
// BM=128: 4 waves 2x2 of 64x64 (FN=4).  BM=64: 4 waves 1x4 of 64x32 (FN=2).
// ---------------------------------------------------------------------------
template<bool OUTF32, int BM>
__global__ __launch_bounds__(256, BM == 128 ? 2 : 3)
void gemm_mfma_kernel(const unsigned short* __restrict__ Xh, const unsigned short* __restrict__ Xl,
                      const unsigned short* __restrict__ WTbase, int wsel0,
                      const float* __restrict__ XA, int xa_stride, int xa_off0,
                      const float* __restrict__ Bu0, const float* __restrict__ Bu1, const float* __restrict__ Bu2,
                      void* __restrict__ O0, void* __restrict__ O1, void* __restrict__ O2)
{
    constexpr int FN = (BM == 128) ? 4 : 2;
    int pz = blockIdx.z;
    const unsigned short* WTh = WTbase + (size_t)(wsel0 + pz) * 2097152;
    const unsigned short* WTl = WTh + 1048576;
    const float* Bu = (pz == 0) ? Bu0 : (pz == 1) ? Bu1 : Bu2;
    void* Ovp       = (pz == 0) ? O0 : (pz == 1) ? O1 : O2;
    int xa_off = xa_off0 + pz * 8;

    int brow = blockIdx.y * BM, bcol = blockIdx.x * 128;
    int t = threadIdx.x, wid = t >> 6, lane = t & 63, l15 = lane & 15, g = lane >> 4;
    int wm = (BM == 128) ? (wid >> 1) * 64 : 0;
    int wn = (BM == 128) ? (wid & 1) * 64 : wid * 32;

    __shared__ unsigned short Ah[BM][40];
    __shared__ unsigned short Al[BM][40];
    __shared__ unsigned short Bh[128][40];
    __shared__ unsigned short Bl[128][40];

    f32x4 acc[4][FN];
#pragma unroll
    for (int i = 0; i < 4; ++i)
#pragma unroll
        for (int j = 0; j < FN; ++j) acc[i][j] = (f32x4){0.f, 0.f, 0.f, 0.f};

    int sm = t >> 2, skg = t & 3;
    const unsigned short* aH0 = Xh  + (size_t)(brow + sm) * HDIM + 8 * skg;
    const unsigned short* aL0 = Xl  + (size_t)(brow + sm) * HDIM + 8 * skg;
    const unsigned short* bH0 = WTh + (size_t)(bcol + sm) * HDIM + 8 * skg;
    const unsigned short* bL0 = WTl + (size_t)(bcol + sm) * HDIM + 8 * skg;
    const size_t R64 = (size_t)64 * HDIM;

    us8 rAH0, rAH1, rAL0, rAL1, rBH0, rBH1, rBL0, rBL1;
    rAH0 = *(const us8*)(aH0);
    rAL0 = *(const us8*)(aL0);
    if (BM == 128) {
        rAH1 = *(const us8*)(aH0 + R64);
        rAL1 = *(const us8*)(aL0 + R64);
    }
    rBH0 = *(const us8*)(bH0);
    rBH1 = *(const us8*)(bH0 + R64);
    rBL0 = *(const us8*)(bL0);
    rBL1 = *(const us8*)(bL0 + R64);

    for (int k0 = 0; k0 < HDIM; k0 += 32) {
        __syncthreads();
        *(us8*)&Ah[sm][8 * skg] = rAH0;
        *(us8*)&Al[sm][8 * skg] = rAL0;
        if (BM == 128) {
            *(us8*)&Ah[(sm + 64) & (BM - 1)][8 * skg] = rAH1;
            *(us8*)&Al[(sm + 64) & (BM - 1)][8 * skg] = rAL1;
        }
        *(us8*)&Bh[sm][8 * skg]      = rBH0;
        *(us8*)&Bh[sm + 64][8 * skg] = rBH1;
        *(us8*)&Bl[sm][8 * skg]      = rBL0;
        *(us8*)&Bl[sm + 64][8 * skg] = rBL1;
        __syncthreads();
        if (k0 + 32 < HDIM) {
            int ko = k0 + 32;
            rAH0 = *(const us8*)(aH0 + ko);
            rAL0 = *(const us8*)(aL0 + ko);
            if (BM == 128) {
                rAH1 = *(const us8*)(aH0 + R64 + ko);
                rAL1 = *(const us8*)(aL0 + R64 + ko);
            }
            rBH0 = *(const us8*)(bH0 + ko);
            rBH1 = *(const us8*)(bH0 + R64 + ko);
            rBL0 = *(const us8*)(bL0 + ko);
            rBL1 = *(const us8*)(bL0 + R64 + ko);
        }
        bf16x8 fah[4], fal[4], fbh[FN], fbl[FN];
#pragma unroll
        for (int f = 0; f < 4; ++f) {
            fah[f] = *(const bf16x8*)&Ah[wm + 16 * f + l15][8 * g];
            fal[f] = *(const bf16x8*)&Al[wm + 16 * f + l15][8 * g];
        }
#pragma unroll
        for (int f = 0; f < FN; ++f) {
            fbh[f] = *(const bf16x8*)&Bh[wn + 16 * f + l15][8 * g];
            fbl[f] = *(const bf16x8*)&Bl[wn + 16 * f + l15][8 * g];
        }
#pragma unroll
        for (int fm = 0; fm < 4; ++fm)
#pragma unroll
            for (int fn = 0; fn < FN; ++fn) {
                f32x4 a = acc[fm][fn];
                a = __builtin_amdgcn_mfma_f32_16x16x32_bf16(fah[fm], fbh[fn], a, 0, 0, 0);
                a = __builtin_amdgcn_mfma_f32_16x16x32_bf16(fah[fm], fbl[fn], a, 0, 0, 0);
                a = __builtin_amdgcn_mfma_f32_16x16x32_bf16(fal[fm], fbh[fn], a, 0, 0, 0);
                acc[fm][fn] = a;
            }
    }

    // LoRA epilogue + store
    float lb[8][FN];
#pragma unroll
    for (int rr = 0; rr < 8; ++rr)
#pragma unroll
        for (int fn = 0; fn < FN; ++fn)
            lb[rr][fn] = Bu[(size_t)rr * HDIM + bcol + wn + 16 * fn + l15] * LSCALE;

#pragma unroll
    for (int fm = 0; fm < 4; ++fm) {
        float la[4][8];
#pragma unroll
        for (int r = 0; r < 4; ++r) {
            int row = brow + wm + 16 * fm + 4 * g + r;
            const float* lap = XA + (size_t)row * xa_stride + xa_off;
            fx4 q0 = *(const fx4*)lap;
            fx4 q1 = *(const fx4*)(lap + 4);
#pragma unroll
            for (int j = 0; j < 4; ++j) { la[r][j] = q0[j]; la[r][4 + j] = q1[j]; }
        }
#pragma unroll
        for (int fn = 0; fn < FN; ++fn)
#pragma unroll
            for (int r = 0; r < 4; ++r) {
                float sum = acc[fm][fn][r];
#pragma unroll
                for (int rr = 0; rr < 8; ++rr) sum += la[r][rr] * lb[rr][fn];
                size_t row = (size_t)(brow + wm + 16 * fm + 4 * g + r);
                int col = bcol + wn + 16 * fn + l15;
                if (OUTF32) ((float*)Ovp)[row * HDIM + col] = sum;
                else ((unsigned short*)Ovp)[row * HDIM + col] = f2bf(sum);
            }
    }
}

// ---------------------------------------------------------------------------
// flash attention, swapped-operand MFMA, FIXED-max softmax:
// row max computed once on tile 0 (exact for any fixed m0), clamped >= -64.
// No per-tile cross-lane ops, no acc rescale; l accumulated in 4 per-lane
// partials, reduced once at the epilogue.
// ---------------------------------------------------------------------------
#define QBLK 64
#define KVB  64
#define NT   (SEQ / KVB)

__global__ __launch_bounds__(256, 4)
void attn_mfma_kernel(const unsigned short* __restrict__ Qg, const unsigned short* __restrict__ Kg,
                      const unsigned short* __restrict__ Vt, const float* __restrict__ mask,
                      unsigned short* __restrict__ Ch, unsigned short* __restrict__ Cl)
{
    int qt = blockIdx.x, h = blockIdx.y, b = blockIdx.z;
    int t    = threadIdx.x;
    int wid  = t >> 6;
    int lane = t & 63;
    int l15  = lane & 15;
    int g    = lane >> 4;

    __shared__ __align__(16) unsigned short Ks[2][64][72];
    __shared__ __align__(16) unsigned short Vs[2][64][72];   // Vs[d][s]
    __shared__ __align__(16) float Msd[2][64];

    // Q as B-fragment: col=q=l15, k=32kc+8g+j
    bf16x8 qa[2];
    const unsigned short* qp = Qg + (size_t)(b * SEQ + qt * QBLK + wid * 16) * HDIM + h * HD;
#pragma unroll
    for (int kc = 0; kc < 2; ++kc)
        qa[kc] = *(const bf16x8*)(qp + (size_t)l15 * HDIM + 32 * kc + 8 * g);

    float m0 = 0.f;                 // fixed row max (log2 domain), set at kt==0
    f32x4 l4 = (f32x4){0.f, 0.f, 0.f, 0.f};
    f32x4 acc[4];
#pragma unroll
    for (int n = 0; n < 4; ++n) acc[n] = (f32x4){0.f, 0.f, 0.f, 0.f};

    const unsigned short* kp0 = Kg + (size_t)(b * SEQ) * HDIM + h * HD;
    const unsigned short* vt0 = Vt + (size_t)((b * NHEAD + h) * HD) * SEQ;

    const float QSCL = 0.125f * LOG2E;
    const float MSCL = -10000.0f * LOG2E;

    int r0 = t >> 3,           c0 = (t & 7) * 8;
    int r1 = (t + 256) >> 3,   c1 = c0;

    // prologue: stage tile 0 into buffer 0
    *(us8*)&Ks[0][r0][c0] = *(const us8*)(kp0 + (size_t)r0 * HDIM + c0);
    *(us8*)&Ks[0][r1][c1] = *(const us8*)(kp0 + (size_t)r1 * HDIM + c1);
    *(us8*)&Vs[0][r0][c0] = *(const us8*)(vt0 + (size_t)r0 * SEQ + c0);
    *(us8*)&Vs[0][r1][c1] = *(const us8*)(vt0 + (size_t)r1 * SEQ + c1);
    if (t < 64) Msd[0][t] = (1.0f - mask[b * SEQ + t]) * MSCL;
    __syncthreads();

    int cur = 0;
    for (int kt = 0; kt < NT; ++kt) {
        us8 knr0, knr1, vnr0, vnr1;
        float mreg = 1.0f;
        bool more = (kt + 1 < NT);
        if (more) {
            const unsigned short* kp = kp0 + (size_t)(kt + 1) * KVB * HDIM;
            const unsigned short* vp = vt0 + (kt + 1) * KVB;
            knr0 = *(const us8*)(kp + (size_t)r0 * HDIM + c0);
            knr1 = *(const us8*)(kp + (size_t)r1 * HDIM + c1);
            vnr0 = *(const us8*)(vp + (size_t)r0 * SEQ + c0);
            vnr1 = *(const us8*)(vp + (size_t)r1 * SEQ + c1);
            if (t < 64) mreg = mask[b * SEQ + (kt + 1) * KVB + t];
        }

        // ---- QK^T swapped: sT[n][r] = S[q=l15][c=16n+4g+r] ----
        f32x4 sT[4];
#pragma unroll
        for (int n = 0; n < 4; ++n) {
            f32x4 a = (f32x4){0.f, 0.f, 0.f, 0.f};
#pragma unroll
            for (int kc = 0; kc < 2; ++kc) {
                bf16x8 kb = *(const bf16x8*)&Ks[cur][16 * n + l15][32 * kc + 8 * g];
                a = __builtin_amdgcn_mfma_f32_16x16x32_bf16(kb, qa[kc], a, 0, 0, 0);
            }
            sT[n] = a;
        }

        // ---- scale + mask (log2 domain) ----
#pragma unroll
        for (int n = 0; n < 4; ++n) {
            fx4 msk = *(const fx4*)&Msd[cur][16 * n + 4 * g];
#pragma unroll
            for (int r = 0; r < 4; ++r) sT[n][r] = fmaf(sT[n][r], QSCL, msk[r]);
        }

        // ---- tile-0: compute fixed row max (tree + 2 shfl), clamp >= -64 ----
        if (kt == 0) {
            f32x4 t01, t23, tt;
#pragma unroll
            for (int r = 0; r < 4; ++r) {
                t01[r] = fmaxf(sT[0][r], sT[1][r]);
                t23[r] = fmaxf(sT[2][r], sT[3][r]);
                tt[r]  = fmaxf(t01[r], t23[r]);
            }
            float mx = fmaxf(fmaxf(tt[0], tt[1]), fmaxf(tt[2], tt[3]));
            mx = fmaxf(mx, __shfl_xor(mx, 16, 64));
            mx = fmaxf(mx, __shfl_xor(mx, 32, 64));
            m0 = fmaxf(mx, -64.f);
        }

        // ---- P = exp2(s - m0); accumulate l in 4 independent partials ----
#pragma unroll
        for (int n = 0; n < 4; ++n)
#pragma unroll
            for (int r = 0; r < 4; ++r) {
                float p = exp2f(sT[n][r] - m0);
                sT[n][r] = p;
                l4[r] += p;
            }

        // ---- pack P to bf16 dwords via v_cvt_pk_bf16_f32 ----
        unsigned int pkx[4], pky[4];
#pragma unroll
        for (int n = 0; n < 4; ++n) {
            pkx[n] = cvt_pk_bf16(sT[n][0], sT[n][1]);
            pky[n] = cvt_pk_bf16(sT[n][2], sT[n][3]);
        }

        // ---- redistribute to B-fragment pb[kc]: P[q=l15][c=32kc+8g+j] ----
        int lA = l15 + 32 * (g & 1);
        int lB = lA + 16;
        bool selhi = (g & 2) != 0;
        bf16x8 pb[2];
#pragma unroll
        for (int kc = 0; kc < 2; ++kc) {
            unsigned int xA0 = __shfl((int)pkx[2 * kc], lA, 64);
            unsigned int yA0 = __shfl((int)pky[2 * kc], lA, 64);
            unsigned int xA1 = __shfl((int)pkx[2 * kc + 1], lA, 64);
            unsigned int yA1 = __shfl((int)pky[2 * kc + 1], lA, 64);
            unsigned int xB0 = __shfl((int)pkx[2 * kc], lB, 64);
            unsigned int yB0 = __shfl((int)pky[2 * kc], lB, 64);
            unsigned int xB1 = __shfl((int)pkx[2 * kc + 1], lB, 64);
            unsigned int yB1 = __shfl((int)pky[2 * kc + 1], lB, 64);
            u32x4 d;
            d[0] = selhi ? xA1 : xA0;
            d[1] = selhi ? yA1 : yA0;
            d[2] = selhi ? xB1 : xB0;
            d[3] = selhi ? yB1 : yB0;
            pb[kc] = *(bf16x8*)&d;
        }

        // ---- PV swapped: acc[n][r] = O[q=l15][dout=16n+4g+r] ----
#pragma unroll
        for (int n = 0; n < 4; ++n)
#pragma unroll
            for (int kc = 0; kc < 2; ++kc) {
                bf16x8 vb = *(const bf16x8*)&Vs[cur][16 * n + l15][32 * kc + 8 * g];
                acc[n] = __builtin_amdgcn_mfma_f32_16x16x32_bf16(vb, pb[kc], acc[n], 0, 0, 0);
            }

        if (more) {
            *(us8*)&Ks[cur ^ 1][r0][c0] = knr0;
            *(us8*)&Ks[cur ^ 1][r1][c1] = knr1;
            *(us8*)&Vs[cur ^ 1][r0][c0] = vnr0;
            *(us8*)&Vs[cur ^ 1][r1][c1] = vnr1;
            if (t < 64) Msd[cur ^ 1][t] = (1.0f - mreg) * MSCL;
        }
        __syncthreads();
        cur ^= 1;
    }

    // ---- epilogue: reduce l once, normalize, store hi/lo ----
    float l = (l4[0] + l4[1]) + (l4[2] + l4[3]);
    l += __shfl_xor(l, 16, 64);
    l += __shfl_xor(l, 32, 64);
    float inv = 1.0f / l;
    size_t row = (size_t)(b * SEQ + qt * QBLK + wid * 16 + l15);
#pragma unroll
    for (int n = 0; n < 4; ++n) {
        us4 hv, lv;
#pragma unroll
        for (int r = 0; r < 4; ++r) {
            float o = acc[n][r] * inv;
            unsigned short hi = f2bf(o);
            hv[r] = hi;
            lv[r] = f2bf(o - bf2f(hi));
        }
        size_t idx = row * HDIM + h * HD + 16 * n + 4 * g;
        *(us4*)&Ch[idx] = hv;
        *(us4*)&Cl[idx] = lv;
    }
}

// ---------------------------------------------------------------------------
extern "C" void kernel_launch(void* const* d_in, const int* in_sizes, int n_in,
                              void* d_out, int out_size, void* d_ws, size_t ws_size,
                              hipStream_t stream)
{
    const float* hs   = (const float*)d_in[0];
    const float* mask = (const float*)d_in[1];
    const float* Wq = (const float*)d_in[2];
    const float* Wk = (const float*)d_in[3];
    const float* Wv = (const float*)d_in[4];
    const float* Wo = (const float*)d_in[5];
    const float* Aq = (const float*)d_in[6];
    const float* Bq = (const float*)d_in[7];
    const float* Ak = (const float*)d_in[8];
    const float* Bk = (const float*)d_in[9];
    const float* Av = (const float*)d_in[10];
    const float* Bv = (const float*)d_in[11];
    const float* Ao = (const float*)d_in[12];
    const float* Bo = (const float*)d_in[13];
    float* out = (float*)d_out;

    char* w = (char*)d_ws;
    unsigned short* Xh = (unsigned short*)(w);                       // 8 MB (later Ch)
    unsigned short* Xl = (unsigned short*)(w + ((size_t)8 << 20));   // 8 MB (later Cl)
    unsigned short* WT = (unsigned short*)(w + ((size_t)16 << 20));  // 16 MB (8 planes)
    unsigned short* qb = (unsigned short*)(w + ((size_t)32 << 20));  // 8 MB
    unsigned short* kb = (unsigned short*)(w + ((size_t)40 << 20));  // 8 MB
    unsigned short* vb = (unsigned short*)(w + ((size_t)48 << 20));  // 8 MB
    unsigned short* vt = (unsigned short*)(w + ((size_t)56 << 20));  // 8 MB
    float* hsA  = (float*)(w + ((size_t)64 << 20));                  // 4096*24*4
    float* ctxA = (float*)(w + ((size_t)64 << 20) + 400 * 1024);     // 4096*8*4

    split_x_kernel<<<2048, 256, 0, stream>>>(hs, Xh, Xl, MTOT * HDIM / 4);
    tsplit_w_kernel<<<dim3(16, 16, 4), 256, 0, stream>>>(Wq, Wk, Wv, Wo, WT);
    lora_down_kernel<<<MTOT, 64, 0, stream>>>(hs, Aq, Ak, Av, hsA, 3);
    gemm_mfma_kernel<false, 128><<<dim3(8, 32, 3), 256, 0, stream>>>(
        Xh, Xl, WT, 0, hsA, 24, 0, Bq, Bk, Bv, qb, kb, vb);
    transpose_v_kernel<<<dim3(SEQ / 64, BATCH * NHEAD), 256, 0, stream>>>(vb, vt);
    attn_mfma_kernel<<<dim3(SEQ / QBLK, NHEAD, BATCH), 256, 0, stream>>>(
        qb, kb, vt, mask, Xh /*Ch*/, Xl /*Cl*/);
    lora_down_bf_kernel<<<MTOT, 64, 0, stream>>>(Xh, Xl, Ao, ctxA);
    gemm_mfma_kernel<true, 64><<<dim3(8, 64, 1), 256, 0, stream>>>(
        Xh, Xl, WT, 3, ctxA, 8, 0, Bo, Bo, Bo, out, out, out);
}

// Round 10
// 240.100 us; speedup vs baseline: 4.3685x; 1.0222x over previous
//
#include <hip/hip_runtime.h>
#include <math.h>

typedef float fx4 __attribute__((ext_vector_type(4)));
typedef float f32x4 __attribute__((ext_vector_type(4)));
typedef short bf16x8 __attribute__((ext_vector_type(8)));
typedef unsigned short us4 __attribute__((ext_vector_type(4)));
typedef unsigned short us8 __attribute__((ext_vector_type(8)));
typedef unsigned int u32x4 __attribute__((ext_vector_type(4)));

#define HDIM 1024
#define SEQ  2048
#define BATCH 2
#define NHEAD 16
#define HD    64
#define MTOT  4096
#define LSCALE 8.0f
#define LOG2E 1.44269504088896340736f

__device__ __forceinline__ unsigned short f2bf(float f) {
    union { float f; unsigned int u; } v; v.f = f;
    unsigned int r = v.u + 0x7FFFu + ((v.u >> 16) & 1u);
    return (unsigned short)(r >> 16);
}
__device__ __forceinline__ float bf2f(unsigned short h) {
    union { unsigned int u; float f; } v; v.u = ((unsigned int)h) << 16;
    return v.f;
}
// packed bf16 convert: low16 = bf16(a), high16 = bf16(b), RNE
__device__ __forceinline__ unsigned int cvt_pk_bf16(float a, float b) {
    unsigned int r;
    asm("v_cvt_pk_bf16_f32 %0, %1, %2" : "=v"(r) : "v"(a), "v"(b));
    return r;
}

// ---------------------------------------------------------------------------
// split X (fp32) -> hi/lo bf16 planes
// ---------------------------------------------------------------------------
__global__ __launch_bounds__(256)
void split_x_kernel(const float* __restrict__ X, unsigned short* __restrict__ Xh,
                    unsigned short* __restrict__ Xl, int n4)
{
    int i = blockIdx.x * 256 + threadIdx.x;
    int stride = gridDim.x * 256;
    for (; i < n4; i += stride) {
        fx4 v = *((const fx4*)X + i);
        us4 h, l;
#pragma unroll
        for (int j = 0; j < 4; ++j) {
            h[j] = f2bf(v[j]);
            l[j] = f2bf(v[j] - bf2f(h[j]));
        }
        *((us4*)Xh + i) = h;
        *((us4*)Xl + i) = l;
    }
}

// ---------------------------------------------------------------------------
// transpose + split W [k][n] fp32 -> WT hi/lo bf16 [n][k]; z selects matrix.
// ---------------------------------------------------------------------------
__global__ __launch_bounds__(256)
void tsplit_w_kernel(const float* __restrict__ W0, const float* __restrict__ W1,
                     const float* __restrict__ W2, const float* __restrict__ W3,
                     unsigned short* __restrict__ WTbase)
{
    int z = blockIdx.z;
    const float* W = (z == 0) ? W0 : (z == 1) ? W1 : (z == 2) ? W2 : W3;
    unsigned short* WTh = WTbase + (size_t)z * 2097152;
    unsigned short* WTl = WTh + 1048576;
    int n0 = blockIdx.x * 64, k0 = blockIdx.y * 64;
    __shared__ unsigned int T[64][65];
    int t = threadIdx.x;
#pragma unroll
    for (int i = 0; i < 4; ++i) {
        int idx = t + 256 * i;
        int r = idx >> 4, c4 = (idx & 15) * 4;
        fx4 w = *(const fx4*)&W[(size_t)(k0 + r) * HDIM + n0 + c4];
#pragma unroll
        for (int j = 0; j < 4; ++j) {
            unsigned short hi = f2bf(w[j]);
            unsigned short lo = f2bf(w[j] - bf2f(hi));
            T[r][c4 + j] = (unsigned int)hi | ((unsigned int)lo << 16);
        }
    }
    __syncthreads();
#pragma unroll
    for (int i = 0; i < 4; ++i) {
        int idx = t + 256 * i;
        int n = idx >> 4, kg = (idx & 15) * 4;
        us4 hv, lv;
#pragma unroll
        for (int j = 0; j < 4; ++j) {
            unsigned int p = T[kg + j][n];
            hv[j] = (unsigned short)(p & 0xffffu);
            lv[j] = (unsigned short)(p >> 16);
        }
        *(us4*)&WTh[(size_t)(n0 + n) * HDIM + k0 + kg] = hv;
        *(us4*)&WTl[(size_t)(n0 + n) * HDIM + k0 + kg] = lv;
    }
}

// ---------------------------------------------------------------------------
// transpose V: vb [4096][1024] bf16 -> vt [(b*16+h)*64+d][2048] bf16
// ---------------------------------------------------------------------------
__global__ __launch_bounds__(256)
void transpose_v_kernel(const unsigned short* __restrict__ vb,
                        unsigned short* __restrict__ vt)
{
    int s0 = blockIdx.x * 64;
    int bh = blockIdx.y;               // b*16+h
    int b = bh >> 4, h = bh & 15;
    __shared__ unsigned short T[64][80];
    int t = threadIdx.x;
#pragma unroll
    for (int i = 0; i < 2; ++i) {
        int u = t + 256 * i;
        int r = u >> 3, cg = u & 7;
        us8 v = *(const us8*)&vb[(size_t)(b * SEQ + s0 + r) * HDIM + h * HD + 8 * cg];
        *(us8*)&T[r][8 * cg] = v;
    }
    __syncthreads();
#pragma unroll
    for (int i = 0; i < 2; ++i) {
        int u = t + 256 * i;
        int d = u & 63, sg = u >> 6;
        us8 v;
#pragma unroll
        for (int j = 0; j < 8; ++j) v[j] = T[8 * sg + j][d];
        *(us8*)&vt[(size_t)(bh * HD + d) * SEQ + s0 + 8 * sg] = v;
    }
}

// ---------------------------------------------------------------------------
// lora down: fp32 X; XA = X @ [A0|A1|A2]; out row stride 24
// ---------------------------------------------------------------------------
__global__ __launch_bounds__(64)
void lora_down_kernel(const float* __restrict__ X,
                      const float* __restrict__ A0,
                      const float* __restrict__ A1,
                      const float* __restrict__ A2,
                      float* __restrict__ out, int nmat)
{
    int row  = blockIdx.x;
    int lane = threadIdx.x;
    const float* xr = X + (size_t)row * HDIM;
    float xv[16];
#pragma unroll
    for (int i = 0; i < 16; ++i) xv[i] = xr[lane + 64 * i];
    const float* Amats[3] = {A0, A1, A2};
    for (int m = 0; m < nmat; ++m) {
        const float* A = Amats[m];
        float s[8];
#pragma unroll
        for (int c = 0; c < 8; ++c) s[c] = 0.f;
#pragma unroll
        for (int i = 0; i < 16; ++i) {
            const float* ap = A + (size_t)(lane + 64 * i) * 8;
#pragma unroll
            for (int c = 0; c < 8; ++c) s[c] += xv[i] * ap[c];
        }
#pragma unroll
        for (int c = 0; c < 8; ++c) {
#pragma unroll
            for (int off = 1; off < 64; off <<= 1)
                s[c] += __shfl_xor(s[c], off, 64);
        }
        if (lane == 0) {
#pragma unroll
            for (int c = 0; c < 8; ++c)
                out[(size_t)row * 24 + m * 8 + c] = s[c];
        }
    }
}

// lora down from hi/lo bf16 planes (ctx); out stride 8
__global__ __launch_bounds__(64)
void lora_down_bf_kernel(const unsigned short* __restrict__ Xh,
                         const unsigned short* __restrict__ Xl,
                         const float* __restrict__ A,
                         float* __restrict__ out)
{
    int row  = blockIdx.x;
    int lane = threadIdx.x;
    const unsigned short* xh = Xh + (size_t)row * HDIM;
    const unsigned short* xl = Xl + (size_t)row * HDIM;
    float xv[16];
#pragma unroll
    for (int i = 0; i < 16; ++i)
        xv[i] = bf2f(xh[lane + 64 * i]) + bf2f(xl[lane + 64 * i]);
    float s[8];
#pragma unroll
    for (int c = 0; c < 8; ++c) s[c] = 0.f;
#pragma unroll
    for (int i = 0; i < 16; ++i) {
        const float* ap = A + (size_t)(lane + 64 * i) * 8;
#pragma unroll
        for (int c = 0; c < 8; ++c) s[c] += xv[i] * ap[c];
    }
#pragma unroll
    for (int c = 0; c < 8; ++c) {
#pragma unroll
        for (int off = 1; off < 64; off <<= 1)
            s[c] += __shfl_xor(s[c], off, 64);
    }
    if (lane == 0) {
#pragma unroll
        for (int c = 0; c < 8; ++c) out[(size_t)row * 8 + c] = s[c];
    }
}

// ---------------------------------------------------------------------------
// split-bf16 MFMA GEMM: Out = X@W + LSCALE*(XA)@Bu
// BM=128: 4 waves 2x2 of 64x64 (FN=4).  BM=64: 4 waves 1x4 of 64x32 (FN=2).
// ---------------------------------------------------------------------------
template<bool OUTF32, int BM>
__global__ __launch_bounds__(256, BM == 128 ? 2 : 3)
void gemm_mfma_kernel(const unsigned short* __restrict__ Xh, const unsigned short* __restrict__ Xl,
                      const unsigned short* __restrict__ WTbase, int wsel0,
                      const float* __restrict__ XA, int xa_stride, int xa_off0,
                      const float* __restrict__ Bu0, const float* __restrict__ Bu1, const float* __restrict__ Bu2,
                      void* __restrict__ O0, void* __restrict__ O1, void* __restrict__ O2)
{
    constexpr int FN = (BM == 128) ? 4 : 2;
    int pz = blockIdx.z;
    const unsigned short* WTh = WTbase + (size_t)(wsel0 + pz) * 2097152;
    const unsigned short* WTl = WTh + 1048576;
    const float* Bu = (pz == 0) ? Bu0 : (pz == 1) ? Bu1 : Bu2;
    void* Ovp       = (pz == 0) ? O0 : (pz == 1) ? O1 : O2;
    int xa_off = xa_off0 + pz * 8;

    int brow = blockIdx.y * BM, bcol = blockIdx.x * 128;
    int t = threadIdx.x, wid = t >> 6, lane = t & 63, l15 = lane & 15, g = lane >> 4;
    int wm = (BM == 128) ? (wid >> 1) * 64 : 0;
    int wn = (BM == 128) ? (wid & 1) * 64 : wid * 32;

    __shared__ unsigned short Ah[BM][40];
    __shared__ unsigned short Al[BM][40];
    __shared__ unsigned short Bh[128][40];
    __shared__ unsigned short Bl[128][40];

    f32x4 acc[4][FN];
#pragma unroll
    for (int i = 0; i < 4; ++i)
#pragma unroll
        for (int j = 0; j < FN; ++j) acc[i][j] = (f32x4){0.f, 0.f, 0.f, 0.f};

    int sm = t >> 2, skg = t & 3;
    const unsigned short* aH0 = Xh  + (size_t)(brow + sm) * HDIM + 8 * skg;
    const unsigned short* aL0 = Xl  + (size_t)(brow + sm) * HDIM + 8 * skg;
    const unsigned short* bH0 = WTh + (size_t)(bcol + sm) * HDIM + 8 * skg;
    const unsigned short* bL0 = WTl + (size_t)(bcol + sm) * HDIM + 8 * skg;
    const size_t R64 = (size_t)64 * HDIM;

    us8 rAH0, rAH1, rAL0, rAL1, rBH0, rBH1, rBL0, rBL1;
    rAH0 = *(const us8*)(aH0);
    rAL0 = *(const us8*)(aL0);
    if (BM == 128) {
        rAH1 = *(const us8*)(aH0 + R64);
        rAL1 = *(const us8*)(aL0 + R64);
    }
    rBH0 = *(const us8*)(bH0);
    rBH1 = *(const us8*)(bH0 + R64);
    rBL0 = *(const us8*)(bL0);
    rBL1 = *(const us8*)(bL0 + R64);

    for (int k0 = 0; k0 < HDIM; k0 += 32) {
        __syncthreads();
        *(us8*)&Ah[sm][8 * skg] = rAH0;
        *(us8*)&Al[sm][8 * skg] = rAL0;
        if (BM == 128) {
            *(us8*)&Ah[(sm + 64) & (BM - 1)][8 * skg] = rAH1;
            *(us8*)&Al[(sm + 64) & (BM - 1)][8 * skg] = rAL1;
        }
        *(us8*)&Bh[sm][8 * skg]      = rBH0;
        *(us8*)&Bh[sm + 64][8 * skg] = rBH1;
        *(us8*)&Bl[sm][8 * skg]      = rBL0;
        *(us8*)&Bl[sm + 64][8 * skg] = rBL1;
        __syncthreads();
        if (k0 + 32 < HDIM) {
            int ko = k0 + 32;
            rAH0 = *(const us8*)(aH0 + ko);
            rAL0 = *(const us8*)(aL0 + ko);
            if (BM == 128) {
                rAH1 = *(const us8*)(aH0 + R64 + ko);
                rAL1 = *(const us8*)(aL0 + R64 + ko);
            }
            rBH0 = *(const us8*)(bH0 + ko);
            rBH1 = *(const us8*)(bH0 + R64 + ko);
            rBL0 = *(const us8*)(bL0 + ko);
            rBL1 = *(const us8*)(bL0 + R64 + ko);
        }
        bf16x8 fah[4], fal[4], fbh[FN], fbl[FN];
#pragma unroll
        for (int f = 0; f < 4; ++f) {
            fah[f] = *(const bf16x8*)&Ah[wm + 16 * f + l15][8 * g];
            fal[f] = *(const bf16x8*)&Al[wm + 16 * f + l15][8 * g];
        }
#pragma unroll
        for (int f = 0; f < FN; ++f) {
            fbh[f] = *(const bf16x8*)&Bh[wn + 16 * f + l15][8 * g];
            fbl[f] = *(const bf16x8*)&Bl[wn + 16 * f + l15][8 * g];
        }
#pragma unroll
        for (int fm = 0; fm < 4; ++fm)
#pragma unroll
            for (int fn = 0; fn < FN; ++fn) {
                f32x4 a = acc[fm][fn];
                a = __builtin_amdgcn_mfma_f32_16x16x32_bf16(fah[fm], fbh[fn], a, 0, 0, 0);
                a = __builtin_amdgcn_mfma_f32_16x16x32_bf16(fah[fm], fbl[fn], a, 0, 0, 0);
                a = __builtin_amdgcn_mfma_f32_16x16x32_bf16(fal[fm], fbh[fn], a, 0, 0, 0);
                acc[fm][fn] = a;
            }
    }

    // LoRA epilogue + store
    float lb[8][FN];
#pragma unroll
    for (int rr = 0; rr < 8; ++rr)
#pragma unroll
        for (int fn = 0; fn < FN; ++fn)
            lb[rr][fn] = Bu[(size_t)rr * HDIM + bcol + wn + 16 * fn + l15] * LSCALE;

#pragma unroll
    for (int fm = 0; fm < 4; ++fm) {
        float la[4][8];
#pragma unroll
        for (int r = 0; r < 4; ++r) {
            int row = brow + wm + 16 * fm + 4 * g + r;
            const float* lap = XA + (size_t)row * xa_stride + xa_off;
            fx4 q0 = *(const fx4*)lap;
            fx4 q1 = *(const fx4*)(lap + 4);
#pragma unroll
            for (int j = 0; j < 4; ++j) { la[r][j] = q0[j]; la[r][4 + j] = q1[j]; }
        }
#pragma unroll
        for (int fn = 0; fn < FN; ++fn)
#pragma unroll
            for (int r = 0; r < 4; ++r) {
                float sum = acc[fm][fn][r];
#pragma unroll
                for (int rr = 0; rr < 8; ++rr) sum += la[r][rr] * lb[rr][fn];
                size_t row = (size_t)(brow + wm + 16 * fm + 4 * g + r);
                int col = bcol + wn + 16 * fn + l15;
                if (OUTF32) ((float*)Ovp)[row * HDIM + col] = sum;
                else ((unsigned short*)Ovp)[row * HDIM + col] = f2bf(sum);
            }
    }
}

// ---------------------------------------------------------------------------
// flash attention, swapped-operand MFMA, fixed-max softmax, DUAL-Q:
// wave owns 32 q-rows as two B-fragments; each K/V fragment is loaded once
// and feeds both Q chains (2x MFMA per LDS read, 2 independent VALU chains).
// QBLK=128, grid 16x16x2 = 512 blocks (2/CU); staging per (b,h) halves.
// ---------------------------------------------------------------------------
#define QBLK 128
#define KVB  64
#define NT   (SEQ / KVB)

__global__ __launch_bounds__(256, 2)
void attn_mfma_kernel(const unsigned short* __restrict__ Qg, const unsigned short* __restrict__ Kg,
                      const unsigned short* __restrict__ Vt, const float* __restrict__ mask,
                      unsigned short* __restrict__ Ch, unsigned short* __restrict__ Cl)
{
    int qt = blockIdx.x, h = blockIdx.y, b = blockIdx.z;
    int t    = threadIdx.x;
    int wid  = t >> 6;
    int lane = t & 63;
    int l15  = lane & 15;
    int g    = lane >> 4;

    __shared__ __align__(16) unsigned short Ks[2][64][72];
    __shared__ __align__(16) unsigned short Vs[2][64][72];   // Vs[d][s]
    __shared__ __align__(16) float Msd[2][64];

    // Q as B-fragments: col=q=l15 (+16m), k=32kc+8g+j
    bf16x8 qa[2][2];
    const unsigned short* qp = Qg + (size_t)(b * SEQ + qt * QBLK + wid * 32) * HDIM + h * HD;
#pragma unroll
    for (int m = 0; m < 2; ++m)
#pragma unroll
        for (int kc = 0; kc < 2; ++kc)
            qa[m][kc] = *(const bf16x8*)(qp + (size_t)(16 * m + l15) * HDIM + 32 * kc + 8 * g);

    float m0[2] = {0.f, 0.f};        // fixed row max (log2 domain), set at kt==0
    f32x4 l4[2];
    f32x4 acc[2][4];
#pragma unroll
    for (int m = 0; m < 2; ++m) {
        l4[m] = (f32x4){0.f, 0.f, 0.f, 0.f};
#pragma unroll
        for (int n = 0; n < 4; ++n) acc[m][n] = (f32x4){0.f, 0.f, 0.f, 0.f};
    }

    const unsigned short* kp0 = Kg + (size_t)(b * SEQ) * HDIM + h * HD;
    const unsigned short* vt0 = Vt + (size_t)((b * NHEAD + h) * HD) * SEQ;

    const float QSCL = 0.125f * LOG2E;
    const float MSCL = -10000.0f * LOG2E;

    int r0 = t >> 3,           c0 = (t & 7) * 8;
    int r1 = (t + 256) >> 3,   c1 = c0;

    // prologue: stage tile 0 into buffer 0
    *(us8*)&Ks[0][r0][c0] = *(const us8*)(kp0 + (size_t)r0 * HDIM + c0);
    *(us8*)&Ks[0][r1][c1] = *(const us8*)(kp0 + (size_t)r1 * HDIM + c1);
    *(us8*)&Vs[0][r0][c0] = *(const us8*)(vt0 + (size_t)r0 * SEQ + c0);
    *(us8*)&Vs[0][r1][c1] = *(const us8*)(vt0 + (size_t)r1 * SEQ + c1);
    if (t < 64) Msd[0][t] = (1.0f - mask[b * SEQ + t]) * MSCL;
    __syncthreads();

    int cur = 0;
    for (int kt = 0; kt < NT; ++kt) {
        us8 knr0, knr1, vnr0, vnr1;
        float mreg = 1.0f;
        bool more = (kt + 1 < NT);
        if (more) {
            const unsigned short* kp = kp0 + (size_t)(kt + 1) * KVB * HDIM;
            const unsigned short* vp = vt0 + (kt + 1) * KVB;
            knr0 = *(const us8*)(kp + (size_t)r0 * HDIM + c0);
            knr1 = *(const us8*)(kp + (size_t)r1 * HDIM + c1);
            vnr0 = *(const us8*)(vp + (size_t)r0 * SEQ + c0);
            vnr1 = *(const us8*)(vp + (size_t)r1 * SEQ + c1);
            if (t < 64) mreg = mask[b * SEQ + (kt + 1) * KVB + t];
        }

        // ---- QK^T swapped, K-fragment shared by both Q chains ----
        f32x4 sT[2][4];
#pragma unroll
        for (int n = 0; n < 4; ++n) {
            bf16x8 kb0 = *(const bf16x8*)&Ks[cur][16 * n + l15][8 * g];
            bf16x8 kb1 = *(const bf16x8*)&Ks[cur][16 * n + l15][32 + 8 * g];
#pragma unroll
            for (int m = 0; m < 2; ++m) {
                f32x4 a = (f32x4){0.f, 0.f, 0.f, 0.f};
                a = __builtin_amdgcn_mfma_f32_16x16x32_bf16(kb0, qa[m][0], a, 0, 0, 0);
                a = __builtin_amdgcn_mfma_f32_16x16x32_bf16(kb1, qa[m][1], a, 0, 0, 0);
                sT[m][n] = a;
            }
        }

        // ---- scale + mask (log2 domain) ----
#pragma unroll
        for (int n = 0; n < 4; ++n) {
            fx4 msk = *(const fx4*)&Msd[cur][16 * n + 4 * g];
#pragma unroll
            for (int m = 0; m < 2; ++m)
#pragma unroll
                for (int r = 0; r < 4; ++r) sT[m][n][r] = fmaf(sT[m][n][r], QSCL, msk[r]);
        }

        // ---- tile-0: fixed row max per m (tree + 2 shfl), clamp >= -64 ----
        if (kt == 0) {
#pragma unroll
            for (int m = 0; m < 2; ++m) {
                f32x4 tt;
#pragma unroll
                for (int r = 0; r < 4; ++r)
                    tt[r] = fmaxf(fmaxf(sT[m][0][r], sT[m][1][r]), fmaxf(sT[m][2][r], sT[m][3][r]));
                float mx = fmaxf(fmaxf(tt[0], tt[1]), fmaxf(tt[2], tt[3]));
                mx = fmaxf(mx, __shfl_xor(mx, 16, 64));
                mx = fmaxf(mx, __shfl_xor(mx, 32, 64));
                m0[m] = fmaxf(mx, -64.f);
            }
        }

        // ---- P = exp2(s - m0); l in 4 independent partials per m ----
#pragma unroll
        for (int m = 0; m < 2; ++m)
#pragma unroll
            for (int n = 0; n < 4; ++n)
#pragma unroll
                for (int r = 0; r < 4; ++r) {
                    float p = exp2f(sT[m][n][r] - m0[m]);
                    sT[m][n][r] = p;
                    l4[m][r] += p;
                }

        // ---- pack + redistribute to B-fragments, per m ----
        int lA = l15 + 32 * (g & 1);
        int lB = lA + 16;
        bool selhi = (g & 2) != 0;
        bf16x8 pb[2][2];
#pragma unroll
        for (int m = 0; m < 2; ++m) {
            unsigned int pkx[4], pky[4];
#pragma unroll
            for (int n = 0; n < 4; ++n) {
                pkx[n] = cvt_pk_bf16(sT[m][n][0], sT[m][n][1]);
                pky[n] = cvt_pk_bf16(sT[m][n][2], sT[m][n][3]);
            }
#pragma unroll
            for (int kc = 0; kc < 2; ++kc) {
                unsigned int xA0 = __shfl((int)pkx[2 * kc], lA, 64);
                unsigned int yA0 = __shfl((int)pky[2 * kc], lA, 64);
                unsigned int xA1 = __shfl((int)pkx[2 * kc + 1], lA, 64);
                unsigned int yA1 = __shfl((int)pky[2 * kc + 1], lA, 64);
                unsigned int xB0 = __shfl((int)pkx[2 * kc], lB, 64);
                unsigned int yB0 = __shfl((int)pky[2 * kc], lB, 64);
                unsigned int xB1 = __shfl((int)pkx[2 * kc + 1], lB, 64);
                unsigned int yB1 = __shfl((int)pky[2 * kc + 1], lB, 64);
                u32x4 d;
                d[0] = selhi ? xA1 : xA0;
                d[1] = selhi ? yA1 : yA0;
                d[2] = selhi ? xB1 : xB0;
                d[3] = selhi ? yB1 : yB0;
                pb[m][kc] = *(bf16x8*)&d;
            }
        }

        // ---- PV swapped, V-fragment shared by both Q chains ----
#pragma unroll
        for (int n = 0; n < 4; ++n) {
            bf16x8 vb0 = *(const bf16x8*)&Vs[cur][16 * n + l15][8 * g];
            bf16x8 vb1 = *(const bf16x8*)&Vs[cur][16 * n + l15][32 + 8 * g];
#pragma unroll
            for (int m = 0; m < 2; ++m) {
                f32x4 a = acc[m][n];
                a = __builtin_amdgcn_mfma_f32_16x16x32_bf16(vb0, pb[m][0], a, 0, 0, 0);
                a = __builtin_amdgcn_mfma_f32_16x16x32_bf16(vb1, pb[m][1], a, 0, 0, 0);
                acc[m][n] = a;
            }
        }

        if (more) {
            *(us8*)&Ks[cur ^ 1][r0][c0] = knr0;
            *(us8*)&Ks[cur ^ 1][r1][c1] = knr1;
            *(us8*)&Vs[cur ^ 1][r0][c0] = vnr0;
            *(us8*)&Vs[cur ^ 1][r1][c1] = vnr1;
            if (t < 64) Msd[cur ^ 1][t] = (1.0f - mreg) * MSCL;
        }
        __syncthreads();
        cur ^= 1;
    }

    // ---- epilogue per m: reduce l once, normalize, store hi/lo ----
#pragma unroll
    for (int m = 0; m < 2; ++m) {
        float l = (l4[m][0] + l4[m][1]) + (l4[m][2] + l4[m][3]);
        l += __shfl_xor(l, 16, 64);
        l += __shfl_xor(l, 32, 64);
        float inv = 1.0f / l;
        size_t row = (size_t)(b * SEQ + qt * QBLK + wid * 32 + 16 * m + l15);
#pragma unroll
        for (int n = 0; n < 4; ++n) {
            us4 hv, lv;
#pragma unroll
            for (int r = 0; r < 4; ++r) {
                float o = acc[m][n][r] * inv;
                unsigned short hi = f2bf(o);
                hv[r] = hi;
                lv[r] = f2bf(o - bf2f(hi));
            }
            size_t idx = row * HDIM + h * HD + 16 * n + 4 * g;
            *(us4*)&Ch[idx] = hv;
            *(us4*)&Cl[idx] = lv;
        }
    }
}

// ---------------------------------------------------------------------------
extern "C" void kernel_launch(void* const* d_in, const int* in_sizes, int n_in,
                              void* d_out, int out_size, void* d_ws, size_t ws_size,
                              hipStream_t stream)
{
    const float* hs   = (const float*)d_in[0];
    const float* mask = (const float*)d_in[1];
    const float* Wq = (const float*)d_in[2];
    const float* Wk = (const float*)d_in[3];
    const float* Wv = (const float*)d_in[4];
    const float* Wo = (const float*)d_in[5];
    const float* Aq = (const float*)d_in[6];
    const float* Bq = (const float*)d_in[7];
    const float* Ak = (const float*)d_in[8];
    const float* Bk = (const float*)d_in[9];
    const float* Av = (const float*)d_in[10];
    const float* Bv = (const float*)d_in[11];
    const float* Ao = (const float*)d_in[12];
    const float* Bo = (const float*)d_in[13];
    float* out = (float*)d_out;

    char* w = (char*)d_ws;
    unsigned short* Xh = (unsigned short*)(w);                       // 8 MB (later Ch)
    unsigned short* Xl = (unsigned short*)(w + ((size_t)8 << 20));   // 8 MB (later Cl)
    unsigned short* WT = (unsigned short*)(w + ((size_t)16 << 20));  // 16 MB (8 planes)
    unsigned short* qb = (unsigned short*)(w + ((size_t)32 << 20));  // 8 MB
    unsigned short* kb = (unsigned short*)(w + ((size_t)40 << 20));  // 8 MB
    unsigned short* vb = (unsigned short*)(w + ((size_t)48 << 20));  // 8 MB
    unsigned short* vt = (unsigned short*)(w + ((size_t)56 << 20));  // 8 MB
    float* hsA  = (float*)(w + ((size_t)64 << 20));                  // 4096*24*4
    float* ctxA = (float*)(w + ((size_t)64 << 20) + 400 * 1024);     // 4096*8*4

    split_x_kernel<<<2048, 256, 0, stream>>>(hs, Xh, Xl, MTOT * HDIM / 4);
    tsplit_w_kernel<<<dim3(16, 16, 4), 256, 0, stream>>>(Wq, Wk, Wv, Wo, WT);
    lora_down_kernel<<<MTOT, 64, 0, stream>>>(hs, Aq, Ak, Av, hsA, 3);
    gemm_mfma_kernel<false, 128><<<dim3(8, 32, 3), 256, 0, stream>>>(
        Xh, Xl, WT, 0, hsA, 24, 0, Bq, Bk, Bv, qb, kb, vb);
    transpose_v_kernel<<<dim3(SEQ / 64, BATCH * NHEAD), 256, 0, stream>>>(vb, vt);
    attn_mfma_kernel<<<dim3(SEQ / QBLK, NHEAD, BATCH), 256, 0, stream>>>(
        qb, kb, vt, mask, Xh /*Ch*/, Xl /*Cl*/);
    lora_down_bf_kernel<<<MTOT, 64, 0, stream>>>(Xh, Xl, Ao, ctxA);
    gemm_mfma_kernel<true, 64><<<dim3(8, 64, 1), 256, 0, stream>>>(
        Xh, Xl, WT, 3, ctxA, 8, 0, Bo, Bo, Bo, out, out, out);
}

// Round 11
// 228.505 us; speedup vs baseline: 4.5902x; 1.0507x over previous
//
#include <hip/hip_runtime.h>
#include <math.h>

typedef float fx4 __attribute__((ext_vector_type(4)));
typedef float f32x4 __attribute__((ext_vector_type(4)));
typedef float f32x16 __attribute__((ext_vector_type(16)));
typedef short bf16x8 __attribute__((ext_vector_type(8)));
typedef unsigned short us4 __attribute__((ext_vector_type(4)));
typedef unsigned short us8 __attribute__((ext_vector_type(8)));
typedef unsigned int u32x4 __attribute__((ext_vector_type(4)));

#define HDIM 1024
#define SEQ  2048
#define BATCH 2
#define NHEAD 16
#define HD    64
#define MTOT  4096
#define LSCALE 8.0f
#define LOG2E 1.44269504088896340736f

__device__ __forceinline__ unsigned short f2bf(float f) {
    union { float f; unsigned int u; } v; v.f = f;
    unsigned int r = v.u + 0x7FFFu + ((v.u >> 16) & 1u);
    return (unsigned short)(r >> 16);
}
__device__ __forceinline__ float bf2f(unsigned short h) {
    union { unsigned int u; float f; } v; v.u = ((unsigned int)h) << 16;
    return v.f;
}
// packed bf16 convert: low16 = bf16(a), high16 = bf16(b), RNE
__device__ __forceinline__ unsigned int cvt_pk_bf16(float a, float b) {
    unsigned int r;
    asm("v_cvt_pk_bf16_f32 %0, %1, %2" : "=v"(r) : "v"(a), "v"(b));
    return r;
}

// ---------------------------------------------------------------------------
// split X (fp32) -> hi/lo bf16 planes
// ---------------------------------------------------------------------------
__global__ __launch_bounds__(256)
void split_x_kernel(const float* __restrict__ X, unsigned short* __restrict__ Xh,
                    unsigned short* __restrict__ Xl, int n4)
{
    int i = blockIdx.x * 256 + threadIdx.x;
    int stride = gridDim.x * 256;
    for (; i < n4; i += stride) {
        fx4 v = *((const fx4*)X + i);
        us4 h, l;
#pragma unroll
        for (int j = 0; j < 4; ++j) {
            h[j] = f2bf(v[j]);
            l[j] = f2bf(v[j] - bf2f(h[j]));
        }
        *((us4*)Xh + i) = h;
        *((us4*)Xl + i) = l;
    }
}

// ---------------------------------------------------------------------------
// transpose + split W [k][n] fp32 -> WT hi/lo bf16 [n][k]; z selects matrix.
// ---------------------------------------------------------------------------
__global__ __launch_bounds__(256)
void tsplit_w_kernel(const float* __restrict__ W0, const float* __restrict__ W1,
                     const float* __restrict__ W2, const float* __restrict__ W3,
                     unsigned short* __restrict__ WTbase)
{
    int z = blockIdx.z;
    const float* W = (z == 0) ? W0 : (z == 1) ? W1 : (z == 2) ? W2 : W3;
    unsigned short* WTh = WTbase + (size_t)z * 2097152;
    unsigned short* WTl = WTh + 1048576;
    int n0 = blockIdx.x * 64, k0 = blockIdx.y * 64;
    __shared__ unsigned int T[64][65];
    int t = threadIdx.x;
#pragma unroll
    for (int i = 0; i < 4; ++i) {
        int idx = t + 256 * i;
        int r = idx >> 4, c4 = (idx & 15) * 4;
        fx4 w = *(const fx4*)&W[(size_t)(k0 + r) * HDIM + n0 + c4];
#pragma unroll
        for (int j = 0; j < 4; ++j) {
            unsigned short hi = f2bf(w[j]);
            unsigned short lo = f2bf(w[j] - bf2f(hi));
            T[r][c4 + j] = (unsigned int)hi | ((unsigned int)lo << 16);
        }
    }
    __syncthreads();
#pragma unroll
    for (int i = 0; i < 4; ++i) {
        int idx = t + 256 * i;
        int n = idx >> 4, kg = (idx & 15) * 4;
        us4 hv, lv;
#pragma unroll
        for (int j = 0; j < 4; ++j) {
            unsigned int p = T[kg + j][n];
            hv[j] = (unsigned short)(p & 0xffffu);
            lv[j] = (unsigned short)(p >> 16);
        }
        *(us4*)&WTh[(size_t)(n0 + n) * HDIM + k0 + kg] = hv;
        *(us4*)&WTl[(size_t)(n0 + n) * HDIM + k0 + kg] = lv;
    }
}

// ---------------------------------------------------------------------------
// lora down: fp32 X; XA = X @ [A0|A1|A2]; out row stride 24
// ---------------------------------------------------------------------------
__global__ __launch_bounds__(64)
void lora_down_kernel(const float* __restrict__ X,
                      const float* __restrict__ A0,
                      const float* __restrict__ A1,
                      const float* __restrict__ A2,
                      float* __restrict__ out, int nmat)
{
    int row  = blockIdx.x;
    int lane = threadIdx.x;
    const float* xr = X + (size_t)row * HDIM;
    float xv[16];
#pragma unroll
    for (int i = 0; i < 16; ++i) xv[i] = xr[lane + 64 * i];
    const float* Amats[3] = {A0, A1, A2};
    for (int m = 0; m < nmat; ++m) {
        const float* A = Amats[m];
        float s[8];
#pragma unroll
        for (int c = 0; c < 8; ++c) s[c] = 0.f;
#pragma unroll
        for (int i = 0; i < 16; ++i) {
            const float* ap = A + (size_t)(lane + 64 * i) * 8;
#pragma unroll
            for (int c = 0; c < 8; ++c) s[c] += xv[i] * ap[c];
        }
#pragma unroll
        for (int c = 0; c < 8; ++c) {
#pragma unroll
            for (int off = 1; off < 64; off <<= 1)
                s[c] += __shfl_xor(s[c], off, 64);
        }
        if (lane == 0) {
#pragma unroll
            for (int c = 0; c < 8; ++c)
                out[(size_t)row * 24 + m * 8 + c] = s[c];
        }
    }
}

// lora down from hi/lo bf16 planes (ctx); out stride 8
__global__ __launch_bounds__(64)
void lora_down_bf_kernel(const unsigned short* __restrict__ Xh,
                         const unsigned short* __restrict__ Xl,
                         const float* __restrict__ A,
                         float* __restrict__ out)
{
    int row  = blockIdx.x;
    int lane = threadIdx.x;
    const unsigned short* xh = Xh + (size_t)row * HDIM;
    const unsigned short* xl = Xl + (size_t)row * HDIM;
    float xv[16];
#pragma unroll
    for (int i = 0; i < 16; ++i)
        xv[i] = bf2f(xh[lane + 64 * i]) + bf2f(xl[lane + 64 * i]);
    float s[8];
#pragma unroll
    for (int c = 0; c < 8; ++c) s[c] = 0.f;
#pragma unroll
    for (int i = 0; i < 16; ++i) {
        const float* ap = A + (size_t)(lane + 64 * i) * 8;
#pragma unroll
        for (int c = 0; c < 8; ++c) s[c] += xv[i] * ap[c];
    }
#pragma unroll
    for (int c = 0; c < 8; ++c) {
#pragma unroll
        for (int off = 1; off < 64; off <<= 1)
            s[c] += __shfl_xor(s[c], off, 64);
    }
    if (lane == 0) {
#pragma unroll
        for (int c = 0; c < 8; ++c) out[(size_t)row * 8 + c] = s[c];
    }
}

// ---------------------------------------------------------------------------
// split-bf16 MFMA GEMM: Out = X@W + LSCALE*(XA)@Bu
// BM=128: 4 waves 2x2 of 64x64 (FN=4).  BM=64: 4 waves 1x4 of 64x32 (FN=2).
// pz == vtpz: write output transposed per head into vtout[(b,h,d)][s] (bf16).
// ---------------------------------------------------------------------------
template<bool OUTF32, int BM>
__global__ __launch_bounds__(256, BM == 128 ? 2 : 3)
void gemm_mfma_kernel(const unsigned short* __restrict__ Xh, const unsigned short* __restrict__ Xl,
                      const unsigned short* __restrict__ WTbase, int wsel0,
                      const float* __restrict__ XA, int xa_stride, int xa_off0,
                      const float* __restrict__ Bu0, const float* __restrict__ Bu1, const float* __restrict__ Bu2,
                      void* __restrict__ O0, void* __restrict__ O1, void* __restrict__ O2,
                      int vtpz, unsigned short* __restrict__ vtout)
{
    constexpr int FN = (BM == 128) ? 4 : 2;
    int pz = blockIdx.z;
    const unsigned short* WTh = WTbase + (size_t)(wsel0 + pz) * 2097152;
    const unsigned short* WTl = WTh + 1048576;
    const float* Bu = (pz == 0) ? Bu0 : (pz == 1) ? Bu1 : Bu2;
    void* Ovp       = (pz == 0) ? O0 : (pz == 1) ? O1 : O2;
    int xa_off = xa_off0 + pz * 8;

    int brow = blockIdx.y * BM, bcol = blockIdx.x * 128;
    int t = threadIdx.x, wid = t >> 6, lane = t & 63, l15 = lane & 15, g = lane >> 4;
    int wm = (BM == 128) ? (wid >> 1) * 64 : 0;
    int wn = (BM == 128) ? (wid & 1) * 64 : wid * 32;

    __shared__ unsigned short Ah[BM][40];
    __shared__ unsigned short Al[BM][40];
    __shared__ unsigned short Bh[128][40];
    __shared__ unsigned short Bl[128][40];

    f32x4 acc[4][FN];
#pragma unroll
    for (int i = 0; i < 4; ++i)
#pragma unroll
        for (int j = 0; j < FN; ++j) acc[i][j] = (f32x4){0.f, 0.f, 0.f, 0.f};

    int sm = t >> 2, skg = t & 3;
    const unsigned short* aH0 = Xh  + (size_t)(brow + sm) * HDIM + 8 * skg;
    const unsigned short* aL0 = Xl  + (size_t)(brow + sm) * HDIM + 8 * skg;
    const unsigned short* bH0 = WTh + (size_t)(bcol + sm) * HDIM + 8 * skg;
    const unsigned short* bL0 = WTl + (size_t)(bcol + sm) * HDIM + 8 * skg;
    const size_t R64 = (size_t)64 * HDIM;

    us8 rAH0, rAH1, rAL0, rAL1, rBH0, rBH1, rBL0, rBL1;
    rAH0 = *(const us8*)(aH0);
    rAL0 = *(const us8*)(aL0);
    if (BM == 128) {
        rAH1 = *(const us8*)(aH0 + R64);
        rAL1 = *(const us8*)(aL0 + R64);
    }
    rBH0 = *(const us8*)(bH0);
    rBH1 = *(const us8*)(bH0 + R64);
    rBL0 = *(const us8*)(bL0);
    rBL1 = *(const us8*)(bL0 + R64);

    for (int k0 = 0; k0 < HDIM; k0 += 32) {
        __syncthreads();
        *(us8*)&Ah[sm][8 * skg] = rAH0;
        *(us8*)&Al[sm][8 * skg] = rAL0;
        if (BM == 128) {
            *(us8*)&Ah[(sm + 64) & (BM - 1)][8 * skg] = rAH1;
            *(us8*)&Al[(sm + 64) & (BM - 1)][8 * skg] = rAL1;
        }
        *(us8*)&Bh[sm][8 * skg]      = rBH0;
        *(us8*)&Bh[sm + 64][8 * skg] = rBH1;
        *(us8*)&Bl[sm][8 * skg]      = rBL0;
        *(us8*)&Bl[sm + 64][8 * skg] = rBL1;
        __syncthreads();
        if (k0 + 32 < HDIM) {
            int ko = k0 + 32;
            rAH0 = *(const us8*)(aH0 + ko);
            rAL0 = *(const us8*)(aL0 + ko);
            if (BM == 128) {
                rAH1 = *(const us8*)(aH0 + R64 + ko);
                rAL1 = *(const us8*)(aL0 + R64 + ko);
            }
            rBH0 = *(const us8*)(bH0 + ko);
            rBH1 = *(const us8*)(bH0 + R64 + ko);
            rBL0 = *(const us8*)(bL0 + ko);
            rBL1 = *(const us8*)(bL0 + R64 + ko);
        }
        bf16x8 fah[4], fal[4], fbh[FN], fbl[FN];
#pragma unroll
        for (int f = 0; f < 4; ++f) {
            fah[f] = *(const bf16x8*)&Ah[wm + 16 * f + l15][8 * g];
            fal[f] = *(const bf16x8*)&Al[wm + 16 * f + l15][8 * g];
        }
#pragma unroll
        for (int f = 0; f < FN; ++f) {
            fbh[f] = *(const bf16x8*)&Bh[wn + 16 * f + l15][8 * g];
            fbl[f] = *(const bf16x8*)&Bl[wn + 16 * f + l15][8 * g];
        }
#pragma unroll
        for (int fm = 0; fm < 4; ++fm)
#pragma unroll
            for (int fn = 0; fn < FN; ++fn) {
                f32x4 a = acc[fm][fn];
                a = __builtin_amdgcn_mfma_f32_16x16x32_bf16(fah[fm], fbh[fn], a, 0, 0, 0);
                a = __builtin_amdgcn_mfma_f32_16x16x32_bf16(fah[fm], fbl[fn], a, 0, 0, 0);
                a = __builtin_amdgcn_mfma_f32_16x16x32_bf16(fal[fm], fbh[fn], a, 0, 0, 0);
                acc[fm][fn] = a;
            }
    }

    // LoRA epilogue + store
    float lb[8][FN];
#pragma unroll
    for (int rr = 0; rr < 8; ++rr)
#pragma unroll
        for (int fn = 0; fn < FN; ++fn)
            lb[rr][fn] = Bu[(size_t)rr * HDIM + bcol + wn + 16 * fn + l15] * LSCALE;

#pragma unroll
    for (int fm = 0; fm < 4; ++fm) {
        float la[4][8];
#pragma unroll
        for (int r = 0; r < 4; ++r) {
            int row = brow + wm + 16 * fm + 4 * g + r;
            const float* lap = XA + (size_t)row * xa_stride + xa_off;
            fx4 q0 = *(const fx4*)lap;
            fx4 q1 = *(const fx4*)(lap + 4);
#pragma unroll
            for (int j = 0; j < 4; ++j) { la[r][j] = q0[j]; la[r][4 + j] = q1[j]; }
        }
#pragma unroll
        for (int fn = 0; fn < FN; ++fn) {
            float tmp[4];
#pragma unroll
            for (int r = 0; r < 4; ++r) {
                float sum = acc[fm][fn][r];
#pragma unroll
                for (int rr = 0; rr < 8; ++rr) sum += la[r][rr] * lb[rr][fn];
                tmp[r] = sum;
            }
            int col  = bcol + wn + 16 * fn + l15;
            int rowb = brow + wm + 16 * fm + 4 * g;
            if (pz == vtpz) {
                int hh = col >> 6, d = col & 63;
                int bb = rowb >> 11, ss = rowb & 2047;
                us4 hv;
#pragma unroll
                for (int r = 0; r < 4; ++r) hv[r] = f2bf(tmp[r]);
                *(us4*)&vtout[(size_t)((bb * NHEAD + hh) * HD + d) * SEQ + ss] = hv;
            } else if (OUTF32) {
#pragma unroll
                for (int r = 0; r < 4; ++r)
                    ((float*)Ovp)[(size_t)(rowb + r) * HDIM + col] = tmp[r];
            } else {
#pragma unroll
                for (int r = 0; r < 4; ++r)
                    ((unsigned short*)Ovp)[(size_t)(rowb + r) * HDIM + col] = f2bf(tmp[r]);
            }
        }
    }
}

// ---------------------------------------------------------------------------
// flash attention, 32x32x16 MFMA, swapped operands, fixed-max softmax.
// Wave owns 32 q-rows (q = lane&31). QK = mfma(K, Q): D col=q, lane holds
// 32 kv slots: kv = r + 8h + 4*g1 + 32*kvhalf (g1 = lane>>5).
// P->B-fragment redistribution via v_permlane32_swap_b32 (0 cndmask).
// PV = mfma(V, P): acc col=q, rows = d. Double-buffered K/V/mask staging.
// ---------------------------------------------------------------------------
#define QBLK 128
#define KVB  64
#define NT   (SEQ / KVB)

__global__ __launch_bounds__(256, 2)
void attn_mfma_kernel(const unsigned short* __restrict__ Qg, const unsigned short* __restrict__ Kg,
                      const unsigned short* __restrict__ Vt, const float* __restrict__ mask,
                      unsigned short* __restrict__ Ch, unsigned short* __restrict__ Cl)
{
    int qt = blockIdx.x, hd = blockIdx.y, b = blockIdx.z;
    int t    = threadIdx.x;
    int wid  = t >> 6;
    int lane = t & 63;
    int q31  = lane & 31;
    int g1   = lane >> 5;

    __shared__ __align__(16) unsigned short Ks[2][64][72];
    __shared__ __align__(16) unsigned short Vs[2][64][72];   // Vs[d][s]
    __shared__ __align__(16) float Msd[2][64];

    // Q as B-fragment: col=q=q31, k(d) = 16kc + 8*g1 + j
    bf16x8 qB[4];
    const unsigned short* qp = Qg + (size_t)(b * SEQ + qt * QBLK + wid * 32 + q31) * HDIM + hd * HD;
#pragma unroll
    for (int kc = 0; kc < 4; ++kc)
        qB[kc] = *(const bf16x8*)(qp + 16 * kc + 8 * g1);

    float m0 = 0.f;                       // fixed row max (log2), set at kt==0
    f32x4 l4 = (f32x4){0.f, 0.f, 0.f, 0.f};
    f32x16 accO[2];
#pragma unroll
    for (int dh = 0; dh < 2; ++dh)
#pragma unroll
        for (int i = 0; i < 16; ++i) accO[dh][i] = 0.f;

    const unsigned short* kp0 = Kg + (size_t)(b * SEQ) * HDIM + hd * HD;
    const unsigned short* vt0 = Vt + (size_t)((b * NHEAD + hd) * HD) * SEQ;

    const float QSCL = 0.125f * LOG2E;
    const float MSCL = -10000.0f * LOG2E;

    int r0 = t >> 3,           c0 = (t & 7) * 8;
    int r1 = (t + 256) >> 3,   c1 = c0;

    // prologue: stage tile 0 into buffer 0
    *(us8*)&Ks[0][r0][c0] = *(const us8*)(kp0 + (size_t)r0 * HDIM + c0);
    *(us8*)&Ks[0][r1][c1] = *(const us8*)(kp0 + (size_t)r1 * HDIM + c1);
    *(us8*)&Vs[0][r0][c0] = *(const us8*)(vt0 + (size_t)r0 * SEQ + c0);
    *(us8*)&Vs[0][r1][c1] = *(const us8*)(vt0 + (size_t)r1 * SEQ + c1);
    if (t < 64) Msd[0][t] = (1.0f - mask[b * SEQ + t]) * MSCL;
    __syncthreads();

    int cur = 0;
    for (int kt = 0; kt < NT; ++kt) {
        us8 knr0, knr1, vnr0, vnr1;
        float mreg = 1.0f;
        bool more = (kt + 1 < NT);
        if (more) {
            const unsigned short* kp = kp0 + (size_t)(kt + 1) * KVB * HDIM;
            const unsigned short* vp = vt0 + (kt + 1) * KVB;
            knr0 = *(const us8*)(kp + (size_t)r0 * HDIM + c0);
            knr1 = *(const us8*)(kp + (size_t)r1 * HDIM + c1);
            vnr0 = *(const us8*)(vp + (size_t)r0 * SEQ + c0);
            vnr1 = *(const us8*)(vp + (size_t)r1 * SEQ + c1);
            if (t < 64) mreg = mask[b * SEQ + (kt + 1) * KVB + t];
        }

        // ---- QK^T swapped (32x32x16): sQ[kvh] col=q31, row=kv ----
        f32x16 sQ[2];
#pragma unroll
        for (int kvh = 0; kvh < 2; ++kvh) {
            f32x16 a;
#pragma unroll
            for (int i = 0; i < 16; ++i) a[i] = 0.f;
#pragma unroll
            for (int kc = 0; kc < 4; ++kc) {
                bf16x8 kA = *(const bf16x8*)&Ks[cur][32 * kvh + q31][16 * kc + 8 * g1];
                a = __builtin_amdgcn_mfma_f32_32x32x16_bf16(kA, qB[kc], a, 0, 0, 0);
            }
            sQ[kvh] = a;
        }

        // ---- scale + mask (log2 domain): kv = r + 8h + 4g1 + 32kvh ----
#pragma unroll
        for (int kvh = 0; kvh < 2; ++kvh)
#pragma unroll
            for (int hh = 0; hh < 4; ++hh) {
                fx4 msk = *(const fx4*)&Msd[cur][32 * kvh + 8 * hh + 4 * g1];
#pragma unroll
                for (int r = 0; r < 4; ++r)
                    sQ[kvh][4 * hh + r] = fmaf(sQ[kvh][4 * hh + r], QSCL, msk[r]);
            }

        // ---- tile-0: fixed row max (this lane's 32 kv + partner's 32) ----
        if (kt == 0) {
            float mx = sQ[0][0];
#pragma unroll
            for (int kvh = 0; kvh < 2; ++kvh)
#pragma unroll
                for (int i = 0; i < 16; ++i) mx = fmaxf(mx, sQ[kvh][i]);
            mx = fmaxf(mx, __shfl_xor(mx, 32, 64));
            m0 = fmaxf(mx, -64.f);
        }

        // ---- P = exp2(s - m0); l in 4 independent partials ----
#pragma unroll
        for (int kvh = 0; kvh < 2; ++kvh)
#pragma unroll
            for (int hh = 0; hh < 4; ++hh)
#pragma unroll
                for (int r = 0; r < 4; ++r) {
                    float p = exp2f(sQ[kvh][4 * hh + r] - m0);
                    sQ[kvh][4 * hh + r] = p;
                    l4[r] += p;
                }

        // ---- pack to bf16 dwords: pkx[kvh][h]=(kv+0,+1), pky=(+2,+3) ----
        unsigned int pkx[2][4], pky[2][4];
#pragma unroll
        for (int kvh = 0; kvh < 2; ++kvh)
#pragma unroll
            for (int hh = 0; hh < 4; ++hh) {
                pkx[kvh][hh] = cvt_pk_bf16(sQ[kvh][4 * hh + 0], sQ[kvh][4 * hh + 1]);
                pky[kvh][hh] = cvt_pk_bf16(sQ[kvh][4 * hh + 2], sQ[kvh][4 * hh + 3]);
            }

        // ---- build PV B-fragments via permlane32_swap (see header) ----
        // pB[kc'] holds P[kv = 16kc' + 8g1 + j][q=q31], j=0..7.
        bf16x8 pB[4];
#pragma unroll
        for (int kvh = 0; kvh < 2; ++kvh)
#pragma unroll
            for (int kc2 = 0; kc2 < 2; ++kc2) {
                unsigned int x0 = pkx[kvh][2 * kc2], x1 = pkx[kvh][2 * kc2 + 1];
                unsigned int y0 = pky[kvh][2 * kc2], y1 = pky[kvh][2 * kc2 + 1];
                asm("v_permlane32_swap_b32 %0, %1" : "+v"(x0), "+v"(x1));
                asm("v_permlane32_swap_b32 %0, %1" : "+v"(y0), "+v"(y1));
                u32x4 dd;
                dd[0] = x0; dd[1] = y0; dd[2] = x1; dd[3] = y1;
                pB[2 * kvh + kc2] = *(bf16x8*)&dd;
            }

        // ---- PV swapped (32x32x16): accO[dh] col=q31, rows=d ----
#pragma unroll
        for (int dh = 0; dh < 2; ++dh) {
            f32x16 a = accO[dh];
#pragma unroll
            for (int kcp = 0; kcp < 4; ++kcp) {
                bf16x8 vA = *(const bf16x8*)&Vs[cur][32 * dh + q31][16 * kcp + 8 * g1];
                a = __builtin_amdgcn_mfma_f32_32x32x16_bf16(vA, pB[kcp], a, 0, 0, 0);
            }
            accO[dh] = a;
        }

        if (more) {
            *(us8*)&Ks[cur ^ 1][r0][c0] = knr0;
            *(us8*)&Ks[cur ^ 1][r1][c1] = knr1;
            *(us8*)&Vs[cur ^ 1][r0][c0] = vnr0;
            *(us8*)&Vs[cur ^ 1][r1][c1] = vnr1;
            if (t < 64) Msd[cur ^ 1][t] = (1.0f - mreg) * MSCL;
        }
        __syncthreads();
        cur ^= 1;
    }

    // ---- epilogue: reduce l (partner holds other 32 kv), store hi/lo ----
    float l = (l4[0] + l4[1]) + (l4[2] + l4[3]);
    l += __shfl_xor(l, 32, 64);
    float inv = 1.0f / l;
    size_t row = (size_t)(b * SEQ + qt * QBLK + wid * 32 + q31);
#pragma unroll
    for (int dh = 0; dh < 2; ++dh)
#pragma unroll
        for (int hh = 0; hh < 4; ++hh) {
            us4 hv, lv;
#pragma unroll
            for (int r = 0; r < 4; ++r) {
                float o = accO[dh][4 * hh + r] * inv;
                unsigned short hi = f2bf(o);
                hv[r] = hi;
                lv[r] = f2bf(o - bf2f(hi));
            }
            size_t idx = row * HDIM + hd * HD + 32 * dh + 8 * hh + 4 * g1;
            *(us4*)&Ch[idx] = hv;
            *(us4*)&Cl[idx] = lv;
        }
}

// ---------------------------------------------------------------------------
extern "C" void kernel_launch(void* const* d_in, const int* in_sizes, int n_in,
                              void* d_out, int out_size, void* d_ws, size_t ws_size,
                              hipStream_t stream)
{
    const float* hs   = (const float*)d_in[0];
    const float* mask = (const float*)d_in[1];
    const float* Wq = (const float*)d_in[2];
    const float* Wk = (const float*)d_in[3];
    const float* Wv = (const float*)d_in[4];
    const float* Wo = (const float*)d_in[5];
    const float* Aq = (const float*)d_in[6];
    const float* Bq = (const float*)d_in[7];
    const float* Ak = (const float*)d_in[8];
    const float* Bk = (const float*)d_in[9];
    const float* Av = (const float*)d_in[10];
    const float* Bv = (const float*)d_in[11];
    const float* Ao = (const float*)d_in[12];
    const float* Bo = (const float*)d_in[13];
    float* out = (float*)d_out;

    char* w = (char*)d_ws;
    unsigned short* Xh = (unsigned short*)(w);                       // 8 MB (later Ch)
    unsigned short* Xl = (unsigned short*)(w + ((size_t)8 << 20));   // 8 MB (later Cl)
    unsigned short* WT = (unsigned short*)(w + ((size_t)16 << 20));  // 16 MB (8 planes)
    unsigned short* qb = (unsigned short*)(w + ((size_t)32 << 20));  // 8 MB
    unsigned short* kb = (unsigned short*)(w + ((size_t)40 << 20));  // 8 MB
    unsigned short* vt = (unsigned short*)(w + ((size_t)56 << 20));  // 8 MB (V transposed, written by GEMM)
    float* hsA  = (float*)(w + ((size_t)64 << 20));                  // 4096*24*4
    float* ctxA = (float*)(w + ((size_t)64 << 20) + 400 * 1024);     // 4096*8*4

    split_x_kernel<<<2048, 256, 0, stream>>>(hs, Xh, Xl, MTOT * HDIM / 4);
    tsplit_w_kernel<<<dim3(16, 16, 4), 256, 0, stream>>>(Wq, Wk, Wv, Wo, WT);
    lora_down_kernel<<<MTOT, 64, 0, stream>>>(hs, Aq, Ak, Av, hsA, 3);
    gemm_mfma_kernel<false, 128><<<dim3(8, 32, 3), 256, 0, stream>>>(
        Xh, Xl, WT, 0, hsA, 24, 0, Bq, Bk, Bv, qb, kb, nullptr, 2, vt);
    attn_mfma_kernel<<<dim3(SEQ / QBLK, NHEAD, BATCH), 256, 0, stream>>>(
        qb, kb, vt, mask, Xh /*Ch*/, Xl /*Cl*/);
    lora_down_bf_kernel<<<MTOT, 64, 0, stream>>>(Xh, Xl, Ao, ctxA);
    gemm_mfma_kernel<true, 64><<<dim3(8, 64, 1), 256, 0, stream>>>(
        Xh, Xl, WT, 3, ctxA, 8, 0, Bo, Bo, Bo, out, out, out, -1, nullptr);
}